// Round 3
// baseline (1557.389 us; speedup 1.0000x reference)
//
#include <hip/hip_runtime.h>
#include <hip/hip_bf16.h>
#include <stdint.h>

// Problem constants: B=4, N=4096, C=512, H=8, M=64, HD=64
#define QSZe 8388608ull  // elements per Q/K/V tensor (B*H*N*HD)

__device__ __forceinline__ float bf2f(unsigned short u) {
  return __uint_as_float(((unsigned int)u) << 16);
}
__device__ __forceinline__ unsigned short f2bf(float f) {
  unsigned int u = __float_as_uint(f);
  unsigned int r = (u + 0x7FFFu + ((u >> 16) & 1u)) >> 16;
  return (unsigned short)r;
}

// ---------------------------------------------------------------------------
// Dtype detector: reads first 256 ushorts of x. bf16 N(0,1) data has exponent
// field <= ~0x82; fp32 bits read as bf16 have ~uniform exponent in the low
// half-word -> values >= 2^16 almost surely. flag=1 means "inputs are fp32".
// ---------------------------------------------------------------------------
__global__ void detect_dtype(const unsigned short* __restrict__ raw,
                             unsigned int* __restrict__ flag) {
  int t = threadIdx.x;  // 64 threads
  int big = 0;
  for (int i = t; i < 256; i += 64) {
    int e = (raw[i] >> 7) & 0xFF;
    if (e >= 0x8F) big = 1;  // |val| >= 2^16 (or NaN/Inf)
  }
  unsigned long long b = __ballot(big);
  if (t == 0) flag[0] = (b != 0ull) ? 1u : 0u;
}

// Canonicalize a tensor to bf16 (round if fp32, copy if already bf16).
__global__ __launch_bounds__(256) void convert_bf16(
    const void* __restrict__ raw, unsigned short* __restrict__ canon, int n,
    const unsigned int* __restrict__ flag) {
  int i8 = (blockIdx.x * 256 + threadIdx.x) * 8;
  if (i8 >= n) return;
  if (flag[0]) {
    const float* f = (const float*)raw;
    float4 a = *(const float4*)(f + i8);
    float4 b = *(const float4*)(f + i8 + 4);
    unsigned short o[8] = {f2bf(a.x), f2bf(a.y), f2bf(a.z), f2bf(a.w),
                           f2bf(b.x), f2bf(b.y), f2bf(b.z), f2bf(b.w)};
    *(uint4*)(canon + i8) = *(const uint4*)o;
  } else {
    *(uint4*)(canon + i8) = *(const uint4*)((const unsigned short*)raw + i8);
  }
}

// Canonicalize a small tensor to fp32 (used for proj_b).
__global__ __launch_bounds__(256) void convert_f32(
    const void* __restrict__ raw, float* __restrict__ canon, int n,
    const unsigned int* __restrict__ flag) {
  int i = blockIdx.x * 256 + threadIdx.x;
  if (i >= n) return;
  canon[i] = flag[0] ? ((const float*)raw)[i]
                     : bf2f(((const unsigned short*)raw)[i]);
}

// ---------------------------------------------------------------------------
// 64x64x64 LDS matmul helper, stride 64.  D = s*(A@B) + dg*I
// ---------------------------------------------------------------------------
__device__ __forceinline__ void mm64(const float* __restrict__ A,
                                     const float* __restrict__ Bm,
                                     float* __restrict__ D,
                                     int t, float s, float dg) {
  const int tx = t & 15, ty = t >> 4;
  const int r0 = ty * 4, c0 = tx * 4;
  float acc[4][4] = {};
#pragma unroll 8
  for (int k = 0; k < 64; k++) {
    float4 b = *(const float4*)&Bm[k * 64 + c0];
    float a[4];
#pragma unroll
    for (int i = 0; i < 4; i++) a[i] = A[(r0 + i) * 64 + k];
#pragma unroll
    for (int i = 0; i < 4; i++) {
      acc[i][0] = fmaf(a[i], b.x, acc[i][0]);
      acc[i][1] = fmaf(a[i], b.y, acc[i][1]);
      acc[i][2] = fmaf(a[i], b.z, acc[i][2]);
      acc[i][3] = fmaf(a[i], b.w, acc[i][3]);
    }
  }
#pragma unroll
  for (int i = 0; i < 4; i++)
#pragma unroll
    for (int j = 0; j < 4; j++)
      D[(r0 + i) * 64 + c0 + j] =
          s * acc[i][j] + (((r0 + i) == (c0 + j)) ? dg : 0.0f);
}

// ---------------------------------------------------------------------------
// Kernel A: qkv = x @ qkv_w^T (bf16 in), write Q,K,V bf16 in [B,H,N,64],
// Q,K scaled by 64^-0.25.  Grid (24, 256), 256 thr.
// ---------------------------------------------------------------------------
__global__ __launch_bounds__(256) void qkv_gemm(
    const unsigned short* __restrict__ x, const unsigned short* __restrict__ w,
    unsigned short* __restrict__ qkv) {
  __shared__ float As[64][36];
  __shared__ float Bs[64][36];
  const int t = threadIdx.x;
  const int tx = t & 15, ty = t >> 4;
  const int i0 = blockIdx.y * 64, j0 = blockIdx.x * 64;
  const int lr = t >> 2, lk = (t & 3) * 8;
  float acc[4][4] = {};
  for (int k0 = 0; k0 < 512; k0 += 32) {
    uint4 av = *(const uint4*)(x + (size_t)(i0 + lr) * 512 + k0 + lk);
    uint4 bv = *(const uint4*)(w + (size_t)(j0 + lr) * 512 + k0 + lk);
    const unsigned short* aa = (const unsigned short*)&av;
    const unsigned short* bb = (const unsigned short*)&bv;
    *(float4*)&As[lr][lk] =
        make_float4(bf2f(aa[0]), bf2f(aa[1]), bf2f(aa[2]), bf2f(aa[3]));
    *(float4*)&As[lr][lk + 4] =
        make_float4(bf2f(aa[4]), bf2f(aa[5]), bf2f(aa[6]), bf2f(aa[7]));
    *(float4*)&Bs[lr][lk] =
        make_float4(bf2f(bb[0]), bf2f(bb[1]), bf2f(bb[2]), bf2f(bb[3]));
    *(float4*)&Bs[lr][lk + 4] =
        make_float4(bf2f(bb[4]), bf2f(bb[5]), bf2f(bb[6]), bf2f(bb[7]));
    __syncthreads();
#pragma unroll
    for (int k4 = 0; k4 < 32; k4 += 4) {
      float4 bq[4];
#pragma unroll
      for (int j = 0; j < 4; j++) bq[j] = *(const float4*)&Bs[tx + 16 * j][k4];
#pragma unroll
      for (int i = 0; i < 4; i++) {
        float4 aq = *(const float4*)&As[ty * 4 + i][k4];
#pragma unroll
        for (int j = 0; j < 4; j++) {
          acc[i][j] = fmaf(aq.x, bq[j].x, acc[i][j]);
          acc[i][j] = fmaf(aq.y, bq[j].y, acc[i][j]);
          acc[i][j] = fmaf(aq.z, bq[j].z, acc[i][j]);
          acc[i][j] = fmaf(aq.w, bq[j].w, acc[i][j]);
        }
      }
    }
    __syncthreads();
  }
  const int which = blockIdx.x >> 3, h = blockIdx.x & 7;
  const float scale = (which < 2) ? 0.3535533905932738f : 1.0f;
#pragma unroll
  for (int i = 0; i < 4; i++) {
    int row = i0 + ty * 4 + i;
    int b_ = row >> 12, n = row & 4095;
    unsigned short* dst = qkv + (size_t)which * QSZe +
                          ((size_t)(b_ * 8 + h) * 4096 + n) * 64;
#pragma unroll
    for (int j = 0; j < 4; j++) dst[tx + 16 * j] = f2bf(acc[i][j] * scale);
  }
}

// ---------------------------------------------------------------------------
// Kernel B: landmark mean-pool over segments of 64 tokens. Grid 512 x 256.
// ---------------------------------------------------------------------------
__global__ __launch_bounds__(256) void pool_kernel(
    const unsigned short* __restrict__ qkv, float* __restrict__ Ql,
    float* __restrict__ Kl) {
  int idx = blockIdx.x * 256 + threadIdx.x;  // [bh][m][d]
  int d = idx & 63;
  int m = (idx >> 6) & 63;
  int bh = idx >> 12;
  const unsigned short* qb =
      qkv + (size_t)bh * 262144 + (size_t)m * 4096 + d;
  const unsigned short* kb = qb + QSZe;
  float sq = 0.f, sk = 0.f;
#pragma unroll 8
  for (int tok = 0; tok < 64; tok++) {
    sq += bf2f(qb[tok * 64]);
    sk += bf2f(kb[tok * 64]);
  }
  Ql[idx] = sq * (1.0f / 64.0f);
  Kl[idx] = sk * (1.0f / 64.0f);
}

// ---------------------------------------------------------------------------
// Kernel C: kernel_2 = softmax(Ql@Kl^T) per (b,h); global max colsum/rowsum
// via atomicMax (positive-float-as-uint).  Grid 32 x 256.
// ---------------------------------------------------------------------------
__global__ __launch_bounds__(256) void k2_kernel(
    const float* __restrict__ Ql, const float* __restrict__ Kl,
    float* __restrict__ k2, unsigned int* __restrict__ gstat) {
  __shared__ float KlT[64 * 64];  // [d][l]
  __shared__ float Ps[64][65];
  int t = threadIdx.x;
  int lane = t & 63, wv = t >> 6;
  int bh = blockIdx.x;
#pragma unroll
  for (int i = 0; i < 16; i++) {
    int idx = i * 256 + t;
    KlT[(idx & 63) * 64 + (idx >> 6)] = Kl[bh * 4096 + idx];
  }
  __syncthreads();
  for (int r = wv * 16; r < wv * 16 + 16; r++) {
    float qv = Ql[(bh * 64 + r) * 64 + lane];
    float acc = 0.f;
#pragma unroll
    for (int k = 0; k < 64; k++) acc += __shfl(qv, k, 64) * KlT[k * 64 + lane];
    float mx = acc;
#pragma unroll
    for (int o = 32; o > 0; o >>= 1) mx = fmaxf(mx, __shfl_xor(mx, o, 64));
    float e = __expf(acc - mx);
    float s = e;
#pragma unroll
    for (int o = 32; o > 0; o >>= 1) s += __shfl_xor(s, o, 64);
    float p = e / s;
    k2[(bh * 64 + r) * 64 + lane] = p;
    Ps[r][lane] = p;
  }
  __syncthreads();
  float val = 0.f;
  if (t < 64) {
    for (int r = 0; r < 64; r++) val += Ps[r][t];  // column sums
  } else if (t < 128) {
    int r = t - 64;
    for (int c = 0; c < 64; c++) val += Ps[r][c];  // row sums
  }
  float mv = val;
#pragma unroll
  for (int o = 32; o > 0; o >>= 1) mv = fmaxf(mv, __shfl_xor(mv, o, 64));
  if (t == 0) atomicMax(gstat + 0, __float_as_uint(mv));
  if (t == 64) atomicMax(gstat + 1, __float_as_uint(mv));
}

// ---------------------------------------------------------------------------
// Kernel E: kernel_3 row softmax over N fused with W = P @ V.
// One block per (b,h,m).  Grid 2048 x 256.
// ---------------------------------------------------------------------------
__global__ __launch_bounds__(256) void k3v_kernel(
    const float* __restrict__ Ql, const unsigned short* __restrict__ qkv,
    float* __restrict__ W) {
  __shared__ float lg[4096];
  __shared__ __align__(16) float qr[64];
  __shared__ float red[256];
  int t = threadIdx.x;
  int m = blockIdx.x & 63, bh = blockIdx.x >> 6;
  const unsigned short* Kb = qkv + QSZe + (size_t)bh * 262144;
  const unsigned short* Vb = qkv + 2 * QSZe + (size_t)bh * 262144;
  if (t < 64) qr[t] = Ql[(bh * 64 + m) * 64 + t];
  __syncthreads();
  float lmax = -1e30f;
#pragma unroll 4
  for (int i = 0; i < 16; i++) {
    int n = i * 256 + t;
    const uint4* kp = (const uint4*)(Kb + (size_t)n * 64);
    float acc = 0.f;
#pragma unroll
    for (int c8 = 0; c8 < 8; c8++) {
      uint4 kv = kp[c8];
      const unsigned short* ks = (const unsigned short*)&kv;
#pragma unroll
      for (int j = 0; j < 8; j++) acc = fmaf(bf2f(ks[j]), qr[c8 * 8 + j], acc);
    }
    lg[n] = acc;
    lmax = fmaxf(lmax, acc);
  }
  red[t] = lmax;
  __syncthreads();
  for (int s = 128; s > 0; s >>= 1) {
    if (t < s) red[t] = fmaxf(red[t], red[t + s]);
    __syncthreads();
  }
  float mx = red[0];
  __syncthreads();
  float lsum = 0.f;
#pragma unroll 4
  for (int i = 0; i < 16; i++) {
    int n = i * 256 + t;
    float e = __expf(lg[n] - mx);
    lg[n] = e;
    lsum += e;
  }
  red[t] = lsum;
  __syncthreads();
  for (int s = 128; s > 0; s >>= 1) {
    if (t < s) red[t] += red[t + s];
    __syncthreads();
  }
  float inv_s = 1.0f / red[0];
  __syncthreads();
  int d = t & 63, ch = t >> 6;
  float acc = 0.f;
  for (int n = ch * 1024; n < ch * 1024 + 1024; n++)
    acc = fmaf(lg[n], bf2f(Vb[(size_t)n * 64 + d]), acc);
  red[t] = acc;
  __syncthreads();
  if (t < 64) {
    float wv = (red[t] + red[64 + t] + red[128 + t] + red[192 + t]) * inv_s;
    W[(bh * 64 + m) * 64 + t] = wv;
  }
}

// ---------------------------------------------------------------------------
// Kernel D: Newton-Schulz pseudo-inverse (6 iters) + Z = inv @ W.
// One block per (b,h). Uses 15I - KV(7I-KV) = 15I - 7*KV + KV^2.
// ---------------------------------------------------------------------------
__global__ __launch_bounds__(256) void ns_kernel(
    const float* __restrict__ k2g, const unsigned int* __restrict__ gstat,
    const float* __restrict__ Wg, float* __restrict__ Z) {
  __shared__ float lds[4 * 4096];
  float* PK = lds;
  float* PV = lds + 4096;
  float* PA = lds + 2 * 4096;
  float* PBf = lds + 3 * 4096;
  int t = threadIdx.x, bh = blockIdx.x;
#pragma unroll
  for (int i = 0; i < 16; i++) {
    int idx = i * 256 + t;
    PK[idx] = k2g[bh * 4096 + idx];
  }
  __syncthreads();
  float scale =
      1.0f / (__uint_as_float(gstat[0]) * __uint_as_float(gstat[1]));
#pragma unroll
  for (int i = 0; i < 16; i++) {
    int idx = i * 256 + t;
    int r = idx >> 6, c = idx & 63;
    PV[r * 64 + c] = PK[c * 64 + r] * scale;  // V0 = K2^T / (cmax*rmax)
  }
  __syncthreads();
  for (int it = 0; it < 6; it++) {
    mm64(PK, PV, PA, t, 1.0f, 0.0f);  // PA = KV
    __syncthreads();
    mm64(PA, PA, PBf, t, 1.0f, 0.0f);  // PBf = KV^2
    __syncthreads();
#pragma unroll
    for (int i = 0; i < 16; i++) {
      int idx = i * 256 + t;
      int r = idx >> 6, c = idx & 63;
      PBf[idx] = ((r == c) ? 15.0f : 0.0f) - 7.0f * PA[idx] + PBf[idx];
    }
    __syncthreads();
    mm64(PA, PBf, PK, t, -1.0f, 13.0f);  // PK = 13I - KV@T2
    __syncthreads();
    mm64(PV, PK, PA, t, 0.25f, 0.0f);  // PA = 0.25 * V@T3
    __syncthreads();
    float* tmp = PV; PV = PA; PA = tmp;
#pragma unroll
    for (int i = 0; i < 16; i++) {
      int idx = i * 256 + t;
      PK[idx] = k2g[bh * 4096 + idx];
    }
    __syncthreads();
  }
#pragma unroll
  for (int i = 0; i < 16; i++) {
    int idx = i * 256 + t;
    PK[idx] = Wg[bh * 4096 + idx];
  }
  __syncthreads();
  mm64(PV, PK, PA, t, 1.0f, 0.0f);  // Z = inv @ W
  __syncthreads();
#pragma unroll
  for (int i = 0; i < 16; i++) {
    int idx = i * 256 + t;
    Z[bh * 4096 + idx] = PA[idx];
  }
}

// ---------------------------------------------------------------------------
// Kernel G: kernel_1 softmax fused with X = P @ Z.  Grid (32, 64).
// Writes X bf16 in [B,N,C].
// ---------------------------------------------------------------------------
__global__ __launch_bounds__(256) void k1x_kernel(
    const unsigned short* __restrict__ qkv, const float* __restrict__ Kl,
    const float* __restrict__ Z, unsigned short* __restrict__ X) {
  __shared__ float lds[16384];
  float* Qs = lds;          // [r][k]
  float* KlT = lds + 4096;  // [k][c]
  float* Ls = lds + 8192;   // [r][c]
  float* Zs = lds + 12288;  // [m][d]
  int t = threadIdx.x;
  int bh = blockIdx.x, n0 = blockIdx.y * 64;
  const unsigned short* Qb = qkv + (size_t)bh * 262144 + (size_t)n0 * 64;
  const float4* Zb4 = (const float4*)(Z + bh * 4096);
  float4* Zs4 = (float4*)Zs;
#pragma unroll
  for (int i = 0; i < 2; i++) {
    int idx8 = (i * 256 + t) * 8;
    uint4 v = *(const uint4*)(Qb + idx8);
    const unsigned short* s = (const unsigned short*)&v;
#pragma unroll
    for (int j = 0; j < 8; j++) Qs[idx8 + j] = bf2f(s[j]);
  }
#pragma unroll
  for (int i = 0; i < 4; i++) Zs4[i * 256 + t] = Zb4[i * 256 + t];
#pragma unroll
  for (int i = 0; i < 16; i++) {
    int idx = i * 256 + t;
    KlT[(idx & 63) * 64 + (idx >> 6)] = Kl[bh * 4096 + idx];
  }
  __syncthreads();
  mm64(Qs, KlT, Ls, t, 1.0f, 0.0f);  // logits
  __syncthreads();
  int lane = t & 63, wv = t >> 6;
  for (int r = wv; r < 64; r += 4) {
    float v = Ls[r * 64 + lane];
    float mx = v;
#pragma unroll
    for (int o = 32; o > 0; o >>= 1) mx = fmaxf(mx, __shfl_xor(mx, o, 64));
    float e = __expf(v - mx);
    float s = e;
#pragma unroll
    for (int o = 32; o > 0; o >>= 1) s += __shfl_xor(s, o, 64);
    Ls[r * 64 + lane] = e / s;
  }
  __syncthreads();
  {
    const int tx = t & 15, ty = t >> 4;
    const int r0 = ty * 4, c0 = tx * 4;
    float acc[4][4] = {};
#pragma unroll 8
    for (int k = 0; k < 64; k++) {
      float4 b = *(const float4*)&Zs[k * 64 + c0];
#pragma unroll
      for (int i = 0; i < 4; i++) {
        float a = Ls[(r0 + i) * 64 + k];
        acc[i][0] = fmaf(a, b.x, acc[i][0]);
        acc[i][1] = fmaf(a, b.y, acc[i][1]);
        acc[i][2] = fmaf(a, b.z, acc[i][2]);
        acc[i][3] = fmaf(a, b.w, acc[i][3]);
      }
    }
    int b_ = bh >> 3, h = bh & 7;
#pragma unroll
    for (int i = 0; i < 4; i++) {
      int n = n0 + r0 + i;
      unsigned short* dst = X + ((size_t)(b_ * 4096 + n)) * 512 + h * 64 + c0;
      unsigned short o4[4] = {f2bf(acc[i][0]), f2bf(acc[i][1]),
                              f2bf(acc[i][2]), f2bf(acc[i][3])};
      *(uint2*)dst = *(const uint2*)o4;
    }
  }
}

// ---------------------------------------------------------------------------
// Kernel H: out = X @ proj_w^T + proj_b, fp32 OUTPUT. Grid (8, 256).
// ---------------------------------------------------------------------------
__global__ __launch_bounds__(256) void proj_gemm(
    const unsigned short* __restrict__ X, const unsigned short* __restrict__ w,
    const float* __restrict__ bias, float* __restrict__ out) {
  __shared__ float As[64][36];
  __shared__ float Bs[64][36];
  const int t = threadIdx.x;
  const int tx = t & 15, ty = t >> 4;
  const int i0 = blockIdx.y * 64, j0 = blockIdx.x * 64;
  const int lr = t >> 2, lk = (t & 3) * 8;
  float acc[4][4] = {};
  for (int k0 = 0; k0 < 512; k0 += 32) {
    uint4 av = *(const uint4*)(X + (size_t)(i0 + lr) * 512 + k0 + lk);
    uint4 bv = *(const uint4*)(w + (size_t)(j0 + lr) * 512 + k0 + lk);
    const unsigned short* aa = (const unsigned short*)&av;
    const unsigned short* bb = (const unsigned short*)&bv;
    *(float4*)&As[lr][lk] =
        make_float4(bf2f(aa[0]), bf2f(aa[1]), bf2f(aa[2]), bf2f(aa[3]));
    *(float4*)&As[lr][lk + 4] =
        make_float4(bf2f(aa[4]), bf2f(aa[5]), bf2f(aa[6]), bf2f(aa[7]));
    *(float4*)&Bs[lr][lk] =
        make_float4(bf2f(bb[0]), bf2f(bb[1]), bf2f(bb[2]), bf2f(bb[3]));
    *(float4*)&Bs[lr][lk + 4] =
        make_float4(bf2f(bb[4]), bf2f(bb[5]), bf2f(bb[6]), bf2f(bb[7]));
    __syncthreads();
#pragma unroll
    for (int k4 = 0; k4 < 32; k4 += 4) {
      float4 bq[4];
#pragma unroll
      for (int j = 0; j < 4; j++) bq[j] = *(const float4*)&Bs[tx + 16 * j][k4];
#pragma unroll
      for (int i = 0; i < 4; i++) {
        float4 aq = *(const float4*)&As[ty * 4 + i][k4];
#pragma unroll
        for (int j = 0; j < 4; j++) {
          acc[i][j] = fmaf(aq.x, bq[j].x, acc[i][j]);
          acc[i][j] = fmaf(aq.y, bq[j].y, acc[i][j]);
          acc[i][j] = fmaf(aq.z, bq[j].z, acc[i][j]);
          acc[i][j] = fmaf(aq.w, bq[j].w, acc[i][j]);
        }
      }
    }
    __syncthreads();
  }
#pragma unroll
  for (int i = 0; i < 4; i++) {
    int row = i0 + ty * 4 + i;
#pragma unroll
    for (int j = 0; j < 4; j++) {
      int col = j0 + tx + 16 * j;
      out[(size_t)row * 512 + col] = acc[i][j] + bias[col];
    }
  }
}

// ---------------------------------------------------------------------------
extern "C" void kernel_launch(void* const* d_in, const int* in_sizes, int n_in,
                              void* d_out, int out_size, void* d_ws,
                              size_t ws_size, hipStream_t stream) {
  (void)in_sizes; (void)n_in; (void)out_size; (void)ws_size;

  char* w8 = (char*)d_ws;
  unsigned short* cx  = (unsigned short*)(w8 + 0);         // x canon bf16
  unsigned short* cwq = (unsigned short*)(w8 + 16777216);  // qkv_w canon
  unsigned short* cwp = (unsigned short*)(w8 + 18350080);  // proj_w canon
  float*          cbf = (float*)(w8 + 18874368);           // proj_b fp32
  unsigned short* qkv = (unsigned short*)(w8 + 18876416);  // Q,K,V bf16
  unsigned short* X   = (unsigned short*)(w8 + 69208064);  // attn out bf16
  float* Ql = (float*)(w8 + 85985280);
  float* Kl = (float*)(w8 + 86509568);
  float* k2 = (float*)(w8 + 87033856);
  float* W  = (float*)(w8 + 87558144);
  float* Z  = (float*)(w8 + 88082432);
  unsigned int* gstat = (unsigned int*)(w8 + 88606720);  // [cmax, rmax, flag]

  hipMemsetAsync(gstat, 0, 16, stream);
  detect_dtype<<<1, 64, 0, stream>>>((const unsigned short*)d_in[0],
                                     gstat + 2);
  convert_bf16<<<4096, 256, 0, stream>>>(d_in[0], cx, 8388608, gstat + 2);
  convert_bf16<<<384, 256, 0, stream>>>(d_in[1], cwq, 786432, gstat + 2);
  convert_bf16<<<128, 256, 0, stream>>>(d_in[2], cwp, 262144, gstat + 2);
  convert_f32<<<2, 256, 0, stream>>>(d_in[3], cbf, 512, gstat + 2);

  qkv_gemm<<<dim3(24, 256), 256, 0, stream>>>(cx, cwq, qkv);
  pool_kernel<<<512, 256, 0, stream>>>(qkv, Ql, Kl);
  k2_kernel<<<32, 256, 0, stream>>>(Ql, Kl, k2, gstat);
  k3v_kernel<<<2048, 256, 0, stream>>>(Ql, qkv, W);
  ns_kernel<<<32, 256, 0, stream>>>(k2, gstat, W, Z);
  k1x_kernel<<<dim3(32, 64), 256, 0, stream>>>(qkv, Kl, Z, X);
  proj_gemm<<<dim3(8, 256), 256, 0, stream>>>(X, cwp, cbf, (float*)d_out);
}

// Round 4
// 817.411 us; speedup vs baseline: 1.9053x; 1.9053x over previous
//
#include <hip/hip_runtime.h>
#include <hip/hip_bf16.h>
#include <stdint.h>

// Problem constants: B=4, N=4096, C=512, H=8, M=64, HD=64
#define QSZe 8388608ull  // elements per Q/K/V tensor (B*H*N*HD)

__device__ __forceinline__ float bf2f(unsigned short u) {
  return __uint_as_float(((unsigned int)u) << 16);
}
__device__ __forceinline__ unsigned short f2bf(float f) {
  unsigned int u = __float_as_uint(f);
  unsigned int r = (u + 0x7FFFu + ((u >> 16) & 1u)) >> 16;
  return (unsigned short)r;
}

// ---------------------------------------------------------------------------
// Dtype detector (inputs proven fp32 on this harness, but keep robustness).
// ---------------------------------------------------------------------------
__global__ void detect_dtype(const unsigned short* __restrict__ raw,
                             unsigned int* __restrict__ flag) {
  int t = threadIdx.x;  // 64 threads
  int big = 0;
  for (int i = t; i < 256; i += 64) {
    int e = (raw[i] >> 7) & 0xFF;
    if (e >= 0x8F) big = 1;  // |val| >= 2^16 (or NaN/Inf)
  }
  unsigned long long b = __ballot(big);
  if (t == 0) flag[0] = (b != 0ull) ? 1u : 0u;
}

// Canonicalize a tensor to bf16 (round if fp32, copy if already bf16).
__global__ __launch_bounds__(256) void convert_bf16(
    const void* __restrict__ raw, unsigned short* __restrict__ canon, int n,
    const unsigned int* __restrict__ flag) {
  int i8 = (blockIdx.x * 256 + threadIdx.x) * 8;
  if (i8 >= n) return;
  if (flag[0]) {
    const float* f = (const float*)raw;
    float4 a = *(const float4*)(f + i8);
    float4 b = *(const float4*)(f + i8 + 4);
    unsigned short o[8] = {f2bf(a.x), f2bf(a.y), f2bf(a.z), f2bf(a.w),
                           f2bf(b.x), f2bf(b.y), f2bf(b.z), f2bf(b.w)};
    *(uint4*)(canon + i8) = *(const uint4*)o;
  } else {
    *(uint4*)(canon + i8) = *(const uint4*)((const unsigned short*)raw + i8);
  }
}

// Canonicalize a small tensor to fp32 (used for proj_b).
__global__ __launch_bounds__(256) void convert_f32(
    const void* __restrict__ raw, float* __restrict__ canon, int n,
    const unsigned int* __restrict__ flag) {
  int i = blockIdx.x * 256 + threadIdx.x;
  if (i >= n) return;
  canon[i] = flag[0] ? ((const float*)raw)[i]
                     : bf2f(((const unsigned short*)raw)[i]);
}

// ---------------------------------------------------------------------------
// 64x64x64 LDS matmul helper, stride 64.  D = s*(A@B) + dg*I
// ---------------------------------------------------------------------------
__device__ __forceinline__ void mm64(const float* __restrict__ A,
                                     const float* __restrict__ Bm,
                                     float* __restrict__ D,
                                     int t, float s, float dg) {
  const int tx = t & 15, ty = t >> 4;
  const int r0 = ty * 4, c0 = tx * 4;
  float acc[4][4] = {};
#pragma unroll 8
  for (int k = 0; k < 64; k++) {
    float4 b = *(const float4*)&Bm[k * 64 + c0];
    float a[4];
#pragma unroll
    for (int i = 0; i < 4; i++) a[i] = A[(r0 + i) * 64 + k];
#pragma unroll
    for (int i = 0; i < 4; i++) {
      acc[i][0] = fmaf(a[i], b.x, acc[i][0]);
      acc[i][1] = fmaf(a[i], b.y, acc[i][1]);
      acc[i][2] = fmaf(a[i], b.z, acc[i][2]);
      acc[i][3] = fmaf(a[i], b.w, acc[i][3]);
    }
  }
#pragma unroll
  for (int i = 0; i < 4; i++)
#pragma unroll
    for (int j = 0; j < 4; j++)
      D[(r0 + i) * 64 + c0 + j] =
          s * acc[i][j] + (((r0 + i) == (c0 + j)) ? dg : 0.0f);
}

// ---------------------------------------------------------------------------
// Kernel A: qkv = x @ qkv_w^T (bf16 in), write Q,K,V bf16 in [B,H,N,64],
// Q,K scaled by 64^-0.25.  Grid (24, 256), 256 thr.
// ---------------------------------------------------------------------------
__global__ __launch_bounds__(256) void qkv_gemm(
    const unsigned short* __restrict__ x, const unsigned short* __restrict__ w,
    unsigned short* __restrict__ qkv) {
  __shared__ float As[64][36];
  __shared__ float Bs[64][36];
  const int t = threadIdx.x;
  const int tx = t & 15, ty = t >> 4;
  const int i0 = blockIdx.y * 64, j0 = blockIdx.x * 64;
  const int lr = t >> 2, lk = (t & 3) * 8;
  float acc[4][4] = {};
  for (int k0 = 0; k0 < 512; k0 += 32) {
    uint4 av = *(const uint4*)(x + (size_t)(i0 + lr) * 512 + k0 + lk);
    uint4 bv = *(const uint4*)(w + (size_t)(j0 + lr) * 512 + k0 + lk);
    const unsigned short* aa = (const unsigned short*)&av;
    const unsigned short* bb = (const unsigned short*)&bv;
    *(float4*)&As[lr][lk] =
        make_float4(bf2f(aa[0]), bf2f(aa[1]), bf2f(aa[2]), bf2f(aa[3]));
    *(float4*)&As[lr][lk + 4] =
        make_float4(bf2f(aa[4]), bf2f(aa[5]), bf2f(aa[6]), bf2f(aa[7]));
    *(float4*)&Bs[lr][lk] =
        make_float4(bf2f(bb[0]), bf2f(bb[1]), bf2f(bb[2]), bf2f(bb[3]));
    *(float4*)&Bs[lr][lk + 4] =
        make_float4(bf2f(bb[4]), bf2f(bb[5]), bf2f(bb[6]), bf2f(bb[7]));
    __syncthreads();
#pragma unroll
    for (int k4 = 0; k4 < 32; k4 += 4) {
      float4 bq[4];
#pragma unroll
      for (int j = 0; j < 4; j++) bq[j] = *(const float4*)&Bs[tx + 16 * j][k4];
#pragma unroll
      for (int i = 0; i < 4; i++) {
        float4 aq = *(const float4*)&As[ty * 4 + i][k4];
#pragma unroll
        for (int j = 0; j < 4; j++) {
          acc[i][j] = fmaf(aq.x, bq[j].x, acc[i][j]);
          acc[i][j] = fmaf(aq.y, bq[j].y, acc[i][j]);
          acc[i][j] = fmaf(aq.z, bq[j].z, acc[i][j]);
          acc[i][j] = fmaf(aq.w, bq[j].w, acc[i][j]);
        }
      }
    }
    __syncthreads();
  }
  const int which = blockIdx.x >> 3, h = blockIdx.x & 7;
  const float scale = (which < 2) ? 0.3535533905932738f : 1.0f;
#pragma unroll
  for (int i = 0; i < 4; i++) {
    int row = i0 + ty * 4 + i;
    int b_ = row >> 12, n = row & 4095;
    unsigned short* dst = qkv + (size_t)which * QSZe +
                          ((size_t)(b_ * 8 + h) * 4096 + n) * 64;
#pragma unroll
    for (int j = 0; j < 4; j++) dst[tx + 16 * j] = f2bf(acc[i][j] * scale);
  }
}

// ---------------------------------------------------------------------------
// Kernel B: landmark mean-pool over segments of 64 tokens. Grid 512 x 256.
// ---------------------------------------------------------------------------
__global__ __launch_bounds__(256) void pool_kernel(
    const unsigned short* __restrict__ qkv, float* __restrict__ Ql,
    float* __restrict__ Kl) {
  int idx = blockIdx.x * 256 + threadIdx.x;  // [bh][m][d]
  int d = idx & 63;
  int m = (idx >> 6) & 63;
  int bh = idx >> 12;
  const unsigned short* qb =
      qkv + (size_t)bh * 262144 + (size_t)m * 4096 + d;
  const unsigned short* kb = qb + QSZe;
  float sq = 0.f, sk = 0.f;
#pragma unroll 8
  for (int tok = 0; tok < 64; tok++) {
    sq += bf2f(qb[tok * 64]);
    sk += bf2f(kb[tok * 64]);
  }
  Ql[idx] = sq * (1.0f / 64.0f);
  Kl[idx] = sk * (1.0f / 64.0f);
}

// ---------------------------------------------------------------------------
// Kernel C: kernel_2 = softmax(Ql@Kl^T) per (b,h); global max colsum/rowsum
// via atomicMax (positive-float-as-uint).  Grid 32 x 256.
// ---------------------------------------------------------------------------
__global__ __launch_bounds__(256) void k2_kernel(
    const float* __restrict__ Ql, const float* __restrict__ Kl,
    float* __restrict__ k2, unsigned int* __restrict__ gstat) {
  __shared__ float KlT[64 * 64];  // [d][l]
  __shared__ float Ps[64][65];
  int t = threadIdx.x;
  int lane = t & 63, wv = t >> 6;
  int bh = blockIdx.x;
#pragma unroll
  for (int i = 0; i < 16; i++) {
    int idx = i * 256 + t;
    KlT[(idx & 63) * 64 + (idx >> 6)] = Kl[bh * 4096 + idx];
  }
  __syncthreads();
  for (int r = wv * 16; r < wv * 16 + 16; r++) {
    float qv = Ql[(bh * 64 + r) * 64 + lane];
    float acc = 0.f;
#pragma unroll
    for (int k = 0; k < 64; k++) acc += __shfl(qv, k, 64) * KlT[k * 64 + lane];
    float mx = acc;
#pragma unroll
    for (int o = 32; o > 0; o >>= 1) mx = fmaxf(mx, __shfl_xor(mx, o, 64));
    float e = __expf(acc - mx);
    float s = e;
#pragma unroll
    for (int o = 32; o > 0; o >>= 1) s += __shfl_xor(s, o, 64);
    float p = e / s;
    k2[(bh * 64 + r) * 64 + lane] = p;
    Ps[r][lane] = p;
  }
  __syncthreads();
  float val = 0.f;
  if (t < 64) {
    for (int r = 0; r < 64; r++) val += Ps[r][t];  // column sums
  } else if (t < 128) {
    int r = t - 64;
    for (int c = 0; c < 64; c++) val += Ps[r][c];  // row sums
  }
  float mv = val;
#pragma unroll
  for (int o = 32; o > 0; o >>= 1) mv = fmaxf(mv, __shfl_xor(mv, o, 64));
  if (t == 0) atomicMax(gstat + 0, __float_as_uint(mv));
  if (t == 64) atomicMax(gstat + 1, __float_as_uint(mv));
}

// ---------------------------------------------------------------------------
// Kernel E (rewritten): kernel_3 softmax-over-N fused with W = P @ V,
// chunked. Grid (8, 32): block = (512-key slab, bh). 256 threads.
// Logits are tiny (|l| < ~2) so exp() without max-subtraction is exact
// softmax. Partial W (regs, accumulated across 4x128-key sub-chunks) and
// partial rowsums go to Wp/sp; k3_reduce normalizes.
// ---------------------------------------------------------------------------
__global__ __launch_bounds__(256) void k3_partial(
    const float* __restrict__ Ql, const unsigned short* __restrict__ qkv,
    float* __restrict__ Wp, float* __restrict__ sp) {
  __shared__ float Qs[64][65];    // Ql tile (padded: 16-lane A-reads 2-way max)
  __shared__ float Bs[128 * 64];  // K^T [d][j=128] for logits; V [n][d] for PV
  __shared__ float Es[64][129];   // exp(logits), padded
  __shared__ float rs[64];        // rowsum accumulator
  const int t = threadIdx.x;
  const int bh = blockIdx.y;
  const int n_base = blockIdx.x * 512;
  const int tm = t & 15, tj = t >> 4;

#pragma unroll
  for (int i = 0; i < 16; i++) {
    int idx = i * 256 + t;
    Qs[idx >> 6][idx & 63] = Ql[bh * 4096 + idx];
  }
  if (t < 64) rs[t] = 0.f;
  float accW[4][4] = {};  // PV accumulator: rows tm*4+i, cols tj*4+c
  __syncthreads();

  for (int sc = 0; sc < 4; sc++) {
    const int n0 = n_base + sc * 128;
    // stage K^T: Bs[d*128 + j] = K[n0+j][d]
    const unsigned short* Kb =
        qkv + QSZe + (size_t)bh * 262144 + (size_t)n0 * 64;
#pragma unroll
    for (int i = 0; i < 4; i++) {
      int li = i * 256 + t;      // 0..1023
      int j = li >> 3;           // key 0..127
      int d0 = (li & 7) * 8;     // 0..56
      uint4 v = *(const uint4*)(Kb + (size_t)j * 64 + d0);
      const unsigned short* s = (const unsigned short*)&v;
#pragma unroll
      for (int u = 0; u < 8; u++) Bs[(d0 + u) * 128 + j] = bf2f(s[u]);
    }
    __syncthreads();
    // logits + exp: E[m][j] = exp( sum_k Qs[m][k]*Bs[k][j] )
    {
      float acc[4][8] = {};
#pragma unroll 16
      for (int k = 0; k < 64; k++) {
        float4 b0 = *(const float4*)&Bs[k * 128 + tj * 8];
        float4 b1 = *(const float4*)&Bs[k * 128 + tj * 8 + 4];
        float b[8] = {b0.x, b0.y, b0.z, b0.w, b1.x, b1.y, b1.z, b1.w};
#pragma unroll
        for (int i2 = 0; i2 < 4; i2++) {
          float a = Qs[tm * 4 + i2][k];
#pragma unroll
          for (int c = 0; c < 8; c++) acc[i2][c] = fmaf(a, b[c], acc[i2][c]);
        }
      }
#pragma unroll
      for (int i2 = 0; i2 < 4; i2++) {
        float rsum = 0.f;
#pragma unroll
        for (int c = 0; c < 8; c++) {
          float e = __expf(acc[i2][c]);
          Es[tm * 4 + i2][tj * 8 + c] = e;
          rsum += e;
        }
        atomicAdd(&rs[tm * 4 + i2], rsum);
      }
    }
    __syncthreads();
    // stage V: Bs[j*64 + d] = V[n0+j][d]
    const unsigned short* Vb =
        qkv + 2 * QSZe + (size_t)bh * 262144 + (size_t)n0 * 64;
#pragma unroll
    for (int i = 0; i < 4; i++) {
      int li = i * 256 + t;
      int j = li >> 3;
      int d0 = (li & 7) * 8;
      uint4 v = *(const uint4*)(Vb + (size_t)j * 64 + d0);
      const unsigned short* s = (const unsigned short*)&v;
#pragma unroll
      for (int u = 0; u < 8; u++) Bs[j * 64 + d0 + u] = bf2f(s[u]);
    }
    __syncthreads();
    // PV accumulate: accW[i][c] += sum_k Es[tm*4+i][k] * V[k][tj*4+c]
#pragma unroll 8
    for (int k = 0; k < 128; k++) {
      float4 b = *(const float4*)&Bs[k * 64 + tj * 4];
#pragma unroll
      for (int i2 = 0; i2 < 4; i2++) {
        float a = Es[tm * 4 + i2][k];
        accW[i2][0] = fmaf(a, b.x, accW[i2][0]);
        accW[i2][1] = fmaf(a, b.y, accW[i2][1]);
        accW[i2][2] = fmaf(a, b.z, accW[i2][2]);
        accW[i2][3] = fmaf(a, b.w, accW[i2][3]);
      }
    }
    __syncthreads();  // protect Bs/Es before next sub-chunk restages
  }
  float* wpo = Wp + ((size_t)bh * 8 + blockIdx.x) * 4096;
#pragma unroll
  for (int i2 = 0; i2 < 4; i2++) {
    *(float4*)&wpo[(tm * 4 + i2) * 64 + tj * 4] =
        make_float4(accW[i2][0], accW[i2][1], accW[i2][2], accW[i2][3]);
  }
  if (t < 64) sp[(bh * 8 + blockIdx.x) * 64 + t] = rs[t];
}

// W[bh][m][d] = sum_c Wp[bh][c][m][d] / sum_c sp[bh][c][m].  Grid 512 x 256.
__global__ __launch_bounds__(256) void k3_reduce(
    const float* __restrict__ Wp, const float* __restrict__ sp,
    float* __restrict__ W) {
  int idx = blockIdx.x * 256 + threadIdx.x;  // bh*4096 + m*64 + d
  int m = (idx >> 6) & 63, bh = idx >> 12;
  float w = 0.f, s = 0.f;
#pragma unroll
  for (int c = 0; c < 8; c++) {
    w += Wp[((size_t)bh * 8 + c) * 4096 + (idx & 4095)];
    s += sp[(bh * 8 + c) * 64 + m];
  }
  W[idx] = w / s;
}

// ---------------------------------------------------------------------------
// Kernel D: Newton-Schulz pseudo-inverse (6 iters) + Z = inv @ W.
// One block per (b,h). Uses 15I - KV(7I-KV) = 15I - 7*KV + KV^2.
// ---------------------------------------------------------------------------
__global__ __launch_bounds__(256) void ns_kernel(
    const float* __restrict__ k2g, const unsigned int* __restrict__ gstat,
    const float* __restrict__ Wg, float* __restrict__ Z) {
  __shared__ float lds[4 * 4096];
  float* PK = lds;
  float* PV = lds + 4096;
  float* PA = lds + 2 * 4096;
  float* PBf = lds + 3 * 4096;
  int t = threadIdx.x, bh = blockIdx.x;
#pragma unroll
  for (int i = 0; i < 16; i++) {
    int idx = i * 256 + t;
    PK[idx] = k2g[bh * 4096 + idx];
  }
  __syncthreads();
  float scale =
      1.0f / (__uint_as_float(gstat[0]) * __uint_as_float(gstat[1]));
#pragma unroll
  for (int i = 0; i < 16; i++) {
    int idx = i * 256 + t;
    int r = idx >> 6, c = idx & 63;
    PV[r * 64 + c] = PK[c * 64 + r] * scale;  // V0 = K2^T / (cmax*rmax)
  }
  __syncthreads();
  for (int it = 0; it < 6; it++) {
    mm64(PK, PV, PA, t, 1.0f, 0.0f);  // PA = KV
    __syncthreads();
    mm64(PA, PA, PBf, t, 1.0f, 0.0f);  // PBf = KV^2
    __syncthreads();
#pragma unroll
    for (int i = 0; i < 16; i++) {
      int idx = i * 256 + t;
      int r = idx >> 6, c = idx & 63;
      PBf[idx] = ((r == c) ? 15.0f : 0.0f) - 7.0f * PA[idx] + PBf[idx];
    }
    __syncthreads();
    mm64(PA, PBf, PK, t, -1.0f, 13.0f);  // PK = 13I - KV@T2
    __syncthreads();
    mm64(PV, PK, PA, t, 0.25f, 0.0f);  // PA = 0.25 * V@T3
    __syncthreads();
    float* tmp = PV; PV = PA; PA = tmp;
#pragma unroll
    for (int i = 0; i < 16; i++) {
      int idx = i * 256 + t;
      PK[idx] = k2g[bh * 4096 + idx];
    }
    __syncthreads();
  }
#pragma unroll
  for (int i = 0; i < 16; i++) {
    int idx = i * 256 + t;
    PK[idx] = Wg[bh * 4096 + idx];
  }
  __syncthreads();
  mm64(PV, PK, PA, t, 1.0f, 0.0f);  // Z = inv @ W
  __syncthreads();
#pragma unroll
  for (int i = 0; i < 16; i++) {
    int idx = i * 256 + t;
    Z[bh * 4096 + idx] = PA[idx];
  }
}

// ---------------------------------------------------------------------------
// Kernel G: kernel_1 softmax fused with X = P @ Z.  Grid (32, 64).
// Writes X bf16 in [B,N,C].
// ---------------------------------------------------------------------------
__global__ __launch_bounds__(256) void k1x_kernel(
    const unsigned short* __restrict__ qkv, const float* __restrict__ Kl,
    const float* __restrict__ Z, unsigned short* __restrict__ X) {
  __shared__ float lds[16384];
  float* Qs = lds;          // [r][k]
  float* KlT = lds + 4096;  // [k][c]
  float* Ls = lds + 8192;   // [r][c]
  float* Zs = lds + 12288;  // [m][d]
  int t = threadIdx.x;
  int bh = blockIdx.x, n0 = blockIdx.y * 64;
  const unsigned short* Qb = qkv + (size_t)bh * 262144 + (size_t)n0 * 64;
  const float4* Zb4 = (const float4*)(Z + bh * 4096);
  float4* Zs4 = (float4*)Zs;
#pragma unroll
  for (int i = 0; i < 2; i++) {
    int idx8 = (i * 256 + t) * 8;
    uint4 v = *(const uint4*)(Qb + idx8);
    const unsigned short* s = (const unsigned short*)&v;
#pragma unroll
    for (int j = 0; j < 8; j++) Qs[idx8 + j] = bf2f(s[j]);
  }
#pragma unroll
  for (int i = 0; i < 4; i++) Zs4[i * 256 + t] = Zb4[i * 256 + t];
#pragma unroll
  for (int i = 0; i < 16; i++) {
    int idx = i * 256 + t;
    KlT[(idx & 63) * 64 + (idx >> 6)] = Kl[bh * 4096 + idx];
  }
  __syncthreads();
  mm64(Qs, KlT, Ls, t, 1.0f, 0.0f);  // logits
  __syncthreads();
  int lane = t & 63, wv = t >> 6;
  for (int r = wv; r < 64; r += 4) {
    float v = Ls[r * 64 + lane];
    float mx = v;
#pragma unroll
    for (int o = 32; o > 0; o >>= 1) mx = fmaxf(mx, __shfl_xor(mx, o, 64));
    float e = __expf(v - mx);
    float s = e;
#pragma unroll
    for (int o = 32; o > 0; o >>= 1) s += __shfl_xor(s, o, 64);
    Ls[r * 64 + lane] = e / s;
  }
  __syncthreads();
  {
    const int tx = t & 15, ty = t >> 4;
    const int r0 = ty * 4, c0 = tx * 4;
    float acc[4][4] = {};
#pragma unroll 8
    for (int k = 0; k < 64; k++) {
      float4 b = *(const float4*)&Zs[k * 64 + c0];
#pragma unroll
      for (int i = 0; i < 4; i++) {
        float a = Ls[(r0 + i) * 64 + k];
        acc[i][0] = fmaf(a, b.x, acc[i][0]);
        acc[i][1] = fmaf(a, b.y, acc[i][1]);
        acc[i][2] = fmaf(a, b.z, acc[i][2]);
        acc[i][3] = fmaf(a, b.w, acc[i][3]);
      }
    }
    int b_ = bh >> 3, h = bh & 7;
#pragma unroll
    for (int i = 0; i < 4; i++) {
      int n = n0 + r0 + i;
      unsigned short* dst = X + ((size_t)(b_ * 4096 + n)) * 512 + h * 64 + c0;
      unsigned short o4[4] = {f2bf(acc[i][0]), f2bf(acc[i][1]),
                              f2bf(acc[i][2]), f2bf(acc[i][3])};
      *(uint2*)dst = *(const uint2*)o4;
    }
  }
}

// ---------------------------------------------------------------------------
// Kernel H: out = X @ proj_w^T + proj_b, fp32 OUTPUT. Grid (8, 256).
// ---------------------------------------------------------------------------
__global__ __launch_bounds__(256) void proj_gemm(
    const unsigned short* __restrict__ X, const unsigned short* __restrict__ w,
    const float* __restrict__ bias, float* __restrict__ out) {
  __shared__ float As[64][36];
  __shared__ float Bs[64][36];
  const int t = threadIdx.x;
  const int tx = t & 15, ty = t >> 4;
  const int i0 = blockIdx.y * 64, j0 = blockIdx.x * 64;
  const int lr = t >> 2, lk = (t & 3) * 8;
  float acc[4][4] = {};
  for (int k0 = 0; k0 < 512; k0 += 32) {
    uint4 av = *(const uint4*)(X + (size_t)(i0 + lr) * 512 + k0 + lk);
    uint4 bv = *(const uint4*)(w + (size_t)(j0 + lr) * 512 + k0 + lk);
    const unsigned short* aa = (const unsigned short*)&av;
    const unsigned short* bb = (const unsigned short*)&bv;
    *(float4*)&As[lr][lk] =
        make_float4(bf2f(aa[0]), bf2f(aa[1]), bf2f(aa[2]), bf2f(aa[3]));
    *(float4*)&As[lr][lk + 4] =
        make_float4(bf2f(aa[4]), bf2f(aa[5]), bf2f(aa[6]), bf2f(aa[7]));
    *(float4*)&Bs[lr][lk] =
        make_float4(bf2f(bb[0]), bf2f(bb[1]), bf2f(bb[2]), bf2f(bb[3]));
    *(float4*)&Bs[lr][lk + 4] =
        make_float4(bf2f(bb[4]), bf2f(bb[5]), bf2f(bb[6]), bf2f(bb[7]));
    __syncthreads();
#pragma unroll
    for (int k4 = 0; k4 < 32; k4 += 4) {
      float4 bq[4];
#pragma unroll
      for (int j = 0; j < 4; j++) bq[j] = *(const float4*)&Bs[tx + 16 * j][k4];
#pragma unroll
      for (int i = 0; i < 4; i++) {
        float4 aq = *(const float4*)&As[ty * 4 + i][k4];
#pragma unroll
        for (int j = 0; j < 4; j++) {
          acc[i][j] = fmaf(aq.x, bq[j].x, acc[i][j]);
          acc[i][j] = fmaf(aq.y, bq[j].y, acc[i][j]);
          acc[i][j] = fmaf(aq.z, bq[j].z, acc[i][j]);
          acc[i][j] = fmaf(aq.w, bq[j].w, acc[i][j]);
        }
      }
    }
    __syncthreads();
  }
#pragma unroll
  for (int i = 0; i < 4; i++) {
    int row = i0 + ty * 4 + i;
#pragma unroll
    for (int j = 0; j < 4; j++) {
      int col = j0 + tx + 16 * j;
      out[(size_t)row * 512 + col] = acc[i][j] + bias[col];
    }
  }
}

// ---------------------------------------------------------------------------
extern "C" void kernel_launch(void* const* d_in, const int* in_sizes, int n_in,
                              void* d_out, int out_size, void* d_ws,
                              size_t ws_size, hipStream_t stream) {
  (void)in_sizes; (void)n_in; (void)out_size; (void)ws_size;

  char* w8 = (char*)d_ws;
  unsigned short* cx  = (unsigned short*)(w8 + 0);         // x canon bf16
  unsigned short* cwq = (unsigned short*)(w8 + 16777216);  // qkv_w canon
  unsigned short* cwp = (unsigned short*)(w8 + 18350080);  // proj_w canon
  float*          cbf = (float*)(w8 + 18874368);           // proj_b fp32
  unsigned short* qkv = (unsigned short*)(w8 + 18876416);  // Q,K,V bf16
  unsigned short* X   = (unsigned short*)(w8 + 69208064);  // attn out bf16
  float* Ql = (float*)(w8 + 85985280);
  float* Kl = (float*)(w8 + 86509568);
  float* k2 = (float*)(w8 + 87033856);
  float* W  = (float*)(w8 + 87558144);
  float* Z  = (float*)(w8 + 88082432);
  unsigned int* gstat = (unsigned int*)(w8 + 88606720);  // [cmax, rmax, flag]
  float* Wp = (float*)(w8 + 88608768);                   // 32*8*4096*4 B
  float* sp = (float*)(w8 + 92803072);                   // 32*8*64*4 B

  hipMemsetAsync(gstat, 0, 16, stream);
  detect_dtype<<<1, 64, 0, stream>>>((const unsigned short*)d_in[0],
                                     gstat + 2);
  convert_bf16<<<4096, 256, 0, stream>>>(d_in[0], cx, 8388608, gstat + 2);
  convert_bf16<<<384, 256, 0, stream>>>(d_in[1], cwq, 786432, gstat + 2);
  convert_bf16<<<128, 256, 0, stream>>>(d_in[2], cwp, 262144, gstat + 2);
  convert_f32<<<2, 256, 0, stream>>>(d_in[3], cbf, 512, gstat + 2);

  qkv_gemm<<<dim3(24, 256), 256, 0, stream>>>(cx, cwq, qkv);
  pool_kernel<<<512, 256, 0, stream>>>(qkv, Ql, Kl);
  k2_kernel<<<32, 256, 0, stream>>>(Ql, Kl, k2, gstat);
  k3_partial<<<dim3(8, 32), 256, 0, stream>>>(Ql, qkv, Wp, sp);
  k3_reduce<<<512, 256, 0, stream>>>(Wp, sp, W);
  ns_kernel<<<32, 256, 0, stream>>>(k2, gstat, W, Z);
  k1x_kernel<<<dim3(32, 64), 256, 0, stream>>>(qkv, Kl, Z, X);
  proj_gemm<<<dim3(8, 256), 256, 0, stream>>>(X, cwp, cbf, (float*)d_out);
}

// Round 5
// 400.790 us; speedup vs baseline: 3.8858x; 2.0395x over previous
//
#include <hip/hip_runtime.h>
#include <hip/hip_bf16.h>
#include <stdint.h>

// Problem constants: B=4, N=4096, C=512, H=8, M=64, HD=64
#define QSZe 8388608ull  // elements per Q/K/V tensor (B*H*N*HD)

typedef __attribute__((ext_vector_type(8))) short bf16x8;
typedef __attribute__((ext_vector_type(4))) float f32x4;
typedef const __attribute__((address_space(1))) unsigned int* gas1_t;
typedef __attribute__((address_space(3))) unsigned int* las3_t;

__device__ __forceinline__ float bf2f(unsigned short u) {
  return __uint_as_float(((unsigned int)u) << 16);
}
__device__ __forceinline__ unsigned short f2bf(float f) {
  unsigned int u = __float_as_uint(f);
  unsigned int r = (u + 0x7FFFu + ((u >> 16) & 1u)) >> 16;
  return (unsigned short)r;
}
__device__ __forceinline__ void gload_lds16(const void* g, void* l) {
  __builtin_amdgcn_global_load_lds((gas1_t)g, (las3_t)l, 16, 0, 0);
}

// ---------------------------------------------------------------------------
// Dtype detector (inputs proven fp32 on this harness, but keep robustness).
// ---------------------------------------------------------------------------
__global__ void detect_dtype(const unsigned short* __restrict__ raw,
                             unsigned int* __restrict__ flag) {
  int t = threadIdx.x;  // 64 threads
  int big = 0;
  for (int i = t; i < 256; i += 64) {
    int e = (raw[i] >> 7) & 0xFF;
    if (e >= 0x8F) big = 1;  // |val| >= 2^16 (or NaN/Inf)
  }
  unsigned long long b = __ballot(big);
  if (t == 0) flag[0] = (b != 0ull) ? 1u : 0u;
}

// Canonicalize a tensor to bf16 (round if fp32, copy if already bf16).
__global__ __launch_bounds__(256) void convert_bf16(
    const void* __restrict__ raw, unsigned short* __restrict__ canon, int n,
    const unsigned int* __restrict__ flag) {
  int i8 = (blockIdx.x * 256 + threadIdx.x) * 8;
  if (i8 >= n) return;
  if (flag[0]) {
    const float* f = (const float*)raw;
    float4 a = *(const float4*)(f + i8);
    float4 b = *(const float4*)(f + i8 + 4);
    unsigned short o[8] = {f2bf(a.x), f2bf(a.y), f2bf(a.z), f2bf(a.w),
                           f2bf(b.x), f2bf(b.y), f2bf(b.z), f2bf(b.w)};
    *(uint4*)(canon + i8) = *(const uint4*)o;
  } else {
    *(uint4*)(canon + i8) = *(const uint4*)((const unsigned short*)raw + i8);
  }
}

// Canonicalize a small tensor to fp32 (used for proj_b).
__global__ __launch_bounds__(256) void convert_f32(
    const void* __restrict__ raw, float* __restrict__ canon, int n,
    const unsigned int* __restrict__ flag) {
  int i = blockIdx.x * 256 + threadIdx.x;
  if (i >= n) return;
  canon[i] = flag[0] ? ((const float*)raw)[i]
                     : bf2f(((const unsigned short*)raw)[i]);
}

// ---------------------------------------------------------------------------
// 64x64x64 LDS matmul helper, stride 64.  D = s*(A@B) + dg*I
// ---------------------------------------------------------------------------
__device__ __forceinline__ void mm64(const float* __restrict__ A,
                                     const float* __restrict__ Bm,
                                     float* __restrict__ D,
                                     int t, float s, float dg) {
  const int tx = t & 15, ty = t >> 4;
  const int r0 = ty * 4, c0 = tx * 4;
  float acc[4][4] = {};
#pragma unroll 8
  for (int k = 0; k < 64; k++) {
    float4 b = *(const float4*)&Bm[k * 64 + c0];
    float a[4];
#pragma unroll
    for (int i = 0; i < 4; i++) a[i] = A[(r0 + i) * 64 + k];
#pragma unroll
    for (int i = 0; i < 4; i++) {
      acc[i][0] = fmaf(a[i], b.x, acc[i][0]);
      acc[i][1] = fmaf(a[i], b.y, acc[i][1]);
      acc[i][2] = fmaf(a[i], b.z, acc[i][2]);
      acc[i][3] = fmaf(a[i], b.w, acc[i][3]);
    }
  }
#pragma unroll
  for (int i = 0; i < 4; i++)
#pragma unroll
    for (int j = 0; j < 4; j++)
      D[(r0 + i) * 64 + c0 + j] =
          s * acc[i][j] + (((r0 + i) == (c0 + j)) ? dg : 0.0f);
}

// ---------------------------------------------------------------------------
// Kernel A (MFMA): qkv = x @ qkv_w^T, bf16 MFMA 128x128 tile, BK=64.
// Writes Q,K,V bf16 in [B,H,N,64]; Q,K scaled by 64^-0.25.
// Grid (12, 128), 256 thr (4 waves in 2x2; each wave 4x4 16x16 tiles).
// ---------------------------------------------------------------------------
__global__ __launch_bounds__(256) void qkv_gemm_mfma(
    const unsigned short* __restrict__ x, const unsigned short* __restrict__ w,
    unsigned short* __restrict__ qkv) {
  __shared__ unsigned short At[128 * 64];  // [row][k], unpadded (gll layout)
  __shared__ unsigned short Bt[128 * 64];
  const int t = threadIdx.x;
  const int lane = t & 63, wave = t >> 6;
  const int wr = wave >> 1, wc = wave & 1;
  const int i0 = blockIdx.y * 128, j0 = blockIdx.x * 128;
  const int srow = lane >> 3;       // 0..7
  const int skc = (lane & 7) * 8;   // k offset (bf16 elems)
  const int fr = lane & 15, fq = lane >> 4;  // frag row / quad
  f32x4 acc[4][4] = {};

  for (int k0 = 0; k0 < 512; k0 += 64) {
#pragma unroll
    for (int s = 0; s < 4; s++) {
      int inst = wave * 4 + s;     // 0..15
      int row = inst * 8 + srow;   // 0..127
      gload_lds16(x + (size_t)(i0 + row) * 512 + k0 + skc, &At[inst * 512]);
      gload_lds16(w + (size_t)(j0 + row) * 512 + k0 + skc, &Bt[inst * 512]);
    }
    __syncthreads();
#pragma unroll
    for (int kk = 0; kk < 64; kk += 32) {
      bf16x8 af[4], bg[4];
#pragma unroll
      for (int i = 0; i < 4; i++)
        af[i] = *(const bf16x8*)&At[(wr * 64 + i * 16 + fr) * 64 + kk + fq * 8];
#pragma unroll
      for (int j = 0; j < 4; j++)
        bg[j] = *(const bf16x8*)&Bt[(wc * 64 + j * 16 + fr) * 64 + kk + fq * 8];
#pragma unroll
      for (int i = 0; i < 4; i++)
#pragma unroll
        for (int j = 0; j < 4; j++)
          acc[i][j] = __builtin_amdgcn_mfma_f32_16x16x32_bf16(
              af[i], bg[j], acc[i][j], 0, 0, 0);
    }
    __syncthreads();
  }
#pragma unroll
  for (int j = 0; j < 4; j++) {
    int col = j0 + wc * 64 + j * 16 + fr;  // 0..1535
    int which = col >> 9;
    int h = (col >> 6) & 7;
    int d = col & 63;
    float scale = (which < 2) ? 0.3535533905932738f : 1.0f;
#pragma unroll
    for (int i = 0; i < 4; i++) {
      int rbase = i0 + wr * 64 + i * 16 + fq * 4;
#pragma unroll
      for (int r = 0; r < 4; r++) {
        int row = rbase + r;
        int b_ = row >> 12, n = row & 4095;
        qkv[(size_t)which * QSZe + ((size_t)(b_ * 8 + h) * 4096 + n) * 64 + d] =
            f2bf(acc[i][j][r] * scale);
      }
    }
  }
}

// ---------------------------------------------------------------------------
// Kernel B: landmark mean-pool over segments of 64 tokens. Grid 512 x 256.
// ---------------------------------------------------------------------------
__global__ __launch_bounds__(256) void pool_kernel(
    const unsigned short* __restrict__ qkv, float* __restrict__ Ql,
    float* __restrict__ Kl) {
  int idx = blockIdx.x * 256 + threadIdx.x;  // [bh][m][d]
  int d = idx & 63;
  int m = (idx >> 6) & 63;
  int bh = idx >> 12;
  const unsigned short* qb =
      qkv + (size_t)bh * 262144 + (size_t)m * 4096 + d;
  const unsigned short* kb = qb + QSZe;
  float sq = 0.f, sk = 0.f;
#pragma unroll 8
  for (int tok = 0; tok < 64; tok++) {
    sq += bf2f(qb[tok * 64]);
    sk += bf2f(kb[tok * 64]);
  }
  Ql[idx] = sq * (1.0f / 64.0f);
  Kl[idx] = sk * (1.0f / 64.0f);
}

// ---------------------------------------------------------------------------
// Kernel C: kernel_2 = softmax(Ql@Kl^T) per (b,h); global max colsum/rowsum
// via atomicMax (positive-float-as-uint).  Grid 32 x 256.
// ---------------------------------------------------------------------------
__global__ __launch_bounds__(256) void k2_kernel(
    const float* __restrict__ Ql, const float* __restrict__ Kl,
    float* __restrict__ k2, unsigned int* __restrict__ gstat) {
  __shared__ float KlT[64 * 64];  // [d][l]
  __shared__ float Ps[64][65];
  int t = threadIdx.x;
  int lane = t & 63, wv = t >> 6;
  int bh = blockIdx.x;
#pragma unroll
  for (int i = 0; i < 16; i++) {
    int idx = i * 256 + t;
    KlT[(idx & 63) * 64 + (idx >> 6)] = Kl[bh * 4096 + idx];
  }
  __syncthreads();
  for (int r = wv * 16; r < wv * 16 + 16; r++) {
    float qv = Ql[(bh * 64 + r) * 64 + lane];
    float acc = 0.f;
#pragma unroll
    for (int k = 0; k < 64; k++) acc += __shfl(qv, k, 64) * KlT[k * 64 + lane];
    float mx = acc;
#pragma unroll
    for (int o = 32; o > 0; o >>= 1) mx = fmaxf(mx, __shfl_xor(mx, o, 64));
    float e = __expf(acc - mx);
    float s = e;
#pragma unroll
    for (int o = 32; o > 0; o >>= 1) s += __shfl_xor(s, o, 64);
    float p = e / s;
    k2[(bh * 64 + r) * 64 + lane] = p;
    Ps[r][lane] = p;
  }
  __syncthreads();
  float val = 0.f;
  if (t < 64) {
    for (int r = 0; r < 64; r++) val += Ps[r][t];  // column sums
  } else if (t < 128) {
    int r = t - 64;
    for (int c = 0; c < 64; c++) val += Ps[r][c];  // row sums
  }
  float mv = val;
#pragma unroll
  for (int o = 32; o > 0; o >>= 1) mv = fmaxf(mv, __shfl_xor(mv, o, 64));
  if (t == 0) atomicMax(gstat + 0, __float_as_uint(mv));
  if (t == 64) atomicMax(gstat + 1, __float_as_uint(mv));
}

// ---------------------------------------------------------------------------
// Kernel E: kernel_3 softmax-over-N fused with W = P @ V, chunked.
// Grid (8, 32): block = (512-key slab, bh). 256 threads.
// ---------------------------------------------------------------------------
__global__ __launch_bounds__(256) void k3_partial(
    const float* __restrict__ Ql, const unsigned short* __restrict__ qkv,
    float* __restrict__ Wp, float* __restrict__ sp) {
  __shared__ float Qs[64][65];
  __shared__ float Bs[128 * 64];
  __shared__ float Es[64][129];
  __shared__ float rs[64];
  const int t = threadIdx.x;
  const int bh = blockIdx.y;
  const int n_base = blockIdx.x * 512;
  const int tm = t & 15, tj = t >> 4;

#pragma unroll
  for (int i = 0; i < 16; i++) {
    int idx = i * 256 + t;
    Qs[idx >> 6][idx & 63] = Ql[bh * 4096 + idx];
  }
  if (t < 64) rs[t] = 0.f;
  float accW[4][4] = {};
  __syncthreads();

  for (int sc = 0; sc < 4; sc++) {
    const int n0 = n_base + sc * 128;
    const unsigned short* Kb =
        qkv + QSZe + (size_t)bh * 262144 + (size_t)n0 * 64;
#pragma unroll
    for (int i = 0; i < 4; i++) {
      int li = i * 256 + t;
      int j = li >> 3;
      int d0 = (li & 7) * 8;
      uint4 v = *(const uint4*)(Kb + (size_t)j * 64 + d0);
      const unsigned short* s = (const unsigned short*)&v;
#pragma unroll
      for (int u = 0; u < 8; u++) Bs[(d0 + u) * 128 + j] = bf2f(s[u]);
    }
    __syncthreads();
    {
      float acc[4][8] = {};
#pragma unroll 16
      for (int k = 0; k < 64; k++) {
        float4 b0 = *(const float4*)&Bs[k * 128 + tj * 8];
        float4 b1 = *(const float4*)&Bs[k * 128 + tj * 8 + 4];
        float b[8] = {b0.x, b0.y, b0.z, b0.w, b1.x, b1.y, b1.z, b1.w};
#pragma unroll
        for (int i2 = 0; i2 < 4; i2++) {
          float a = Qs[tm * 4 + i2][k];
#pragma unroll
          for (int c = 0; c < 8; c++) acc[i2][c] = fmaf(a, b[c], acc[i2][c]);
        }
      }
#pragma unroll
      for (int i2 = 0; i2 < 4; i2++) {
        float rsum = 0.f;
#pragma unroll
        for (int c = 0; c < 8; c++) {
          float e = __expf(acc[i2][c]);
          Es[tm * 4 + i2][tj * 8 + c] = e;
          rsum += e;
        }
        atomicAdd(&rs[tm * 4 + i2], rsum);
      }
    }
    __syncthreads();
    const unsigned short* Vb =
        qkv + 2 * QSZe + (size_t)bh * 262144 + (size_t)n0 * 64;
#pragma unroll
    for (int i = 0; i < 4; i++) {
      int li = i * 256 + t;
      int j = li >> 3;
      int d0 = (li & 7) * 8;
      uint4 v = *(const uint4*)(Vb + (size_t)j * 64 + d0);
      const unsigned short* s = (const unsigned short*)&v;
#pragma unroll
      for (int u = 0; u < 8; u++) Bs[j * 64 + d0 + u] = bf2f(s[u]);
    }
    __syncthreads();
#pragma unroll 8
    for (int k = 0; k < 128; k++) {
      float4 b = *(const float4*)&Bs[k * 64 + tj * 4];
#pragma unroll
      for (int i2 = 0; i2 < 4; i2++) {
        float a = Es[tm * 4 + i2][k];
        accW[i2][0] = fmaf(a, b.x, accW[i2][0]);
        accW[i2][1] = fmaf(a, b.y, accW[i2][1]);
        accW[i2][2] = fmaf(a, b.z, accW[i2][2]);
        accW[i2][3] = fmaf(a, b.w, accW[i2][3]);
      }
    }
    __syncthreads();
  }
  float* wpo = Wp + ((size_t)bh * 8 + blockIdx.x) * 4096;
#pragma unroll
  for (int i2 = 0; i2 < 4; i2++) {
    *(float4*)&wpo[(tm * 4 + i2) * 64 + tj * 4] =
        make_float4(accW[i2][0], accW[i2][1], accW[i2][2], accW[i2][3]);
  }
  if (t < 64) sp[(bh * 8 + blockIdx.x) * 64 + t] = rs[t];
}

// W[bh][m][d] = sum_c Wp[bh][c][m][d] / sum_c sp[bh][c][m].  Grid 512 x 256.
__global__ __launch_bounds__(256) void k3_reduce(
    const float* __restrict__ Wp, const float* __restrict__ sp,
    float* __restrict__ W) {
  int idx = blockIdx.x * 256 + threadIdx.x;
  int m = (idx >> 6) & 63, bh = idx >> 12;
  float w = 0.f, s = 0.f;
#pragma unroll
  for (int c = 0; c < 8; c++) {
    w += Wp[((size_t)bh * 8 + c) * 4096 + (idx & 4095)];
    s += sp[(bh * 8 + c) * 64 + m];
  }
  W[idx] = w / s;
}

// ---------------------------------------------------------------------------
// Kernel D: Newton-Schulz pseudo-inverse (6 iters) + Z = inv @ W.
// ---------------------------------------------------------------------------
__global__ __launch_bounds__(256) void ns_kernel(
    const float* __restrict__ k2g, const unsigned int* __restrict__ gstat,
    const float* __restrict__ Wg, float* __restrict__ Z) {
  __shared__ float lds[4 * 4096];
  float* PK = lds;
  float* PV = lds + 4096;
  float* PA = lds + 2 * 4096;
  float* PBf = lds + 3 * 4096;
  int t = threadIdx.x, bh = blockIdx.x;
#pragma unroll
  for (int i = 0; i < 16; i++) {
    int idx = i * 256 + t;
    PK[idx] = k2g[bh * 4096 + idx];
  }
  __syncthreads();
  float scale =
      1.0f / (__uint_as_float(gstat[0]) * __uint_as_float(gstat[1]));
#pragma unroll
  for (int i = 0; i < 16; i++) {
    int idx = i * 256 + t;
    int r = idx >> 6, c = idx & 63;
    PV[r * 64 + c] = PK[c * 64 + r] * scale;
  }
  __syncthreads();
  for (int it = 0; it < 6; it++) {
    mm64(PK, PV, PA, t, 1.0f, 0.0f);
    __syncthreads();
    mm64(PA, PA, PBf, t, 1.0f, 0.0f);
    __syncthreads();
#pragma unroll
    for (int i = 0; i < 16; i++) {
      int idx = i * 256 + t;
      int r = idx >> 6, c = idx & 63;
      PBf[idx] = ((r == c) ? 15.0f : 0.0f) - 7.0f * PA[idx] + PBf[idx];
    }
    __syncthreads();
    mm64(PA, PBf, PK, t, -1.0f, 13.0f);
    __syncthreads();
    mm64(PV, PK, PA, t, 0.25f, 0.0f);
    __syncthreads();
    float* tmp = PV; PV = PA; PA = tmp;
#pragma unroll
    for (int i = 0; i < 16; i++) {
      int idx = i * 256 + t;
      PK[idx] = k2g[bh * 4096 + idx];
    }
    __syncthreads();
  }
#pragma unroll
  for (int i = 0; i < 16; i++) {
    int idx = i * 256 + t;
    PK[idx] = Wg[bh * 4096 + idx];
  }
  __syncthreads();
  mm64(PV, PK, PA, t, 1.0f, 0.0f);
  __syncthreads();
#pragma unroll
  for (int i = 0; i < 16; i++) {
    int idx = i * 256 + t;
    Z[bh * 4096 + idx] = PA[idx];
  }
}

// ---------------------------------------------------------------------------
// Kernel G: kernel_1 softmax fused with X = P @ Z.  Grid (32, 64).
// ---------------------------------------------------------------------------
__global__ __launch_bounds__(256) void k1x_kernel(
    const unsigned short* __restrict__ qkv, const float* __restrict__ Kl,
    const float* __restrict__ Z, unsigned short* __restrict__ X) {
  __shared__ float lds[16384];
  float* Qs = lds;
  float* KlT = lds + 4096;
  float* Ls = lds + 8192;
  float* Zs = lds + 12288;
  int t = threadIdx.x;
  int bh = blockIdx.x, n0 = blockIdx.y * 64;
  const unsigned short* Qb = qkv + (size_t)bh * 262144 + (size_t)n0 * 64;
  const float4* Zb4 = (const float4*)(Z + bh * 4096);
  float4* Zs4 = (float4*)Zs;
#pragma unroll
  for (int i = 0; i < 2; i++) {
    int idx8 = (i * 256 + t) * 8;
    uint4 v = *(const uint4*)(Qb + idx8);
    const unsigned short* s = (const unsigned short*)&v;
#pragma unroll
    for (int j = 0; j < 8; j++) Qs[idx8 + j] = bf2f(s[j]);
  }
#pragma unroll
  for (int i = 0; i < 4; i++) Zs4[i * 256 + t] = Zb4[i * 256 + t];
#pragma unroll
  for (int i = 0; i < 16; i++) {
    int idx = i * 256 + t;
    KlT[(idx & 63) * 64 + (idx >> 6)] = Kl[bh * 4096 + idx];
  }
  __syncthreads();
  mm64(Qs, KlT, Ls, t, 1.0f, 0.0f);
  __syncthreads();
  int lane = t & 63, wv = t >> 6;
  for (int r = wv; r < 64; r += 4) {
    float v = Ls[r * 64 + lane];
    float mx = v;
#pragma unroll
    for (int o = 32; o > 0; o >>= 1) mx = fmaxf(mx, __shfl_xor(mx, o, 64));
    float e = __expf(v - mx);
    float s = e;
#pragma unroll
    for (int o = 32; o > 0; o >>= 1) s += __shfl_xor(s, o, 64);
    Ls[r * 64 + lane] = e / s;
  }
  __syncthreads();
  {
    const int tx = t & 15, ty = t >> 4;
    const int r0 = ty * 4, c0 = tx * 4;
    float acc[4][4] = {};
#pragma unroll 8
    for (int k = 0; k < 64; k++) {
      float4 b = *(const float4*)&Zs[k * 64 + c0];
#pragma unroll
      for (int i = 0; i < 4; i++) {
        float a = Ls[(r0 + i) * 64 + k];
        acc[i][0] = fmaf(a, b.x, acc[i][0]);
        acc[i][1] = fmaf(a, b.y, acc[i][1]);
        acc[i][2] = fmaf(a, b.z, acc[i][2]);
        acc[i][3] = fmaf(a, b.w, acc[i][3]);
      }
    }
    int b_ = bh >> 3, h = bh & 7;
#pragma unroll
    for (int i = 0; i < 4; i++) {
      int n = n0 + r0 + i;
      unsigned short* dst = X + ((size_t)(b_ * 4096 + n)) * 512 + h * 64 + c0;
      unsigned short o4[4] = {f2bf(acc[i][0]), f2bf(acc[i][1]),
                              f2bf(acc[i][2]), f2bf(acc[i][3])};
      *(uint2*)dst = *(const uint2*)o4;
    }
  }
}

// ---------------------------------------------------------------------------
// Kernel H (MFMA): out = X @ proj_w^T + proj_b, fp32 OUT. Grid (4, 128).
// ---------------------------------------------------------------------------
__global__ __launch_bounds__(256) void proj_gemm_mfma(
    const unsigned short* __restrict__ X, const unsigned short* __restrict__ w,
    const float* __restrict__ bias, float* __restrict__ out) {
  __shared__ unsigned short At[128 * 64];
  __shared__ unsigned short Bt[128 * 64];
  const int t = threadIdx.x;
  const int lane = t & 63, wave = t >> 6;
  const int wr = wave >> 1, wc = wave & 1;
  const int i0 = blockIdx.y * 128, j0 = blockIdx.x * 128;
  const int srow = lane >> 3;
  const int skc = (lane & 7) * 8;
  const int fr = lane & 15, fq = lane >> 4;
  f32x4 acc[4][4] = {};

  for (int k0 = 0; k0 < 512; k0 += 64) {
#pragma unroll
    for (int s = 0; s < 4; s++) {
      int inst = wave * 4 + s;
      int row = inst * 8 + srow;
      gload_lds16(X + (size_t)(i0 + row) * 512 + k0 + skc, &At[inst * 512]);
      gload_lds16(w + (size_t)(j0 + row) * 512 + k0 + skc, &Bt[inst * 512]);
    }
    __syncthreads();
#pragma unroll
    for (int kk = 0; kk < 64; kk += 32) {
      bf16x8 af[4], bg[4];
#pragma unroll
      for (int i = 0; i < 4; i++)
        af[i] = *(const bf16x8*)&At[(wr * 64 + i * 16 + fr) * 64 + kk + fq * 8];
#pragma unroll
      for (int j = 0; j < 4; j++)
        bg[j] = *(const bf16x8*)&Bt[(wc * 64 + j * 16 + fr) * 64 + kk + fq * 8];
#pragma unroll
      for (int i = 0; i < 4; i++)
#pragma unroll
        for (int j = 0; j < 4; j++)
          acc[i][j] = __builtin_amdgcn_mfma_f32_16x16x32_bf16(
              af[i], bg[j], acc[i][j], 0, 0, 0);
    }
    __syncthreads();
  }
#pragma unroll
  for (int j = 0; j < 4; j++) {
    int col = j0 + wc * 64 + j * 16 + fr;  // 0..511
    float bia = bias[col];
#pragma unroll
    for (int i = 0; i < 4; i++) {
      int rbase = i0 + wr * 64 + i * 16 + fq * 4;
#pragma unroll
      for (int r = 0; r < 4; r++) {
        out[(size_t)(rbase + r) * 512 + col] = acc[i][j][r] + bia;
      }
    }
  }
}

// ---------------------------------------------------------------------------
extern "C" void kernel_launch(void* const* d_in, const int* in_sizes, int n_in,
                              void* d_out, int out_size, void* d_ws,
                              size_t ws_size, hipStream_t stream) {
  (void)in_sizes; (void)n_in; (void)out_size; (void)ws_size;

  char* w8 = (char*)d_ws;
  unsigned short* cx  = (unsigned short*)(w8 + 0);         // x canon bf16
  unsigned short* cwq = (unsigned short*)(w8 + 16777216);  // qkv_w canon
  unsigned short* cwp = (unsigned short*)(w8 + 18350080);  // proj_w canon
  float*          cbf = (float*)(w8 + 18874368);           // proj_b fp32
  unsigned short* qkv = (unsigned short*)(w8 + 18876416);  // Q,K,V bf16
  unsigned short* X   = (unsigned short*)(w8 + 69208064);  // attn out bf16
  float* Ql = (float*)(w8 + 85985280);
  float* Kl = (float*)(w8 + 86509568);
  float* k2 = (float*)(w8 + 87033856);
  float* W  = (float*)(w8 + 87558144);
  float* Z  = (float*)(w8 + 88082432);
  unsigned int* gstat = (unsigned int*)(w8 + 88606720);  // [cmax, rmax, flag]
  float* Wp = (float*)(w8 + 88608768);                   // 32*8*4096*4 B
  float* sp = (float*)(w8 + 92803072);                   // 32*8*64*4 B

  hipMemsetAsync(gstat, 0, 16, stream);
  detect_dtype<<<1, 64, 0, stream>>>((const unsigned short*)d_in[0],
                                     gstat + 2);
  convert_bf16<<<4096, 256, 0, stream>>>(d_in[0], cx, 8388608, gstat + 2);
  convert_bf16<<<384, 256, 0, stream>>>(d_in[1], cwq, 786432, gstat + 2);
  convert_bf16<<<128, 256, 0, stream>>>(d_in[2], cwp, 262144, gstat + 2);
  convert_f32<<<2, 256, 0, stream>>>(d_in[3], cbf, 512, gstat + 2);

  qkv_gemm_mfma<<<dim3(12, 128), 256, 0, stream>>>(cx, cwq, qkv);
  pool_kernel<<<512, 256, 0, stream>>>(qkv, Ql, Kl);
  k2_kernel<<<32, 256, 0, stream>>>(Ql, Kl, k2, gstat);
  k3_partial<<<dim3(8, 32), 256, 0, stream>>>(Ql, qkv, Wp, sp);
  k3_reduce<<<512, 256, 0, stream>>>(Wp, sp, W);
  ns_kernel<<<32, 256, 0, stream>>>(k2, gstat, W, Z);
  k1x_kernel<<<dim3(32, 64), 256, 0, stream>>>(qkv, Kl, Z, X);
  proj_gemm_mfma<<<dim3(4, 128), 256, 0, stream>>>(X, cwp, cbf,
                                                   (float*)d_out);
}

// Round 6
// 341.452 us; speedup vs baseline: 4.5611x; 1.1738x over previous
//
#include <hip/hip_runtime.h>
#include <hip/hip_bf16.h>
#include <stdint.h>

// Problem constants: B=4, N=4096, C=512, H=8, M=64, HD=64
#define QSZe 8388608ull  // elements per Q/K/V tensor (B*H*N*HD)

typedef __attribute__((ext_vector_type(8))) short bf16x8;
typedef __attribute__((ext_vector_type(4))) float f32x4;
typedef const __attribute__((address_space(1))) unsigned int* gas1_t;
typedef __attribute__((address_space(3))) unsigned int* las3_t;

__device__ __forceinline__ float bf2f(unsigned short u) {
  return __uint_as_float(((unsigned int)u) << 16);
}
__device__ __forceinline__ unsigned short f2bf(float f) {
  unsigned int u = __float_as_uint(f);
  unsigned int r = (u + 0x7FFFu + ((u >> 16) & 1u)) >> 16;
  return (unsigned short)r;
}
__device__ __forceinline__ void gload_lds16(const void* g, void* l) {
  __builtin_amdgcn_global_load_lds((gas1_t)g, (las3_t)l, 16, 0, 0);
}

// ---------------------------------------------------------------------------
// Dtype detector (inputs proven fp32 on this harness, but keep robustness).
// ---------------------------------------------------------------------------
__global__ void detect_dtype(const unsigned short* __restrict__ raw,
                             unsigned int* __restrict__ flag) {
  int t = threadIdx.x;  // 64 threads
  int big = 0;
  for (int i = t; i < 256; i += 64) {
    int e = (raw[i] >> 7) & 0xFF;
    if (e >= 0x8F) big = 1;  // |val| >= 2^16 (or NaN/Inf)
  }
  unsigned long long b = __ballot(big);
  if (t == 0) flag[0] = (b != 0ull) ? 1u : 0u;
}

// Canonicalize a tensor to bf16 (round if fp32, copy if already bf16).
__global__ __launch_bounds__(256) void convert_bf16(
    const void* __restrict__ raw, unsigned short* __restrict__ canon, int n,
    const unsigned int* __restrict__ flag) {
  int i8 = (blockIdx.x * 256 + threadIdx.x) * 8;
  if (i8 >= n) return;
  if (flag[0]) {
    const float* f = (const float*)raw;
    float4 a = *(const float4*)(f + i8);
    float4 b = *(const float4*)(f + i8 + 4);
    unsigned short o[8] = {f2bf(a.x), f2bf(a.y), f2bf(a.z), f2bf(a.w),
                           f2bf(b.x), f2bf(b.y), f2bf(b.z), f2bf(b.w)};
    *(uint4*)(canon + i8) = *(const uint4*)o;
  } else {
    *(uint4*)(canon + i8) = *(const uint4*)((const unsigned short*)raw + i8);
  }
}

// Canonicalize a small tensor to fp32 (used for proj_b).
__global__ __launch_bounds__(256) void convert_f32(
    const void* __restrict__ raw, float* __restrict__ canon, int n,
    const unsigned int* __restrict__ flag) {
  int i = blockIdx.x * 256 + threadIdx.x;
  if (i >= n) return;
  canon[i] = flag[0] ? ((const float*)raw)[i]
                     : bf2f(((const unsigned short*)raw)[i]);
}

// ---------------------------------------------------------------------------
// 64x64x64 LDS matmul helper, stride 64.  D = s*(A@B) + dg*I
// ---------------------------------------------------------------------------
__device__ __forceinline__ void mm64(const float* __restrict__ A,
                                     const float* __restrict__ Bm,
                                     float* __restrict__ D,
                                     int t, float s, float dg) {
  const int tx = t & 15, ty = t >> 4;
  const int r0 = ty * 4, c0 = tx * 4;
  float acc[4][4] = {};
#pragma unroll 8
  for (int k = 0; k < 64; k++) {
    float4 b = *(const float4*)&Bm[k * 64 + c0];
    float a[4];
#pragma unroll
    for (int i = 0; i < 4; i++) a[i] = A[(r0 + i) * 64 + k];
#pragma unroll
    for (int i = 0; i < 4; i++) {
      acc[i][0] = fmaf(a[i], b.x, acc[i][0]);
      acc[i][1] = fmaf(a[i], b.y, acc[i][1]);
      acc[i][2] = fmaf(a[i], b.z, acc[i][2]);
      acc[i][3] = fmaf(a[i], b.w, acc[i][3]);
    }
  }
#pragma unroll
  for (int i = 0; i < 4; i++)
#pragma unroll
    for (int j = 0; j < 4; j++)
      D[(r0 + i) * 64 + c0 + j] =
          s * acc[i][j] + (((r0 + i) == (c0 + j)) ? dg : 0.0f);
}

// ---------------------------------------------------------------------------
// Kernel A (MFMA): qkv = x @ qkv_w^T, bf16 MFMA 128x128 tile, BK=64.
// Writes Q,K,V bf16 in [B,H,N,64]; Q,K scaled by 64^-0.25.
// Grid (12, 128), 256 thr.
// ---------------------------------------------------------------------------
__global__ __launch_bounds__(256) void qkv_gemm_mfma(
    const unsigned short* __restrict__ x, const unsigned short* __restrict__ w,
    unsigned short* __restrict__ qkv) {
  __shared__ __align__(16) unsigned short At[128 * 64];
  __shared__ __align__(16) unsigned short Bt[128 * 64];
  const int t = threadIdx.x;
  const int lane = t & 63, wave = t >> 6;
  const int wr = wave >> 1, wc = wave & 1;
  const int i0 = blockIdx.y * 128, j0 = blockIdx.x * 128;
  const int srow = lane >> 3;
  const int skc = (lane & 7) * 8;
  const int fr = lane & 15, fq = lane >> 4;
  f32x4 acc[4][4] = {};

  for (int k0 = 0; k0 < 512; k0 += 64) {
#pragma unroll
    for (int s = 0; s < 4; s++) {
      int inst = wave * 4 + s;
      int row = inst * 8 + srow;
      gload_lds16(x + (size_t)(i0 + row) * 512 + k0 + skc, &At[inst * 512]);
      gload_lds16(w + (size_t)(j0 + row) * 512 + k0 + skc, &Bt[inst * 512]);
    }
    __syncthreads();
#pragma unroll
    for (int kk = 0; kk < 64; kk += 32) {
      bf16x8 af[4], bg[4];
#pragma unroll
      for (int i = 0; i < 4; i++)
        af[i] = *(const bf16x8*)&At[(wr * 64 + i * 16 + fr) * 64 + kk + fq * 8];
#pragma unroll
      for (int j = 0; j < 4; j++)
        bg[j] = *(const bf16x8*)&Bt[(wc * 64 + j * 16 + fr) * 64 + kk + fq * 8];
#pragma unroll
      for (int i = 0; i < 4; i++)
#pragma unroll
        for (int j = 0; j < 4; j++)
          acc[i][j] = __builtin_amdgcn_mfma_f32_16x16x32_bf16(
              af[i], bg[j], acc[i][j], 0, 0, 0);
    }
    __syncthreads();
  }
#pragma unroll
  for (int j = 0; j < 4; j++) {
    int col = j0 + wc * 64 + j * 16 + fr;  // 0..1535
    int which = col >> 9;
    int h = (col >> 6) & 7;
    int d = col & 63;
    float scale = (which < 2) ? 0.3535533905932738f : 1.0f;
#pragma unroll
    for (int i = 0; i < 4; i++) {
      int rbase = i0 + wr * 64 + i * 16 + fq * 4;
#pragma unroll
      for (int r = 0; r < 4; r++) {
        int row = rbase + r;
        int b_ = row >> 12, n = row & 4095;
        qkv[(size_t)which * QSZe + ((size_t)(b_ * 8 + h) * 4096 + n) * 64 + d] =
            f2bf(acc[i][j][r] * scale);
      }
    }
  }
}

// ---------------------------------------------------------------------------
// Kernel B: landmark mean-pool; also emits bf16 Kl copy. Grid 512 x 256.
// ---------------------------------------------------------------------------
__global__ __launch_bounds__(256) void pool_kernel(
    const unsigned short* __restrict__ qkv, float* __restrict__ Ql,
    float* __restrict__ Kl, unsigned short* __restrict__ Klb) {
  int idx = blockIdx.x * 256 + threadIdx.x;  // [bh][m][d]
  int d = idx & 63;
  int m = (idx >> 6) & 63;
  int bh = idx >> 12;
  const unsigned short* qb =
      qkv + (size_t)bh * 262144 + (size_t)m * 4096 + d;
  const unsigned short* kb = qb + QSZe;
  float sq = 0.f, sk = 0.f;
#pragma unroll 8
  for (int tok = 0; tok < 64; tok++) {
    sq += bf2f(qb[tok * 64]);
    sk += bf2f(kb[tok * 64]);
  }
  float kv = sk * (1.0f / 64.0f);
  Ql[idx] = sq * (1.0f / 64.0f);
  Kl[idx] = kv;
  Klb[idx] = f2bf(kv);
}

// ---------------------------------------------------------------------------
// Kernel C: kernel_2 = softmax(Ql@Kl^T) per (b,h); global max colsum/rowsum
// via atomicMax (positive-float-as-uint).  Grid 32 x 256.
// ---------------------------------------------------------------------------
__global__ __launch_bounds__(256) void k2_kernel(
    const float* __restrict__ Ql, const float* __restrict__ Kl,
    float* __restrict__ k2, unsigned int* __restrict__ gstat) {
  __shared__ float KlT[64 * 64];  // [d][l]
  __shared__ float Ps[64][65];
  int t = threadIdx.x;
  int lane = t & 63, wv = t >> 6;
  int bh = blockIdx.x;
#pragma unroll
  for (int i = 0; i < 16; i++) {
    int idx = i * 256 + t;
    KlT[(idx & 63) * 64 + (idx >> 6)] = Kl[bh * 4096 + idx];
  }
  __syncthreads();
  for (int r = wv * 16; r < wv * 16 + 16; r++) {
    float qv = Ql[(bh * 64 + r) * 64 + lane];
    float acc = 0.f;
#pragma unroll
    for (int k = 0; k < 64; k++) acc += __shfl(qv, k, 64) * KlT[k * 64 + lane];
    float mx = acc;
#pragma unroll
    for (int o = 32; o > 0; o >>= 1) mx = fmaxf(mx, __shfl_xor(mx, o, 64));
    float e = __expf(acc - mx);
    float s = e;
#pragma unroll
    for (int o = 32; o > 0; o >>= 1) s += __shfl_xor(s, o, 64);
    float p = e / s;
    k2[(bh * 64 + r) * 64 + lane] = p;
    Ps[r][lane] = p;
  }
  __syncthreads();
  float val = 0.f;
  if (t < 64) {
    for (int r = 0; r < 64; r++) val += Ps[r][t];  // column sums
  } else if (t < 128) {
    int r = t - 64;
    for (int c = 0; c < 64; c++) val += Ps[r][c];  // row sums
  }
  float mv = val;
#pragma unroll
  for (int o = 32; o > 0; o >>= 1) mv = fmaxf(mv, __shfl_xor(mv, o, 64));
  if (t == 0) atomicMax(gstat + 0, __float_as_uint(mv));
  if (t == 64) atomicMax(gstat + 1, __float_as_uint(mv));
}

// ---------------------------------------------------------------------------
// Kernel E: kernel_3 softmax-over-N fused with W = P @ V, chunked.
// Grid (8, 32): block = (512-key slab, bh). 256 threads.
// ---------------------------------------------------------------------------
__global__ __launch_bounds__(256) void k3_partial(
    const float* __restrict__ Ql, const unsigned short* __restrict__ qkv,
    float* __restrict__ Wp, float* __restrict__ sp) {
  __shared__ float Qs[64][65];
  __shared__ float Bs[128 * 64];
  __shared__ float Es[64][129];
  __shared__ float rs[64];
  const int t = threadIdx.x;
  const int bh = blockIdx.y;
  const int n_base = blockIdx.x * 512;
  const int tm = t & 15, tj = t >> 4;

#pragma unroll
  for (int i = 0; i < 16; i++) {
    int idx = i * 256 + t;
    Qs[idx >> 6][idx & 63] = Ql[bh * 4096 + idx];
  }
  if (t < 64) rs[t] = 0.f;
  float accW[4][4] = {};
  __syncthreads();

  for (int sc = 0; sc < 4; sc++) {
    const int n0 = n_base + sc * 128;
    const unsigned short* Kb =
        qkv + QSZe + (size_t)bh * 262144 + (size_t)n0 * 64;
#pragma unroll
    for (int i = 0; i < 4; i++) {
      int li = i * 256 + t;
      int j = li >> 3;
      int d0 = (li & 7) * 8;
      uint4 v = *(const uint4*)(Kb + (size_t)j * 64 + d0);
      const unsigned short* s = (const unsigned short*)&v;
#pragma unroll
      for (int u = 0; u < 8; u++) Bs[(d0 + u) * 128 + j] = bf2f(s[u]);
    }
    __syncthreads();
    {
      float acc[4][8] = {};
#pragma unroll 16
      for (int k = 0; k < 64; k++) {
        float4 b0 = *(const float4*)&Bs[k * 128 + tj * 8];
        float4 b1 = *(const float4*)&Bs[k * 128 + tj * 8 + 4];
        float b[8] = {b0.x, b0.y, b0.z, b0.w, b1.x, b1.y, b1.z, b1.w};
#pragma unroll
        for (int i2 = 0; i2 < 4; i2++) {
          float a = Qs[tm * 4 + i2][k];
#pragma unroll
          for (int c = 0; c < 8; c++) acc[i2][c] = fmaf(a, b[c], acc[i2][c]);
        }
      }
#pragma unroll
      for (int i2 = 0; i2 < 4; i2++) {
        float rsum = 0.f;
#pragma unroll
        for (int c = 0; c < 8; c++) {
          float e = __expf(acc[i2][c]);
          Es[tm * 4 + i2][tj * 8 + c] = e;
          rsum += e;
        }
        atomicAdd(&rs[tm * 4 + i2], rsum);
      }
    }
    __syncthreads();
    const unsigned short* Vb =
        qkv + 2 * QSZe + (size_t)bh * 262144 + (size_t)n0 * 64;
#pragma unroll
    for (int i = 0; i < 4; i++) {
      int li = i * 256 + t;
      int j = li >> 3;
      int d0 = (li & 7) * 8;
      uint4 v = *(const uint4*)(Vb + (size_t)j * 64 + d0);
      const unsigned short* s = (const unsigned short*)&v;
#pragma unroll
      for (int u = 0; u < 8; u++) Bs[j * 64 + d0 + u] = bf2f(s[u]);
    }
    __syncthreads();
#pragma unroll 8
    for (int k = 0; k < 128; k++) {
      float4 b = *(const float4*)&Bs[k * 64 + tj * 4];
#pragma unroll
      for (int i2 = 0; i2 < 4; i2++) {
        float a = Es[tm * 4 + i2][k];
        accW[i2][0] = fmaf(a, b.x, accW[i2][0]);
        accW[i2][1] = fmaf(a, b.y, accW[i2][1]);
        accW[i2][2] = fmaf(a, b.z, accW[i2][2]);
        accW[i2][3] = fmaf(a, b.w, accW[i2][3]);
      }
    }
    __syncthreads();
  }
  float* wpo = Wp + ((size_t)bh * 8 + blockIdx.x) * 4096;
#pragma unroll
  for (int i2 = 0; i2 < 4; i2++) {
    *(float4*)&wpo[(tm * 4 + i2) * 64 + tj * 4] =
        make_float4(accW[i2][0], accW[i2][1], accW[i2][2], accW[i2][3]);
  }
  if (t < 64) sp[(bh * 8 + blockIdx.x) * 64 + t] = rs[t];
}

// W[bh][m][d] = sum_c Wp[bh][c][m][d] / sum_c sp[bh][c][m].  Grid 512 x 256.
__global__ __launch_bounds__(256) void k3_reduce(
    const float* __restrict__ Wp, const float* __restrict__ sp,
    float* __restrict__ W) {
  int idx = blockIdx.x * 256 + threadIdx.x;
  int m = (idx >> 6) & 63, bh = idx >> 12;
  float w = 0.f, s = 0.f;
#pragma unroll
  for (int c = 0; c < 8; c++) {
    w += Wp[((size_t)bh * 8 + c) * 4096 + (idx & 4095)];
    s += sp[(bh * 8 + c) * 64 + m];
  }
  W[idx] = w / s;
}

// ---------------------------------------------------------------------------
// Kernel D: Newton-Schulz pseudo-inverse (6 iters) + Z = inv @ W.
// Emits Z TRANSPOSED as bf16: Ztb[bh][d][m]  (for k1x PV B-fragments).
// ---------------------------------------------------------------------------
__global__ __launch_bounds__(256) void ns_kernel(
    const float* __restrict__ k2g, const unsigned int* __restrict__ gstat,
    const float* __restrict__ Wg, unsigned short* __restrict__ Ztb) {
  __shared__ float lds[4 * 4096];
  float* PK = lds;
  float* PV = lds + 4096;
  float* PA = lds + 2 * 4096;
  float* PBf = lds + 3 * 4096;
  int t = threadIdx.x, bh = blockIdx.x;
#pragma unroll
  for (int i = 0; i < 16; i++) {
    int idx = i * 256 + t;
    PK[idx] = k2g[bh * 4096 + idx];
  }
  __syncthreads();
  float scale =
      1.0f / (__uint_as_float(gstat[0]) * __uint_as_float(gstat[1]));
#pragma unroll
  for (int i = 0; i < 16; i++) {
    int idx = i * 256 + t;
    int r = idx >> 6, c = idx & 63;
    PV[r * 64 + c] = PK[c * 64 + r] * scale;
  }
  __syncthreads();
  for (int it = 0; it < 6; it++) {
    mm64(PK, PV, PA, t, 1.0f, 0.0f);
    __syncthreads();
    mm64(PA, PA, PBf, t, 1.0f, 0.0f);
    __syncthreads();
#pragma unroll
    for (int i = 0; i < 16; i++) {
      int idx = i * 256 + t;
      int r = idx >> 6, c = idx & 63;
      PBf[idx] = ((r == c) ? 15.0f : 0.0f) - 7.0f * PA[idx] + PBf[idx];
    }
    __syncthreads();
    mm64(PA, PBf, PK, t, -1.0f, 13.0f);
    __syncthreads();
    mm64(PV, PK, PA, t, 0.25f, 0.0f);
    __syncthreads();
    float* tmp = PV; PV = PA; PA = tmp;
#pragma unroll
    for (int i = 0; i < 16; i++) {
      int idx = i * 256 + t;
      PK[idx] = k2g[bh * 4096 + idx];
    }
    __syncthreads();
  }
#pragma unroll
  for (int i = 0; i < 16; i++) {
    int idx = i * 256 + t;
    PK[idx] = Wg[bh * 4096 + idx];
  }
  __syncthreads();
  mm64(PV, PK, PA, t, 1.0f, 0.0f);  // PA = Z = inv @ W  [m][d]
  __syncthreads();
#pragma unroll
  for (int i = 0; i < 16; i++) {
    int idx = i * 256 + t;  // = d*64 + m
    Ztb[bh * 4096 + idx] = f2bf(PA[(idx & 63) * 64 + (idx >> 6)]);
  }
}

// ---------------------------------------------------------------------------
// Kernel G (MFMA): kernel_1 softmax fused with X = P @ Z.
// Grid (32 bh, 32 rowtiles), 256 thr; 128 Q-rows per block, 32 per wave.
// QK^T mfma -> exp (no max-shift; |logit|<~1) -> rowsum via shfl_xor ->
// P bf16 to LDS (pad-72) -> PV mfma vs Ztb B-frags. Writes X bf16 [B,N,C].
// ---------------------------------------------------------------------------
__global__ __launch_bounds__(256) void k1x_mfma(
    const unsigned short* __restrict__ qkv,
    const unsigned short* __restrict__ Klb,
    const unsigned short* __restrict__ Ztb, unsigned short* __restrict__ X) {
  __shared__ __align__(16) unsigned short Qt[128 * 64];  // 16 KB
  __shared__ __align__(16) unsigned short Ps[128 * 72];  // 18 KB
  const int t = threadIdx.x;
  const int lane = t & 63, wave = t >> 6;
  const int fr = lane & 15, fq = lane >> 4;
  const int bh = blockIdx.x;
  const int n0 = blockIdx.y * 128;
  const unsigned short* Qb = qkv + (size_t)bh * 262144 + (size_t)n0 * 64;
  const unsigned short* Klp = Klb + bh * 4096;
  const unsigned short* Ztp = Ztb + bh * 4096;

  {
    const int srow = lane >> 3, skc = (lane & 7) * 8;
#pragma unroll
    for (int s = 0; s < 4; s++) {
      int inst = wave * 4 + s;
      gload_lds16(Qb + (size_t)(inst * 8 + srow) * 64 + skc, &Qt[inst * 512]);
    }
  }
  __syncthreads();

  // QK^T: rows wave*32 + i*16, cols (landmarks) j*16
  f32x4 acc[2][4] = {};
#pragma unroll
  for (int kk = 0; kk < 64; kk += 32) {
    bf16x8 af[2], bg[4];
#pragma unroll
    for (int i = 0; i < 2; i++)
      af[i] =
          *(const bf16x8*)&Qt[(wave * 32 + i * 16 + fr) * 64 + kk + fq * 8];
#pragma unroll
    for (int j = 0; j < 4; j++)
      bg[j] = *(const bf16x8*)(Klp + (j * 16 + fr) * 64 + kk + fq * 8);
#pragma unroll
    for (int i = 0; i < 2; i++)
#pragma unroll
      for (int j = 0; j < 4; j++)
        acc[i][j] = __builtin_amdgcn_mfma_f32_16x16x32_bf16(af[i], bg[j],
                                                            acc[i][j], 0, 0, 0);
  }

  // softmax rows: exp, rowsum over 64 cols (4 j-tiles x 16 lanes), P->LDS
#pragma unroll
  for (int i = 0; i < 2; i++) {
    float sr[4] = {0.f, 0.f, 0.f, 0.f};
#pragma unroll
    for (int j = 0; j < 4; j++)
#pragma unroll
      for (int r = 0; r < 4; r++) {
        float e = __expf(acc[i][j][r]);
        acc[i][j][r] = e;
        sr[r] += e;
      }
#pragma unroll
    for (int mask = 1; mask < 16; mask <<= 1)
#pragma unroll
      for (int r = 0; r < 4; r++) sr[r] += __shfl_xor(sr[r], mask, 64);
    float is[4];
#pragma unroll
    for (int r = 0; r < 4; r++) is[r] = 1.0f / sr[r];
#pragma unroll
    for (int j = 0; j < 4; j++)
#pragma unroll
      for (int r = 0; r < 4; r++)
        Ps[(wave * 32 + i * 16 + fq * 4 + r) * 72 + j * 16 + fr] =
            f2bf(acc[i][j][r] * is[r]);
  }
  __syncthreads();

  // PV: X = P @ Z, B-frags from Ztb[d][m] (contiguous in m)
  f32x4 ax[2][4] = {};
#pragma unroll
  for (int kk = 0; kk < 64; kk += 32) {
    bf16x8 ap[2], bz[4];
#pragma unroll
    for (int i = 0; i < 2; i++)
      ap[i] =
          *(const bf16x8*)&Ps[(wave * 32 + i * 16 + fr) * 72 + kk + fq * 8];
#pragma unroll
    for (int j = 0; j < 4; j++)
      bz[j] = *(const bf16x8*)(Ztp + (j * 16 + fr) * 64 + kk + fq * 8);
#pragma unroll
    for (int i = 0; i < 2; i++)
#pragma unroll
      for (int j = 0; j < 4; j++)
        ax[i][j] = __builtin_amdgcn_mfma_f32_16x16x32_bf16(ap[i], bz[j],
                                                           ax[i][j], 0, 0, 0);
  }

  const int b_ = bh >> 3, h = bh & 7;
#pragma unroll
  for (int i = 0; i < 2; i++) {
#pragma unroll
    for (int j = 0; j < 4; j++) {
      int c = h * 64 + j * 16 + fr;
#pragma unroll
      for (int r = 0; r < 4; r++) {
        int n = n0 + wave * 32 + i * 16 + fq * 4 + r;
        X[((size_t)(b_ * 4096 + n)) * 512 + c] = f2bf(ax[i][j][r]);
      }
    }
  }
}

// ---------------------------------------------------------------------------
// Kernel H (MFMA): out = X @ proj_w^T + proj_b, fp32 OUT. Grid (4, 128).
// ---------------------------------------------------------------------------
__global__ __launch_bounds__(256) void proj_gemm_mfma(
    const unsigned short* __restrict__ X, const unsigned short* __restrict__ w,
    const float* __restrict__ bias, float* __restrict__ out) {
  __shared__ __align__(16) unsigned short At[128 * 64];
  __shared__ __align__(16) unsigned short Bt[128 * 64];
  const int t = threadIdx.x;
  const int lane = t & 63, wave = t >> 6;
  const int wr = wave >> 1, wc = wave & 1;
  const int i0 = blockIdx.y * 128, j0 = blockIdx.x * 128;
  const int srow = lane >> 3;
  const int skc = (lane & 7) * 8;
  const int fr = lane & 15, fq = lane >> 4;
  f32x4 acc[4][4] = {};

  for (int k0 = 0; k0 < 512; k0 += 64) {
#pragma unroll
    for (int s = 0; s < 4; s++) {
      int inst = wave * 4 + s;
      int row = inst * 8 + srow;
      gload_lds16(X + (size_t)(i0 + row) * 512 + k0 + skc, &At[inst * 512]);
      gload_lds16(w + (size_t)(j0 + row) * 512 + k0 + skc, &Bt[inst * 512]);
    }
    __syncthreads();
#pragma unroll
    for (int kk = 0; kk < 64; kk += 32) {
      bf16x8 af[4], bg[4];
#pragma unroll
      for (int i = 0; i < 4; i++)
        af[i] = *(const bf16x8*)&At[(wr * 64 + i * 16 + fr) * 64 + kk + fq * 8];
#pragma unroll
      for (int j = 0; j < 4; j++)
        bg[j] = *(const bf16x8*)&Bt[(wc * 64 + j * 16 + fr) * 64 + kk + fq * 8];
#pragma unroll
      for (int i = 0; i < 4; i++)
#pragma unroll
        for (int j = 0; j < 4; j++)
          acc[i][j] = __builtin_amdgcn_mfma_f32_16x16x32_bf16(
              af[i], bg[j], acc[i][j], 0, 0, 0);
    }
    __syncthreads();
  }
#pragma unroll
  for (int j = 0; j < 4; j++) {
    int col = j0 + wc * 64 + j * 16 + fr;  // 0..511
    float bia = bias[col];
#pragma unroll
    for (int i = 0; i < 4; i++) {
      int rbase = i0 + wr * 64 + i * 16 + fq * 4;
#pragma unroll
      for (int r = 0; r < 4; r++) {
        out[(size_t)(rbase + r) * 512 + col] = acc[i][j][r] + bia;
      }
    }
  }
}

// ---------------------------------------------------------------------------
extern "C" void kernel_launch(void* const* d_in, const int* in_sizes, int n_in,
                              void* d_out, int out_size, void* d_ws,
                              size_t ws_size, hipStream_t stream) {
  (void)in_sizes; (void)n_in; (void)out_size; (void)ws_size;

  char* w8 = (char*)d_ws;
  unsigned short* cx  = (unsigned short*)(w8 + 0);         // x canon bf16
  unsigned short* cwq = (unsigned short*)(w8 + 16777216);  // qkv_w canon
  unsigned short* cwp = (unsigned short*)(w8 + 18350080);  // proj_w canon
  float*          cbf = (float*)(w8 + 18874368);           // proj_b fp32
  unsigned short* qkv = (unsigned short*)(w8 + 18876416);  // Q,K,V bf16
  unsigned short* X   = (unsigned short*)(w8 + 69208064);  // attn out bf16
  float* Ql = (float*)(w8 + 85985280);
  float* Kl = (float*)(w8 + 86509568);
  float* k2 = (float*)(w8 + 87033856);
  float* W  = (float*)(w8 + 87558144);
  unsigned short* Ztb = (unsigned short*)(w8 + 88082432);  // Z^T bf16 [bh][d][m]
  unsigned int* gstat = (unsigned int*)(w8 + 88606720);  // [cmax, rmax, flag]
  float* Wp = (float*)(w8 + 88608768);                   // 32*8*4096*4 B
  float* sp = (float*)(w8 + 92803072);                   // 32*8*64*4 B
  unsigned short* Klb = (unsigned short*)(w8 + 92868608); // Kl bf16

  hipMemsetAsync(gstat, 0, 16, stream);
  detect_dtype<<<1, 64, 0, stream>>>((const unsigned short*)d_in[0],
                                     gstat + 2);
  convert_bf16<<<4096, 256, 0, stream>>>(d_in[0], cx, 8388608, gstat + 2);
  convert_bf16<<<384, 256, 0, stream>>>(d_in[1], cwq, 786432, gstat + 2);
  convert_bf16<<<128, 256, 0, stream>>>(d_in[2], cwp, 262144, gstat + 2);
  convert_f32<<<2, 256, 0, stream>>>(d_in[3], cbf, 512, gstat + 2);

  qkv_gemm_mfma<<<dim3(12, 128), 256, 0, stream>>>(cx, cwq, qkv);
  pool_kernel<<<512, 256, 0, stream>>>(qkv, Ql, Kl, Klb);
  k2_kernel<<<32, 256, 0, stream>>>(Ql, Kl, k2, gstat);
  k3_partial<<<dim3(8, 32), 256, 0, stream>>>(Ql, qkv, Wp, sp);
  k3_reduce<<<512, 256, 0, stream>>>(Wp, sp, W);
  ns_kernel<<<32, 256, 0, stream>>>(k2, gstat, W, Ztb);
  k1x_mfma<<<dim3(32, 32), 256, 0, stream>>>(qkv, Klb, Ztb, X);
  proj_gemm_mfma<<<dim3(4, 128), 256, 0, stream>>>(X, cwp, cbf,
                                                   (float*)d_out);
}

// Round 7
// 295.361 us; speedup vs baseline: 5.2728x; 1.1561x over previous
//
#include <hip/hip_runtime.h>
#include <hip/hip_bf16.h>
#include <stdint.h>

// Problem constants: B=4, N=4096, C=512, H=8, M=64, HD=64
#define QSZe 8388608ull  // elements per Q/K/V tensor (B*H*N*HD)

typedef __attribute__((ext_vector_type(8))) short bf16x8;
typedef __attribute__((ext_vector_type(4))) float f32x4;
typedef const __attribute__((address_space(1))) unsigned int* gas1_t;
typedef __attribute__((address_space(3))) unsigned int* las3_t;

__device__ __forceinline__ float bf2f(unsigned short u) {
  return __uint_as_float(((unsigned int)u) << 16);
}
__device__ __forceinline__ unsigned short f2bf(float f) {
  unsigned int u = __float_as_uint(f);
  unsigned int r = (u + 0x7FFFu + ((u >> 16) & 1u)) >> 16;
  return (unsigned short)r;
}
__device__ __forceinline__ void gload_lds16(const void* g, void* l) {
  __builtin_amdgcn_global_load_lds((gas1_t)g, (las3_t)l, 16, 0, 0);
}

// ---------------------------------------------------------------------------
// Dtype detector (inputs proven fp32 on this harness, but keep robustness).
// ---------------------------------------------------------------------------
__global__ void detect_dtype(const unsigned short* __restrict__ raw,
                             unsigned int* __restrict__ flag) {
  int t = threadIdx.x;  // 64 threads
  int big = 0;
  for (int i = t; i < 256; i += 64) {
    int e = (raw[i] >> 7) & 0xFF;
    if (e >= 0x8F) big = 1;  // |val| >= 2^16 (or NaN/Inf)
  }
  unsigned long long b = __ballot(big);
  if (t == 0) flag[0] = (b != 0ull) ? 1u : 0u;
}

// Canonicalize a tensor to bf16 (round if fp32, copy if already bf16).
__global__ __launch_bounds__(256) void convert_bf16(
    const void* __restrict__ raw, unsigned short* __restrict__ canon, int n,
    const unsigned int* __restrict__ flag) {
  int i8 = (blockIdx.x * 256 + threadIdx.x) * 8;
  if (i8 >= n) return;
  if (flag[0]) {
    const float* f = (const float*)raw;
    float4 a = *(const float4*)(f + i8);
    float4 b = *(const float4*)(f + i8 + 4);
    unsigned short o[8] = {f2bf(a.x), f2bf(a.y), f2bf(a.z), f2bf(a.w),
                           f2bf(b.x), f2bf(b.y), f2bf(b.z), f2bf(b.w)};
    *(uint4*)(canon + i8) = *(const uint4*)o;
  } else {
    *(uint4*)(canon + i8) = *(const uint4*)((const unsigned short*)raw + i8);
  }
}

// Canonicalize a small tensor to fp32 (used for proj_b).
__global__ __launch_bounds__(256) void convert_f32(
    const void* __restrict__ raw, float* __restrict__ canon, int n,
    const unsigned int* __restrict__ flag) {
  int i = blockIdx.x * 256 + threadIdx.x;
  if (i >= n) return;
  canon[i] = flag[0] ? ((const float*)raw)[i]
                     : bf2f(((const unsigned short*)raw)[i]);
}

// ---------------------------------------------------------------------------
// bf16 MFMA 64x64x64 helper for ns_kernel.
// C = s*(A@B) + dg*I + a7*Aelt ; A_R row-major bf16, B_T = B col-major bf16.
// 4 waves; wave w computes rows [w*16, w*16+16). Optional outputs: out_R
// (row-major) and out_T (col-major), bf16 LDS. Internal sync separates all
// operand reads from writes (out may alias an operand). Caller syncs after.
// ---------------------------------------------------------------------------
__device__ __forceinline__ void mmB(const unsigned short* A_R,
                                    const unsigned short* B_T,
                                    unsigned short* out_R,
                                    unsigned short* out_T, int wave, int lane,
                                    float s, float dg, float a7,
                                    const unsigned short* Aelt) {
  const int fr = lane & 15, fq = lane >> 4;
  bf16x8 af0 = *(const bf16x8*)&A_R[(wave * 16 + fr) * 64 + fq * 8];
  bf16x8 af1 = *(const bf16x8*)&A_R[(wave * 16 + fr) * 64 + 32 + fq * 8];
  f32x4 acc[4] = {};
#pragma unroll
  for (int j = 0; j < 4; j++) {
    bf16x8 b0 = *(const bf16x8*)&B_T[(j * 16 + fr) * 64 + fq * 8];
    bf16x8 b1 = *(const bf16x8*)&B_T[(j * 16 + fr) * 64 + 32 + fq * 8];
    acc[j] = __builtin_amdgcn_mfma_f32_16x16x32_bf16(af0, b0, acc[j], 0, 0, 0);
    acc[j] = __builtin_amdgcn_mfma_f32_16x16x32_bf16(af1, b1, acc[j], 0, 0, 0);
  }
  float ael[4][4];
  if (Aelt) {
#pragma unroll
    for (int j = 0; j < 4; j++)
#pragma unroll
      for (int r = 0; r < 4; r++)
        ael[j][r] = bf2f(Aelt[(wave * 16 + fq * 4 + r) * 64 + j * 16 + fr]);
  }
  __syncthreads();  // all reads complete before any write
#pragma unroll
  for (int j = 0; j < 4; j++) {
    int col = j * 16 + fr;
    unsigned short pack[4];
#pragma unroll
    for (int r = 0; r < 4; r++) {
      int row = wave * 16 + fq * 4 + r;
      float v = s * acc[j][r] + ((row == col) ? dg : 0.0f);
      if (Aelt) v += a7 * ael[j][r];
      unsigned short bv = f2bf(v);
      if (out_R) out_R[row * 64 + col] = bv;
      pack[r] = bv;
    }
    if (out_T)
      *(uint2*)&out_T[col * 64 + wave * 16 + fq * 4] = *(const uint2*)pack;
  }
}

// ---------------------------------------------------------------------------
// Kernel A (MFMA): qkv = x @ qkv_w^T, bf16 MFMA 128x128 tile, BK=64.
// Writes Q,K,V bf16 in [B,H,N,64]; Q,K scaled by 64^-0.25.
// Grid (12, 128), 256 thr.
// ---------------------------------------------------------------------------
__global__ __launch_bounds__(256) void qkv_gemm_mfma(
    const unsigned short* __restrict__ x, const unsigned short* __restrict__ w,
    unsigned short* __restrict__ qkv) {
  __shared__ __align__(16) unsigned short At[128 * 64];
  __shared__ __align__(16) unsigned short Bt[128 * 64];
  const int t = threadIdx.x;
  const int lane = t & 63, wave = t >> 6;
  const int wr = wave >> 1, wc = wave & 1;
  const int i0 = blockIdx.y * 128, j0 = blockIdx.x * 128;
  const int srow = lane >> 3;
  const int skc = (lane & 7) * 8;
  const int fr = lane & 15, fq = lane >> 4;
  f32x4 acc[4][4] = {};

  for (int k0 = 0; k0 < 512; k0 += 64) {
#pragma unroll
    for (int s = 0; s < 4; s++) {
      int inst = wave * 4 + s;
      int row = inst * 8 + srow;
      gload_lds16(x + (size_t)(i0 + row) * 512 + k0 + skc, &At[inst * 512]);
      gload_lds16(w + (size_t)(j0 + row) * 512 + k0 + skc, &Bt[inst * 512]);
    }
    __syncthreads();
#pragma unroll
    for (int kk = 0; kk < 64; kk += 32) {
      bf16x8 af[4], bg[4];
#pragma unroll
      for (int i = 0; i < 4; i++)
        af[i] = *(const bf16x8*)&At[(wr * 64 + i * 16 + fr) * 64 + kk + fq * 8];
#pragma unroll
      for (int j = 0; j < 4; j++)
        bg[j] = *(const bf16x8*)&Bt[(wc * 64 + j * 16 + fr) * 64 + kk + fq * 8];
#pragma unroll
      for (int i = 0; i < 4; i++)
#pragma unroll
        for (int j = 0; j < 4; j++)
          acc[i][j] = __builtin_amdgcn_mfma_f32_16x16x32_bf16(
              af[i], bg[j], acc[i][j], 0, 0, 0);
    }
    __syncthreads();
  }
#pragma unroll
  for (int j = 0; j < 4; j++) {
    int col = j0 + wc * 64 + j * 16 + fr;  // 0..1535
    int which = col >> 9;
    int h = (col >> 6) & 7;
    int d = col & 63;
    float scale = (which < 2) ? 0.3535533905932738f : 1.0f;
#pragma unroll
    for (int i = 0; i < 4; i++) {
      int rbase = i0 + wr * 64 + i * 16 + fq * 4;
#pragma unroll
      for (int r = 0; r < 4; r++) {
        int row = rbase + r;
        int b_ = row >> 12, n = row & 4095;
        qkv[(size_t)which * QSZe + ((size_t)(b_ * 8 + h) * 4096 + n) * 64 + d] =
            f2bf(acc[i][j][r] * scale);
      }
    }
  }
}

// ---------------------------------------------------------------------------
// Kernel B: landmark mean-pool; also emits bf16 Kl copy. Grid 512 x 256.
// ---------------------------------------------------------------------------
__global__ __launch_bounds__(256) void pool_kernel(
    const unsigned short* __restrict__ qkv, float* __restrict__ Ql,
    float* __restrict__ Kl, unsigned short* __restrict__ Klb) {
  int idx = blockIdx.x * 256 + threadIdx.x;  // [bh][m][d]
  int d = idx & 63;
  int m = (idx >> 6) & 63;
  int bh = idx >> 12;
  const unsigned short* qb =
      qkv + (size_t)bh * 262144 + (size_t)m * 4096 + d;
  const unsigned short* kb = qb + QSZe;
  float sq = 0.f, sk = 0.f;
#pragma unroll 8
  for (int tok = 0; tok < 64; tok++) {
    sq += bf2f(qb[tok * 64]);
    sk += bf2f(kb[tok * 64]);
  }
  float kv = sk * (1.0f / 64.0f);
  Ql[idx] = sq * (1.0f / 64.0f);
  Kl[idx] = kv;
  Klb[idx] = f2bf(kv);
}

// ---------------------------------------------------------------------------
// Kernel C: kernel_2 = softmax(Ql@Kl^T) per (b,h); global max colsum/rowsum
// via atomicMax (positive-float-as-uint).  Grid 32 x 256.
// ---------------------------------------------------------------------------
__global__ __launch_bounds__(256) void k2_kernel(
    const float* __restrict__ Ql, const float* __restrict__ Kl,
    float* __restrict__ k2, unsigned int* __restrict__ gstat) {
  __shared__ float KlT[64 * 64];  // [d][l]
  __shared__ float Ps[64][65];
  int t = threadIdx.x;
  int lane = t & 63, wv = t >> 6;
  int bh = blockIdx.x;
#pragma unroll
  for (int i = 0; i < 16; i++) {
    int idx = i * 256 + t;
    KlT[(idx & 63) * 64 + (idx >> 6)] = Kl[bh * 4096 + idx];
  }
  __syncthreads();
  for (int r = wv * 16; r < wv * 16 + 16; r++) {
    float qv = Ql[(bh * 64 + r) * 64 + lane];
    float acc = 0.f;
#pragma unroll
    for (int k = 0; k < 64; k++) acc += __shfl(qv, k, 64) * KlT[k * 64 + lane];
    float mx = acc;
#pragma unroll
    for (int o = 32; o > 0; o >>= 1) mx = fmaxf(mx, __shfl_xor(mx, o, 64));
    float e = __expf(acc - mx);
    float s = e;
#pragma unroll
    for (int o = 32; o > 0; o >>= 1) s += __shfl_xor(s, o, 64);
    float p = e / s;
    k2[(bh * 64 + r) * 64 + lane] = p;
    Ps[r][lane] = p;
  }
  __syncthreads();
  float val = 0.f;
  if (t < 64) {
    for (int r = 0; r < 64; r++) val += Ps[r][t];  // column sums
  } else if (t < 128) {
    int r = t - 64;
    for (int c = 0; c < 64; c++) val += Ps[r][c];  // row sums
  }
  float mv = val;
#pragma unroll
  for (int o = 32; o > 0; o >>= 1) mv = fmaxf(mv, __shfl_xor(mv, o, 64));
  if (t == 0) atomicMax(gstat + 0, __float_as_uint(mv));
  if (t == 64) atomicMax(gstat + 1, __float_as_uint(mv));
}

// ---------------------------------------------------------------------------
// Kernel E: kernel_3 softmax-over-N fused with W = P @ V, chunked.
// Grid (8, 32): block = (512-key slab, bh). 256 threads.
// ---------------------------------------------------------------------------
__global__ __launch_bounds__(256) void k3_partial(
    const float* __restrict__ Ql, const unsigned short* __restrict__ qkv,
    float* __restrict__ Wp, float* __restrict__ sp) {
  __shared__ float Qs[64][65];
  __shared__ float Bs[128 * 64];
  __shared__ float Es[64][129];
  __shared__ float rs[64];
  const int t = threadIdx.x;
  const int bh = blockIdx.y;
  const int n_base = blockIdx.x * 512;
  const int tm = t & 15, tj = t >> 4;

#pragma unroll
  for (int i = 0; i < 16; i++) {
    int idx = i * 256 + t;
    Qs[idx >> 6][idx & 63] = Ql[bh * 4096 + idx];
  }
  if (t < 64) rs[t] = 0.f;
  float accW[4][4] = {};
  __syncthreads();

  for (int sc = 0; sc < 4; sc++) {
    const int n0 = n_base + sc * 128;
    const unsigned short* Kb =
        qkv + QSZe + (size_t)bh * 262144 + (size_t)n0 * 64;
#pragma unroll
    for (int i = 0; i < 4; i++) {
      int li = i * 256 + t;
      int j = li >> 3;
      int d0 = (li & 7) * 8;
      uint4 v = *(const uint4*)(Kb + (size_t)j * 64 + d0);
      const unsigned short* s = (const unsigned short*)&v;
#pragma unroll
      for (int u = 0; u < 8; u++) Bs[(d0 + u) * 128 + j] = bf2f(s[u]);
    }
    __syncthreads();
    {
      float acc[4][8] = {};
#pragma unroll 16
      for (int k = 0; k < 64; k++) {
        float4 b0 = *(const float4*)&Bs[k * 128 + tj * 8];
        float4 b1 = *(const float4*)&Bs[k * 128 + tj * 8 + 4];
        float b[8] = {b0.x, b0.y, b0.z, b0.w, b1.x, b1.y, b1.z, b1.w};
#pragma unroll
        for (int i2 = 0; i2 < 4; i2++) {
          float a = Qs[tm * 4 + i2][k];
#pragma unroll
          for (int c = 0; c < 8; c++) acc[i2][c] = fmaf(a, b[c], acc[i2][c]);
        }
      }
#pragma unroll
      for (int i2 = 0; i2 < 4; i2++) {
        float rsum = 0.f;
#pragma unroll
        for (int c = 0; c < 8; c++) {
          float e = __expf(acc[i2][c]);
          Es[tm * 4 + i2][tj * 8 + c] = e;
          rsum += e;
        }
        atomicAdd(&rs[tm * 4 + i2], rsum);
      }
    }
    __syncthreads();
    const unsigned short* Vb =
        qkv + 2 * QSZe + (size_t)bh * 262144 + (size_t)n0 * 64;
#pragma unroll
    for (int i = 0; i < 4; i++) {
      int li = i * 256 + t;
      int j = li >> 3;
      int d0 = (li & 7) * 8;
      uint4 v = *(const uint4*)(Vb + (size_t)j * 64 + d0);
      const unsigned short* s = (const unsigned short*)&v;
#pragma unroll
      for (int u = 0; u < 8; u++) Bs[j * 64 + d0 + u] = bf2f(s[u]);
    }
    __syncthreads();
#pragma unroll 8
    for (int k = 0; k < 128; k++) {
      float4 b = *(const float4*)&Bs[k * 64 + tj * 4];
#pragma unroll
      for (int i2 = 0; i2 < 4; i2++) {
        float a = Es[tm * 4 + i2][k];
        accW[i2][0] = fmaf(a, b.x, accW[i2][0]);
        accW[i2][1] = fmaf(a, b.y, accW[i2][1]);
        accW[i2][2] = fmaf(a, b.z, accW[i2][2]);
        accW[i2][3] = fmaf(a, b.w, accW[i2][3]);
      }
    }
    __syncthreads();
  }
  float* wpo = Wp + ((size_t)bh * 8 + blockIdx.x) * 4096;
#pragma unroll
  for (int i2 = 0; i2 < 4; i2++) {
    *(float4*)&wpo[(tm * 4 + i2) * 64 + tj * 4] =
        make_float4(accW[i2][0], accW[i2][1], accW[i2][2], accW[i2][3]);
  }
  if (t < 64) sp[(bh * 8 + blockIdx.x) * 64 + t] = rs[t];
}

// W[bh][m][d] = sum_c Wp[bh][c][m][d] / sum_c sp[bh][c][m].  Grid 512 x 256.
__global__ __launch_bounds__(256) void k3_reduce(
    const float* __restrict__ Wp, const float* __restrict__ sp,
    float* __restrict__ W) {
  int idx = blockIdx.x * 256 + threadIdx.x;
  int m = (idx >> 6) & 63, bh = idx >> 12;
  float w = 0.f, s = 0.f;
#pragma unroll
  for (int c = 0; c < 8; c++) {
    w += Wp[((size_t)bh * 8 + c) * 4096 + (idx & 4095)];
    s += sp[(bh * 8 + c) * 64 + m];
  }
  W[idx] = w / s;
}

// ---------------------------------------------------------------------------
// Kernel D (MFMA): Newton-Schulz (6 iters, bf16 MFMA, fp32 accum) +
// Z^T = W^T @ V6^T written bf16 to Ztb[bh][d][m].  One block per (b,h).
// NS is self-correcting, so bf16 intermediates only leave final-iterate
// rounding ~2^-9 (same order as the Ztb bf16 conversion downstream).
// LDS: 8 x (64x64 bf16) = 64 KB: each matrix kept row-major (A-op) and/or
// col-major (B-op) as needed.
// ---------------------------------------------------------------------------
__global__ __launch_bounds__(256) void ns_kernel(
    const float* __restrict__ k2g, const unsigned int* __restrict__ gstat,
    const float* __restrict__ Wg, unsigned short* __restrict__ Ztb) {
  __shared__ __align__(16) unsigned short L[8 * 4096];
  unsigned short* K2R = L;            // K2 row-major
  unsigned short* VR = L + 4096;      // V row-major
  unsigned short* VT = L + 2 * 4096;  // V col-major
  unsigned short* AR = L + 3 * 4096;  // A=K2@V row-major
  unsigned short* AT = L + 4 * 4096;  // A col-major
  unsigned short* T2T = L + 5 * 4096; // 15I-7A+A^2, col-major
  unsigned short* T3T = L + 6 * 4096; // 13I-A@T2, col-major
  unsigned short* WT = L + 7 * 4096;  // W^T row-major [d][m]
  const int t = threadIdx.x, bh = blockIdx.x;
  const int lane = t & 63, wave = t >> 6;
  const float scale =
      1.0f / (__uint_as_float(gstat[0]) * __uint_as_float(gstat[1]));
  const float* k2p = k2g + bh * 4096;
  const float* wp = Wg + bh * 4096;
#pragma unroll
  for (int i = 0; i < 16; i++) {
    int idx = i * 256 + t;
    int r = idx >> 6, c = idx & 63;
    float kv = k2p[idx];
    K2R[idx] = f2bf(kv);
    VT[idx] = f2bf(kv * scale);                 // VT[c'][m] = K2[c'][m]*s
    VR[idx] = f2bf(k2p[c * 64 + r] * scale);    // VR[m][c'] = K2[c'][m]*s
    WT[idx] = f2bf(wp[c * 64 + r]);             // WT[d][m] = W[m][d]
  }
  __syncthreads();
  for (int it = 0; it < 6; it++) {
    mmB(K2R, VT, AR, AT, wave, lane, 1.0f, 0.0f, 0.0f, nullptr);   // A=K2@V
    __syncthreads();
    mmB(AR, AT, nullptr, T2T, wave, lane, 1.0f, 15.0f, -7.0f, AR); // T2
    __syncthreads();
    mmB(AR, T2T, nullptr, T3T, wave, lane, -1.0f, 13.0f, 0.0f, nullptr);
    __syncthreads();
    mmB(VR, T3T, VR, VT, wave, lane, 0.25f, 0.0f, 0.0f, nullptr);  // V'
    __syncthreads();
  }
  // Z^T = W^T @ V^T : A-frags from WT, B-frags from VR (= (V^T) col-major).
  {
    const int fr = lane & 15, fq = lane >> 4;
    bf16x8 af0 = *(const bf16x8*)&WT[(wave * 16 + fr) * 64 + fq * 8];
    bf16x8 af1 = *(const bf16x8*)&WT[(wave * 16 + fr) * 64 + 32 + fq * 8];
    f32x4 acc[4] = {};
#pragma unroll
    for (int j = 0; j < 4; j++) {
      bf16x8 b0 = *(const bf16x8*)&VR[(j * 16 + fr) * 64 + fq * 8];
      bf16x8 b1 = *(const bf16x8*)&VR[(j * 16 + fr) * 64 + 32 + fq * 8];
      acc[j] =
          __builtin_amdgcn_mfma_f32_16x16x32_bf16(af0, b0, acc[j], 0, 0, 0);
      acc[j] =
          __builtin_amdgcn_mfma_f32_16x16x32_bf16(af1, b1, acc[j], 0, 0, 0);
    }
#pragma unroll
    for (int j = 0; j < 4; j++) {
      int m = j * 16 + fr;
#pragma unroll
      for (int r = 0; r < 4; r++) {
        int d = wave * 16 + fq * 4 + r;
        Ztb[bh * 4096 + d * 64 + m] = f2bf(acc[j][r]);
      }
    }
  }
}

// ---------------------------------------------------------------------------
// Kernel G (MFMA): kernel_1 softmax fused with X = P @ Z.
// Grid (32 bh, 32 rowtiles), 256 thr; 128 Q-rows per block, 32 per wave.
// ---------------------------------------------------------------------------
__global__ __launch_bounds__(256) void k1x_mfma(
    const unsigned short* __restrict__ qkv,
    const unsigned short* __restrict__ Klb,
    const unsigned short* __restrict__ Ztb, unsigned short* __restrict__ X) {
  __shared__ __align__(16) unsigned short Qt[128 * 64];  // 16 KB
  __shared__ __align__(16) unsigned short Ps[128 * 72];  // 18 KB
  const int t = threadIdx.x;
  const int lane = t & 63, wave = t >> 6;
  const int fr = lane & 15, fq = lane >> 4;
  const int bh = blockIdx.x;
  const int n0 = blockIdx.y * 128;
  const unsigned short* Qb = qkv + (size_t)bh * 262144 + (size_t)n0 * 64;
  const unsigned short* Klp = Klb + bh * 4096;
  const unsigned short* Ztp = Ztb + bh * 4096;

  {
    const int srow = lane >> 3, skc = (lane & 7) * 8;
#pragma unroll
    for (int s = 0; s < 4; s++) {
      int inst = wave * 4 + s;
      gload_lds16(Qb + (size_t)(inst * 8 + srow) * 64 + skc, &Qt[inst * 512]);
    }
  }
  __syncthreads();

  f32x4 acc[2][4] = {};
#pragma unroll
  for (int kk = 0; kk < 64; kk += 32) {
    bf16x8 af[2], bg[4];
#pragma unroll
    for (int i = 0; i < 2; i++)
      af[i] =
          *(const bf16x8*)&Qt[(wave * 32 + i * 16 + fr) * 64 + kk + fq * 8];
#pragma unroll
    for (int j = 0; j < 4; j++)
      bg[j] = *(const bf16x8*)(Klp + (j * 16 + fr) * 64 + kk + fq * 8);
#pragma unroll
    for (int i = 0; i < 2; i++)
#pragma unroll
      for (int j = 0; j < 4; j++)
        acc[i][j] = __builtin_amdgcn_mfma_f32_16x16x32_bf16(af[i], bg[j],
                                                            acc[i][j], 0, 0, 0);
  }

#pragma unroll
  for (int i = 0; i < 2; i++) {
    float sr[4] = {0.f, 0.f, 0.f, 0.f};
#pragma unroll
    for (int j = 0; j < 4; j++)
#pragma unroll
      for (int r = 0; r < 4; r++) {
        float e = __expf(acc[i][j][r]);
        acc[i][j][r] = e;
        sr[r] += e;
      }
#pragma unroll
    for (int mask = 1; mask < 16; mask <<= 1)
#pragma unroll
      for (int r = 0; r < 4; r++) sr[r] += __shfl_xor(sr[r], mask, 64);
    float is[4];
#pragma unroll
    for (int r = 0; r < 4; r++) is[r] = 1.0f / sr[r];
#pragma unroll
    for (int j = 0; j < 4; j++)
#pragma unroll
      for (int r = 0; r < 4; r++)
        Ps[(wave * 32 + i * 16 + fq * 4 + r) * 72 + j * 16 + fr] =
            f2bf(acc[i][j][r] * is[r]);
  }
  __syncthreads();

  f32x4 ax[2][4] = {};
#pragma unroll
  for (int kk = 0; kk < 64; kk += 32) {
    bf16x8 ap[2], bz[4];
#pragma unroll
    for (int i = 0; i < 2; i++)
      ap[i] =
          *(const bf16x8*)&Ps[(wave * 32 + i * 16 + fr) * 72 + kk + fq * 8];
#pragma unroll
    for (int j = 0; j < 4; j++)
      bz[j] = *(const bf16x8*)(Ztp + (j * 16 + fr) * 64 + kk + fq * 8);
#pragma unroll
    for (int i = 0; i < 2; i++)
#pragma unroll
      for (int j = 0; j < 4; j++)
        ax[i][j] = __builtin_amdgcn_mfma_f32_16x16x32_bf16(ap[i], bz[j],
                                                           ax[i][j], 0, 0, 0);
  }

  const int b_ = bh >> 3, h = bh & 7;
#pragma unroll
  for (int i = 0; i < 2; i++) {
#pragma unroll
    for (int j = 0; j < 4; j++) {
      int c = h * 64 + j * 16 + fr;
#pragma unroll
      for (int r = 0; r < 4; r++) {
        int n = n0 + wave * 32 + i * 16 + fq * 4 + r;
        X[((size_t)(b_ * 4096 + n)) * 512 + c] = f2bf(ax[i][j][r]);
      }
    }
  }
}

// ---------------------------------------------------------------------------
// Kernel H (MFMA): out = X @ proj_w^T + proj_b, fp32 OUT. Grid (4, 128).
// ---------------------------------------------------------------------------
__global__ __launch_bounds__(256) void proj_gemm_mfma(
    const unsigned short* __restrict__ X, const unsigned short* __restrict__ w,
    const float* __restrict__ bias, float* __restrict__ out) {
  __shared__ __align__(16) unsigned short At[128 * 64];
  __shared__ __align__(16) unsigned short Bt[128 * 64];
  const int t = threadIdx.x;
  const int lane = t & 63, wave = t >> 6;
  const int wr = wave >> 1, wc = wave & 1;
  const int i0 = blockIdx.y * 128, j0 = blockIdx.x * 128;
  const int srow = lane >> 3;
  const int skc = (lane & 7) * 8;
  const int fr = lane & 15, fq = lane >> 4;
  f32x4 acc[4][4] = {};

  for (int k0 = 0; k0 < 512; k0 += 64) {
#pragma unroll
    for (int s = 0; s < 4; s++) {
      int inst = wave * 4 + s;
      int row = inst * 8 + srow;
      gload_lds16(X + (size_t)(i0 + row) * 512 + k0 + skc, &At[inst * 512]);
      gload_lds16(w + (size_t)(j0 + row) * 512 + k0 + skc, &Bt[inst * 512]);
    }
    __syncthreads();
#pragma unroll
    for (int kk = 0; kk < 64; kk += 32) {
      bf16x8 af[4], bg[4];
#pragma unroll
      for (int i = 0; i < 4; i++)
        af[i] = *(const bf16x8*)&At[(wr * 64 + i * 16 + fr) * 64 + kk + fq * 8];
#pragma unroll
      for (int j = 0; j < 4; j++)
        bg[j] = *(const bf16x8*)&Bt[(wc * 64 + j * 16 + fr) * 64 + kk + fq * 8];
#pragma unroll
      for (int i = 0; i < 4; i++)
#pragma unroll
        for (int j = 0; j < 4; j++)
          acc[i][j] = __builtin_amdgcn_mfma_f32_16x16x32_bf16(
              af[i], bg[j], acc[i][j], 0, 0, 0);
    }
    __syncthreads();
  }
#pragma unroll
  for (int j = 0; j < 4; j++) {
    int col = j0 + wc * 64 + j * 16 + fr;  // 0..511
    float bia = bias[col];
#pragma unroll
    for (int i = 0; i < 4; i++) {
      int rbase = i0 + wr * 64 + i * 16 + fq * 4;
#pragma unroll
      for (int r = 0; r < 4; r++) {
        out[(size_t)(rbase + r) * 512 + col] = acc[i][j][r] + bia;
      }
    }
  }
}

// ---------------------------------------------------------------------------
extern "C" void kernel_launch(void* const* d_in, const int* in_sizes, int n_in,
                              void* d_out, int out_size, void* d_ws,
                              size_t ws_size, hipStream_t stream) {
  (void)in_sizes; (void)n_in; (void)out_size; (void)ws_size;

  char* w8 = (char*)d_ws;
  unsigned short* cx  = (unsigned short*)(w8 + 0);         // x canon bf16
  unsigned short* cwq = (unsigned short*)(w8 + 16777216);  // qkv_w canon
  unsigned short* cwp = (unsigned short*)(w8 + 18350080);  // proj_w canon
  float*          cbf = (float*)(w8 + 18874368);           // proj_b fp32
  unsigned short* qkv = (unsigned short*)(w8 + 18876416);  // Q,K,V bf16
  unsigned short* X   = (unsigned short*)(w8 + 69208064);  // attn out bf16
  float* Ql = (float*)(w8 + 85985280);
  float* Kl = (float*)(w8 + 86509568);
  float* k2 = (float*)(w8 + 87033856);
  float* W  = (float*)(w8 + 87558144);
  unsigned short* Ztb = (unsigned short*)(w8 + 88082432);  // Z^T bf16 [bh][d][m]
  unsigned int* gstat = (unsigned int*)(w8 + 88606720);  // [cmax, rmax, flag]
  float* Wp = (float*)(w8 + 88608768);                   // 32*8*4096*4 B
  float* sp = (float*)(w8 + 92803072);                   // 32*8*64*4 B
  unsigned short* Klb = (unsigned short*)(w8 + 92868608); // Kl bf16

  hipMemsetAsync(gstat, 0, 16, stream);
  detect_dtype<<<1, 64, 0, stream>>>((const unsigned short*)d_in[0],
                                     gstat + 2);
  convert_bf16<<<4096, 256, 0, stream>>>(d_in[0], cx, 8388608, gstat + 2);
  convert_bf16<<<384, 256, 0, stream>>>(d_in[1], cwq, 786432, gstat + 2);
  convert_bf16<<<128, 256, 0, stream>>>(d_in[2], cwp, 262144, gstat + 2);
  convert_f32<<<2, 256, 0, stream>>>(d_in[3], cbf, 512, gstat + 2);

  qkv_gemm_mfma<<<dim3(12, 128), 256, 0, stream>>>(cx, cwq, qkv);
  pool_kernel<<<512, 256, 0, stream>>>(qkv, Ql, Kl, Klb);
  k2_kernel<<<32, 256, 0, stream>>>(Ql, Kl, k2, gstat);
  k3_partial<<<dim3(8, 32), 256, 0, stream>>>(Ql, qkv, Wp, sp);
  k3_reduce<<<512, 256, 0, stream>>>(Wp, sp, W);
  ns_kernel<<<32, 256, 0, stream>>>(k2, gstat, W, Ztb);
  k1x_mfma<<<dim3(32, 32), 256, 0, stream>>>(qkv, Klb, Ztb, X);
  proj_gemm_mfma<<<dim3(4, 128), 256, 0, stream>>>(X, cwp, cbf,
                                                   (float*)d_out);
}

// Round 8
// 255.255 us; speedup vs baseline: 6.1013x; 1.1571x over previous
//
#include <hip/hip_runtime.h>
#include <hip/hip_bf16.h>
#include <stdint.h>

// Problem constants: B=4, N=4096, C=512, H=8, M=64, HD=64
#define QSZe 8388608ull  // elements per Q/K/V tensor (B*H*N*HD)

typedef __attribute__((ext_vector_type(8))) short bf16x8;
typedef __attribute__((ext_vector_type(4))) float f32x4;
typedef const __attribute__((address_space(1))) unsigned int* gas1_t;
typedef __attribute__((address_space(3))) unsigned int* las3_t;

__device__ __forceinline__ float bf2f(unsigned short u) {
  return __uint_as_float(((unsigned int)u) << 16);
}
__device__ __forceinline__ unsigned short f2bf(float f) {
  unsigned int u = __float_as_uint(f);
  unsigned int r = (u + 0x7FFFu + ((u >> 16) & 1u)) >> 16;
  return (unsigned short)r;
}
__device__ __forceinline__ void gload_lds16(const void* g, void* l) {
  __builtin_amdgcn_global_load_lds((gas1_t)g, (las3_t)l, 16, 0, 0);
}

// ---------------------------------------------------------------------------
// Dtype detector (inputs proven fp32 on this harness, but keep robustness).
// ---------------------------------------------------------------------------
__global__ void detect_dtype(const unsigned short* __restrict__ raw,
                             unsigned int* __restrict__ flag) {
  int t = threadIdx.x;  // 64 threads
  int big = 0;
  for (int i = t; i < 256; i += 64) {
    int e = (raw[i] >> 7) & 0xFF;
    if (e >= 0x8F) big = 1;  // |val| >= 2^16 (or NaN/Inf)
  }
  unsigned long long b = __ballot(big);
  if (t == 0) flag[0] = (b != 0ull) ? 1u : 0u;
}

// Canonicalize a tensor to bf16 (round if fp32, copy if already bf16).
__global__ __launch_bounds__(256) void convert_bf16(
    const void* __restrict__ raw, unsigned short* __restrict__ canon, int n,
    const unsigned int* __restrict__ flag) {
  int i8 = (blockIdx.x * 256 + threadIdx.x) * 8;
  if (i8 >= n) return;
  if (flag[0]) {
    const float* f = (const float*)raw;
    float4 a = *(const float4*)(f + i8);
    float4 b = *(const float4*)(f + i8 + 4);
    unsigned short o[8] = {f2bf(a.x), f2bf(a.y), f2bf(a.z), f2bf(a.w),
                           f2bf(b.x), f2bf(b.y), f2bf(b.z), f2bf(b.w)};
    *(uint4*)(canon + i8) = *(const uint4*)o;
  } else {
    *(uint4*)(canon + i8) = *(const uint4*)((const unsigned short*)raw + i8);
  }
}

// Canonicalize a small tensor to fp32 (used for proj_b).
__global__ __launch_bounds__(256) void convert_f32(
    const void* __restrict__ raw, float* __restrict__ canon, int n,
    const unsigned int* __restrict__ flag) {
  int i = blockIdx.x * 256 + threadIdx.x;
  if (i >= n) return;
  canon[i] = flag[0] ? ((const float*)raw)[i]
                     : bf2f(((const unsigned short*)raw)[i]);
}

// ---------------------------------------------------------------------------
// bf16 MFMA 64x64x64 helper for ns_kernel (see r6 notes).
// ---------------------------------------------------------------------------
__device__ __forceinline__ void mmB(const unsigned short* A_R,
                                    const unsigned short* B_T,
                                    unsigned short* out_R,
                                    unsigned short* out_T, int wave, int lane,
                                    float s, float dg, float a7,
                                    const unsigned short* Aelt) {
  const int fr = lane & 15, fq = lane >> 4;
  bf16x8 af0 = *(const bf16x8*)&A_R[(wave * 16 + fr) * 64 + fq * 8];
  bf16x8 af1 = *(const bf16x8*)&A_R[(wave * 16 + fr) * 64 + 32 + fq * 8];
  f32x4 acc[4] = {};
#pragma unroll
  for (int j = 0; j < 4; j++) {
    bf16x8 b0 = *(const bf16x8*)&B_T[(j * 16 + fr) * 64 + fq * 8];
    bf16x8 b1 = *(const bf16x8*)&B_T[(j * 16 + fr) * 64 + 32 + fq * 8];
    acc[j] = __builtin_amdgcn_mfma_f32_16x16x32_bf16(af0, b0, acc[j], 0, 0, 0);
    acc[j] = __builtin_amdgcn_mfma_f32_16x16x32_bf16(af1, b1, acc[j], 0, 0, 0);
  }
  float ael[4][4];
  if (Aelt) {
#pragma unroll
    for (int j = 0; j < 4; j++)
#pragma unroll
      for (int r = 0; r < 4; r++)
        ael[j][r] = bf2f(Aelt[(wave * 16 + fq * 4 + r) * 64 + j * 16 + fr]);
  }
  __syncthreads();  // all reads complete before any write
#pragma unroll
  for (int j = 0; j < 4; j++) {
    int col = j * 16 + fr;
    unsigned short pack[4];
#pragma unroll
    for (int r = 0; r < 4; r++) {
      int row = wave * 16 + fq * 4 + r;
      float v = s * acc[j][r] + ((row == col) ? dg : 0.0f);
      if (Aelt) v += a7 * ael[j][r];
      unsigned short bv = f2bf(v);
      if (out_R) out_R[row * 64 + col] = bv;
      pack[r] = bv;
    }
    if (out_T)
      *(uint2*)&out_T[col * 64 + wave * 16 + fq * 4] = *(const uint2*)pack;
  }
}

// ---------------------------------------------------------------------------
// Kernel A (MFMA): qkv = x @ qkv_w^T, bf16 MFMA 128x128 tile, BK=64.
// Grid (12, 128), 256 thr.
// ---------------------------------------------------------------------------
__global__ __launch_bounds__(256) void qkv_gemm_mfma(
    const unsigned short* __restrict__ x, const unsigned short* __restrict__ w,
    unsigned short* __restrict__ qkv) {
  __shared__ __align__(16) unsigned short At[128 * 64];
  __shared__ __align__(16) unsigned short Bt[128 * 64];
  const int t = threadIdx.x;
  const int lane = t & 63, wave = t >> 6;
  const int wr = wave >> 1, wc = wave & 1;
  const int i0 = blockIdx.y * 128, j0 = blockIdx.x * 128;
  const int srow = lane >> 3;
  const int skc = (lane & 7) * 8;
  const int fr = lane & 15, fq = lane >> 4;
  f32x4 acc[4][4] = {};

  for (int k0 = 0; k0 < 512; k0 += 64) {
#pragma unroll
    for (int s = 0; s < 4; s++) {
      int inst = wave * 4 + s;
      int row = inst * 8 + srow;
      gload_lds16(x + (size_t)(i0 + row) * 512 + k0 + skc, &At[inst * 512]);
      gload_lds16(w + (size_t)(j0 + row) * 512 + k0 + skc, &Bt[inst * 512]);
    }
    __syncthreads();
#pragma unroll
    for (int kk = 0; kk < 64; kk += 32) {
      bf16x8 af[4], bg[4];
#pragma unroll
      for (int i = 0; i < 4; i++)
        af[i] = *(const bf16x8*)&At[(wr * 64 + i * 16 + fr) * 64 + kk + fq * 8];
#pragma unroll
      for (int j = 0; j < 4; j++)
        bg[j] = *(const bf16x8*)&Bt[(wc * 64 + j * 16 + fr) * 64 + kk + fq * 8];
#pragma unroll
      for (int i = 0; i < 4; i++)
#pragma unroll
        for (int j = 0; j < 4; j++)
          acc[i][j] = __builtin_amdgcn_mfma_f32_16x16x32_bf16(
              af[i], bg[j], acc[i][j], 0, 0, 0);
    }
    __syncthreads();
  }
#pragma unroll
  for (int j = 0; j < 4; j++) {
    int col = j0 + wc * 64 + j * 16 + fr;  // 0..1535
    int which = col >> 9;
    int h = (col >> 6) & 7;
    int d = col & 63;
    float scale = (which < 2) ? 0.3535533905932738f : 1.0f;
#pragma unroll
    for (int i = 0; i < 4; i++) {
      int rbase = i0 + wr * 64 + i * 16 + fq * 4;
#pragma unroll
      for (int r = 0; r < 4; r++) {
        int row = rbase + r;
        int b_ = row >> 12, n = row & 4095;
        qkv[(size_t)which * QSZe + ((size_t)(b_ * 8 + h) * 4096 + n) * 64 + d] =
            f2bf(acc[i][j][r] * scale);
      }
    }
  }
}

// ---------------------------------------------------------------------------
// Kernel B: landmark mean-pool; emits fp32 Ql/Kl + bf16 Qlb/Klb. Grid 512.
// ---------------------------------------------------------------------------
__global__ __launch_bounds__(256) void pool_kernel(
    const unsigned short* __restrict__ qkv, float* __restrict__ Ql,
    float* __restrict__ Kl, unsigned short* __restrict__ Klb,
    unsigned short* __restrict__ Qlb) {
  int idx = blockIdx.x * 256 + threadIdx.x;  // [bh][m][d]
  int d = idx & 63;
  int m = (idx >> 6) & 63;
  int bh = idx >> 12;
  const unsigned short* qb =
      qkv + (size_t)bh * 262144 + (size_t)m * 4096 + d;
  const unsigned short* kb = qb + QSZe;
  float sq = 0.f, sk = 0.f;
#pragma unroll 8
  for (int tok = 0; tok < 64; tok++) {
    sq += bf2f(qb[tok * 64]);
    sk += bf2f(kb[tok * 64]);
  }
  float qv = sq * (1.0f / 64.0f);
  float kv = sk * (1.0f / 64.0f);
  Ql[idx] = qv;
  Kl[idx] = kv;
  Klb[idx] = f2bf(kv);
  Qlb[idx] = f2bf(qv);
}

// ---------------------------------------------------------------------------
// Kernel C: kernel_2 = softmax(Ql@Kl^T) per (b,h); global max colsum/rowsum
// via atomicMax (positive-float-as-uint).  Grid 32 x 256.
// ---------------------------------------------------------------------------
__global__ __launch_bounds__(256) void k2_kernel(
    const float* __restrict__ Ql, const float* __restrict__ Kl,
    float* __restrict__ k2, unsigned int* __restrict__ gstat) {
  __shared__ float KlT[64 * 64];  // [d][l]
  __shared__ float Ps[64][65];
  int t = threadIdx.x;
  int lane = t & 63, wv = t >> 6;
  int bh = blockIdx.x;
#pragma unroll
  for (int i = 0; i < 16; i++) {
    int idx = i * 256 + t;
    KlT[(idx & 63) * 64 + (idx >> 6)] = Kl[bh * 4096 + idx];
  }
  __syncthreads();
  for (int r = wv * 16; r < wv * 16 + 16; r++) {
    float qv = Ql[(bh * 64 + r) * 64 + lane];
    float acc = 0.f;
#pragma unroll
    for (int k = 0; k < 64; k++) acc += __shfl(qv, k, 64) * KlT[k * 64 + lane];
    float mx = acc;
#pragma unroll
    for (int o = 32; o > 0; o >>= 1) mx = fmaxf(mx, __shfl_xor(mx, o, 64));
    float e = __expf(acc - mx);
    float s = e;
#pragma unroll
    for (int o = 32; o > 0; o >>= 1) s += __shfl_xor(s, o, 64);
    float p = e / s;
    k2[(bh * 64 + r) * 64 + lane] = p;
    Ps[r][lane] = p;
  }
  __syncthreads();
  float val = 0.f;
  if (t < 64) {
    for (int r = 0; r < 64; r++) val += Ps[r][t];  // column sums
  } else if (t < 128) {
    int r = t - 64;
    for (int c = 0; c < 64; c++) val += Ps[r][c];  // row sums
  }
  float mv = val;
#pragma unroll
  for (int o = 32; o > 0; o >>= 1) mv = fmaxf(mv, __shfl_xor(mv, o, 64));
  if (t == 0) atomicMax(gstat + 0, __float_as_uint(mv));
  if (t == 64) atomicMax(gstat + 1, __float_as_uint(mv));
}

// ---------------------------------------------------------------------------
// Kernel E (MFMA): kernel_3 + P@V partials. Grid (8 slabs, 32 bh), 256 thr.
// S^T = K_slab @ Ql^T via mfma (A-frags direct from global K, B-frags from
// global Qlb). exp in registers (no max-shift; logits tiny). E^T packed to
// LDS [m][n] (uint2, 4 consec n); V^T staged LDS [d][n]; PV = E^T@V mfma.
// Column sums (softmax denom partials) via lane accum + shfl + LDS reduce.
// ---------------------------------------------------------------------------
__global__ __launch_bounds__(256) void k3_mfma(
    const unsigned short* __restrict__ Qlb,
    const unsigned short* __restrict__ qkv, float* __restrict__ Wp,
    float* __restrict__ sp) {
  __shared__ __align__(16) unsigned short Et[64 * 136];  // E^T [m][n], 17.4 KB
  __shared__ __align__(16) unsigned short Vt[64 * 136];  // V^T [d][n], 17.4 KB
  __shared__ float scol_l[4][64];
  const int t = threadIdx.x;
  const int lane = t & 63, wave = t >> 6;
  const int fr = lane & 15, fq = lane >> 4;
  const int slab = blockIdx.x, bh = blockIdx.y;
  const int n_base = slab * 512;
  const unsigned short* Kb = qkv + QSZe + (size_t)bh * 262144;
  const unsigned short* Vb = qkv + 2 * QSZe + (size_t)bh * 262144;
  const unsigned short* Qlp = Qlb + bh * 4096;

  // Preload Ql B-frags (reused every sub-chunk)
  bf16x8 qb[2][4];
#pragma unroll
  for (int h = 0; h < 2; h++)
#pragma unroll
    for (int j = 0; j < 4; j++)
      qb[h][j] = *(const bf16x8*)(Qlp + (j * 16 + fr) * 64 + h * 32 + fq * 8);

  f32x4 accW[4] = {};
  float scol[4] = {0.f, 0.f, 0.f, 0.f};

  for (int sc = 0; sc < 4; sc++) {
    const int n0 = n_base + sc * 128;
    // stage V^T: Vt[d][n]
    {
      int n = t & 127, dg = t >> 7;
#pragma unroll
      for (int i = 0; i < 4; i++) {
        int d0 = (dg + 2 * i) * 8;
        uint4 v = *(const uint4*)(Vb + (size_t)(n0 + n) * 64 + d0);
        const unsigned short* s = (const unsigned short*)&v;
#pragma unroll
        for (int u = 0; u < 8; u++) Vt[(d0 + u) * 136 + n] = s[u];
      }
    }
    // S^T: rows = keys (32/wave), cols = landmarks
    f32x4 acc[2][4] = {};
#pragma unroll
    for (int i = 0; i < 2; i++) {
      const unsigned short* Kr =
          Kb + (size_t)(n0 + wave * 32 + i * 16 + fr) * 64;
      bf16x8 a0 = *(const bf16x8*)(Kr + fq * 8);
      bf16x8 a1 = *(const bf16x8*)(Kr + 32 + fq * 8);
#pragma unroll
      for (int j = 0; j < 4; j++) {
        acc[i][j] =
            __builtin_amdgcn_mfma_f32_16x16x32_bf16(a0, qb[0][j], acc[i][j],
                                                    0, 0, 0);
        acc[i][j] =
            __builtin_amdgcn_mfma_f32_16x16x32_bf16(a1, qb[1][j], acc[i][j],
                                                    0, 0, 0);
      }
    }
    // exp + column partials + pack E^T to LDS
#pragma unroll
    for (int i = 0; i < 2; i++)
#pragma unroll
      for (int j = 0; j < 4; j++) {
        unsigned short pack[4];
        float s4 = 0.f;
#pragma unroll
        for (int r = 0; r < 4; r++) {
          float e = __expf(acc[i][j][r]);
          s4 += e;
          pack[r] = f2bf(e);
        }
        scol[j] += s4;
        *(uint2*)&Et[(j * 16 + fr) * 136 + wave * 32 + i * 16 + fq * 4] =
            *(const uint2*)pack;
      }
    __syncthreads();
    // PV: W-tile rows m = wave*16.., cols d; k = n over 128
#pragma unroll
    for (int kk = 0; kk < 128; kk += 32) {
      bf16x8 ap = *(const bf16x8*)&Et[(wave * 16 + fr) * 136 + kk + fq * 8];
#pragma unroll
      for (int j = 0; j < 4; j++) {
        bf16x8 bv = *(const bf16x8*)&Vt[(j * 16 + fr) * 136 + kk + fq * 8];
        accW[j] =
            __builtin_amdgcn_mfma_f32_16x16x32_bf16(ap, bv, accW[j], 0, 0, 0);
      }
    }
    __syncthreads();
  }
  // column-sum partials: reduce over fq groups, then across waves via LDS
#pragma unroll
  for (int j = 0; j < 4; j++) {
    float s = scol[j];
    s += __shfl_xor(s, 16, 64);
    s += __shfl_xor(s, 32, 64);
    if (fq == 0) scol_l[wave][j * 16 + fr] = s;
  }
  __syncthreads();
  if (t < 64)
    sp[(bh * 8 + slab) * 64 + t] =
        scol_l[0][t] + scol_l[1][t] + scol_l[2][t] + scol_l[3][t];
  float* wpo = Wp + ((size_t)bh * 8 + slab) * 4096;
#pragma unroll
  for (int j = 0; j < 4; j++)
#pragma unroll
    for (int r = 0; r < 4; r++)
      wpo[(wave * 16 + fq * 4 + r) * 64 + j * 16 + fr] = accW[j][r];
}

// W[bh][m][d] = sum_c Wp[bh][c][m][d] / sum_c sp[bh][c][m].  Grid 512 x 256.
__global__ __launch_bounds__(256) void k3_reduce(
    const float* __restrict__ Wp, const float* __restrict__ sp,
    float* __restrict__ W) {
  int idx = blockIdx.x * 256 + threadIdx.x;
  int m = (idx >> 6) & 63, bh = idx >> 12;
  float w = 0.f, s = 0.f;
#pragma unroll
  for (int c = 0; c < 8; c++) {
    w += Wp[((size_t)bh * 8 + c) * 4096 + (idx & 4095)];
    s += sp[(bh * 8 + c) * 64 + m];
  }
  W[idx] = w / s;
}

// ---------------------------------------------------------------------------
// Kernel D (MFMA): Newton-Schulz (6 iters) + Z^T -> Ztb[bh][d][m] bf16.
// ---------------------------------------------------------------------------
__global__ __launch_bounds__(256) void ns_kernel(
    const float* __restrict__ k2g, const unsigned int* __restrict__ gstat,
    const float* __restrict__ Wg, unsigned short* __restrict__ Ztb) {
  __shared__ __align__(16) unsigned short L[8 * 4096];
  unsigned short* K2R = L;
  unsigned short* VR = L + 4096;
  unsigned short* VT = L + 2 * 4096;
  unsigned short* AR = L + 3 * 4096;
  unsigned short* AT = L + 4 * 4096;
  unsigned short* T2T = L + 5 * 4096;
  unsigned short* T3T = L + 6 * 4096;
  unsigned short* WT = L + 7 * 4096;
  const int t = threadIdx.x, bh = blockIdx.x;
  const int lane = t & 63, wave = t >> 6;
  const float scale =
      1.0f / (__uint_as_float(gstat[0]) * __uint_as_float(gstat[1]));
  const float* k2p = k2g + bh * 4096;
  const float* wp = Wg + bh * 4096;
#pragma unroll
  for (int i = 0; i < 16; i++) {
    int idx = i * 256 + t;
    int r = idx >> 6, c = idx & 63;
    float kv = k2p[idx];
    K2R[idx] = f2bf(kv);
    VT[idx] = f2bf(kv * scale);
    VR[idx] = f2bf(k2p[c * 64 + r] * scale);
    WT[idx] = f2bf(wp[c * 64 + r]);
  }
  __syncthreads();
  for (int it = 0; it < 6; it++) {
    mmB(K2R, VT, AR, AT, wave, lane, 1.0f, 0.0f, 0.0f, nullptr);
    __syncthreads();
    mmB(AR, AT, nullptr, T2T, wave, lane, 1.0f, 15.0f, -7.0f, AR);
    __syncthreads();
    mmB(AR, T2T, nullptr, T3T, wave, lane, -1.0f, 13.0f, 0.0f, nullptr);
    __syncthreads();
    mmB(VR, T3T, VR, VT, wave, lane, 0.25f, 0.0f, 0.0f, nullptr);
    __syncthreads();
  }
  {
    const int fr = lane & 15, fq = lane >> 4;
    bf16x8 af0 = *(const bf16x8*)&WT[(wave * 16 + fr) * 64 + fq * 8];
    bf16x8 af1 = *(const bf16x8*)&WT[(wave * 16 + fr) * 64 + 32 + fq * 8];
    f32x4 acc[4] = {};
#pragma unroll
    for (int j = 0; j < 4; j++) {
      bf16x8 b0 = *(const bf16x8*)&VR[(j * 16 + fr) * 64 + fq * 8];
      bf16x8 b1 = *(const bf16x8*)&VR[(j * 16 + fr) * 64 + 32 + fq * 8];
      acc[j] =
          __builtin_amdgcn_mfma_f32_16x16x32_bf16(af0, b0, acc[j], 0, 0, 0);
      acc[j] =
          __builtin_amdgcn_mfma_f32_16x16x32_bf16(af1, b1, acc[j], 0, 0, 0);
    }
#pragma unroll
    for (int j = 0; j < 4; j++) {
      int m = j * 16 + fr;
#pragma unroll
      for (int r = 0; r < 4; r++) {
        int d = wave * 16 + fq * 4 + r;
        Ztb[bh * 4096 + d * 64 + m] = f2bf(acc[j][r]);
      }
    }
  }
}

// ---------------------------------------------------------------------------
// Kernel G (MFMA): kernel_1 softmax fused with X = P @ Z. Grid (32, 32).
// ---------------------------------------------------------------------------
__global__ __launch_bounds__(256) void k1x_mfma(
    const unsigned short* __restrict__ qkv,
    const unsigned short* __restrict__ Klb,
    const unsigned short* __restrict__ Ztb, unsigned short* __restrict__ X) {
  __shared__ __align__(16) unsigned short Qt[128 * 64];  // 16 KB
  __shared__ __align__(16) unsigned short Ps[128 * 72];  // 18 KB
  const int t = threadIdx.x;
  const int lane = t & 63, wave = t >> 6;
  const int fr = lane & 15, fq = lane >> 4;
  const int bh = blockIdx.x;
  const int n0 = blockIdx.y * 128;
  const unsigned short* Qb = qkv + (size_t)bh * 262144 + (size_t)n0 * 64;
  const unsigned short* Klp = Klb + bh * 4096;
  const unsigned short* Ztp = Ztb + bh * 4096;

  {
    const int srow = lane >> 3, skc = (lane & 7) * 8;
#pragma unroll
    for (int s = 0; s < 4; s++) {
      int inst = wave * 4 + s;
      gload_lds16(Qb + (size_t)(inst * 8 + srow) * 64 + skc, &Qt[inst * 512]);
    }
  }
  __syncthreads();

  f32x4 acc[2][4] = {};
#pragma unroll
  for (int kk = 0; kk < 64; kk += 32) {
    bf16x8 af[2], bg[4];
#pragma unroll
    for (int i = 0; i < 2; i++)
      af[i] =
          *(const bf16x8*)&Qt[(wave * 32 + i * 16 + fr) * 64 + kk + fq * 8];
#pragma unroll
    for (int j = 0; j < 4; j++)
      bg[j] = *(const bf16x8*)(Klp + (j * 16 + fr) * 64 + kk + fq * 8);
#pragma unroll
    for (int i = 0; i < 2; i++)
#pragma unroll
      for (int j = 0; j < 4; j++)
        acc[i][j] = __builtin_amdgcn_mfma_f32_16x16x32_bf16(af[i], bg[j],
                                                            acc[i][j], 0, 0, 0);
  }

#pragma unroll
  for (int i = 0; i < 2; i++) {
    float sr[4] = {0.f, 0.f, 0.f, 0.f};
#pragma unroll
    for (int j = 0; j < 4; j++)
#pragma unroll
      for (int r = 0; r < 4; r++) {
        float e = __expf(acc[i][j][r]);
        acc[i][j][r] = e;
        sr[r] += e;
      }
#pragma unroll
    for (int mask = 1; mask < 16; mask <<= 1)
#pragma unroll
      for (int r = 0; r < 4; r++) sr[r] += __shfl_xor(sr[r], mask, 64);
    float is[4];
#pragma unroll
    for (int r = 0; r < 4; r++) is[r] = 1.0f / sr[r];
#pragma unroll
    for (int j = 0; j < 4; j++)
#pragma unroll
      for (int r = 0; r < 4; r++)
        Ps[(wave * 32 + i * 16 + fq * 4 + r) * 72 + j * 16 + fr] =
            f2bf(acc[i][j][r] * is[r]);
  }
  __syncthreads();

  f32x4 ax[2][4] = {};
#pragma unroll
  for (int kk = 0; kk < 64; kk += 32) {
    bf16x8 ap[2], bz[4];
#pragma unroll
    for (int i = 0; i < 2; i++)
      ap[i] =
          *(const bf16x8*)&Ps[(wave * 32 + i * 16 + fr) * 72 + kk + fq * 8];
#pragma unroll
    for (int j = 0; j < 4; j++)
      bz[j] = *(const bf16x8*)(Ztp + (j * 16 + fr) * 64 + kk + fq * 8);
#pragma unroll
    for (int i = 0; i < 2; i++)
#pragma unroll
      for (int j = 0; j < 4; j++)
        ax[i][j] = __builtin_amdgcn_mfma_f32_16x16x32_bf16(ap[i], bz[j],
                                                           ax[i][j], 0, 0, 0);
  }

  const int b_ = bh >> 3, h = bh & 7;
#pragma unroll
  for (int i = 0; i < 2; i++) {
#pragma unroll
    for (int j = 0; j < 4; j++) {
      int c = h * 64 + j * 16 + fr;
#pragma unroll
      for (int r = 0; r < 4; r++) {
        int n = n0 + wave * 32 + i * 16 + fq * 4 + r;
        X[((size_t)(b_ * 4096 + n)) * 512 + c] = f2bf(ax[i][j][r]);
      }
    }
  }
}

// ---------------------------------------------------------------------------
// Kernel H (MFMA): out = X @ proj_w^T + proj_b, fp32 OUT. Grid (4, 128).
// ---------------------------------------------------------------------------
__global__ __launch_bounds__(256) void proj_gemm_mfma(
    const unsigned short* __restrict__ X, const unsigned short* __restrict__ w,
    const float* __restrict__ bias, float* __restrict__ out) {
  __shared__ __align__(16) unsigned short At[128 * 64];
  __shared__ __align__(16) unsigned short Bt[128 * 64];
  const int t = threadIdx.x;
  const int lane = t & 63, wave = t >> 6;
  const int wr = wave >> 1, wc = wave & 1;
  const int i0 = blockIdx.y * 128, j0 = blockIdx.x * 128;
  const int srow = lane >> 3;
  const int skc = (lane & 7) * 8;
  const int fr = lane & 15, fq = lane >> 4;
  f32x4 acc[4][4] = {};

  for (int k0 = 0; k0 < 512; k0 += 64) {
#pragma unroll
    for (int s = 0; s < 4; s++) {
      int inst = wave * 4 + s;
      int row = inst * 8 + srow;
      gload_lds16(X + (size_t)(i0 + row) * 512 + k0 + skc, &At[inst * 512]);
      gload_lds16(w + (size_t)(j0 + row) * 512 + k0 + skc, &Bt[inst * 512]);
    }
    __syncthreads();
#pragma unroll
    for (int kk = 0; kk < 64; kk += 32) {
      bf16x8 af[4], bg[4];
#pragma unroll
      for (int i = 0; i < 4; i++)
        af[i] = *(const bf16x8*)&At[(wr * 64 + i * 16 + fr) * 64 + kk + fq * 8];
#pragma unroll
      for (int j = 0; j < 4; j++)
        bg[j] = *(const bf16x8*)&Bt[(wc * 64 + j * 16 + fr) * 64 + kk + fq * 8];
#pragma unroll
      for (int i = 0; i < 4; i++)
#pragma unroll
        for (int j = 0; j < 4; j++)
          acc[i][j] = __builtin_amdgcn_mfma_f32_16x16x32_bf16(
              af[i], bg[j], acc[i][j], 0, 0, 0);
    }
    __syncthreads();
  }
#pragma unroll
  for (int j = 0; j < 4; j++) {
    int col = j0 + wc * 64 + j * 16 + fr;  // 0..511
    float bia = bias[col];
#pragma unroll
    for (int i = 0; i < 4; i++) {
      int rbase = i0 + wr * 64 + i * 16 + fq * 4;
#pragma unroll
      for (int r = 0; r < 4; r++) {
        out[(size_t)(rbase + r) * 512 + col] = acc[i][j][r] + bia;
      }
    }
  }
}

// ---------------------------------------------------------------------------
extern "C" void kernel_launch(void* const* d_in, const int* in_sizes, int n_in,
                              void* d_out, int out_size, void* d_ws,
                              size_t ws_size, hipStream_t stream) {
  (void)in_sizes; (void)n_in; (void)out_size; (void)ws_size;

  char* w8 = (char*)d_ws;
  unsigned short* cx  = (unsigned short*)(w8 + 0);         // x canon bf16
  unsigned short* cwq = (unsigned short*)(w8 + 16777216);  // qkv_w canon
  unsigned short* cwp = (unsigned short*)(w8 + 18350080);  // proj_w canon
  float*          cbf = (float*)(w8 + 18874368);           // proj_b fp32
  unsigned short* qkv = (unsigned short*)(w8 + 18876416);  // Q,K,V bf16
  unsigned short* X   = (unsigned short*)(w8 + 69208064);  // attn out bf16
  float* Ql = (float*)(w8 + 85985280);
  float* Kl = (float*)(w8 + 86509568);
  float* k2 = (float*)(w8 + 87033856);
  float* W  = (float*)(w8 + 87558144);
  unsigned short* Ztb = (unsigned short*)(w8 + 88082432);  // Z^T bf16 [bh][d][m]
  unsigned int* gstat = (unsigned int*)(w8 + 88606720);  // [cmax, rmax, flag]
  float* Wp = (float*)(w8 + 88608768);                   // 32*8*4096*4 B
  float* sp = (float*)(w8 + 92803072);                   // 32*8*64*4 B
  unsigned short* Klb = (unsigned short*)(w8 + 92868608); // Kl bf16
  unsigned short* Qlb = (unsigned short*)(w8 + 93130752); // Ql bf16

  hipMemsetAsync(gstat, 0, 16, stream);
  detect_dtype<<<1, 64, 0, stream>>>((const unsigned short*)d_in[0],
                                     gstat + 2);
  convert_bf16<<<4096, 256, 0, stream>>>(d_in[0], cx, 8388608, gstat + 2);
  convert_bf16<<<384, 256, 0, stream>>>(d_in[1], cwq, 786432, gstat + 2);
  convert_bf16<<<128, 256, 0, stream>>>(d_in[2], cwp, 262144, gstat + 2);
  convert_f32<<<2, 256, 0, stream>>>(d_in[3], cbf, 512, gstat + 2);

  qkv_gemm_mfma<<<dim3(12, 128), 256, 0, stream>>>(cx, cwq, qkv);
  pool_kernel<<<512, 256, 0, stream>>>(qkv, Ql, Kl, Klb, Qlb);
  k2_kernel<<<32, 256, 0, stream>>>(Ql, Kl, k2, gstat);
  k3_mfma<<<dim3(8, 32), 256, 0, stream>>>(Qlb, qkv, Wp, sp);
  k3_reduce<<<512, 256, 0, stream>>>(Wp, sp, W);
  ns_kernel<<<32, 256, 0, stream>>>(k2, gstat, W, Ztb);
  k1x_mfma<<<dim3(32, 32), 256, 0, stream>>>(qkv, Klb, Ztb, X);
  proj_gemm_mfma<<<dim3(4, 128), 256, 0, stream>>>(X, cwp, cbf,
                                                   (float*)d_out);
}

// Round 9
// 249.462 us; speedup vs baseline: 6.2430x; 1.0232x over previous
//
#include <hip/hip_runtime.h>
#include <hip/hip_bf16.h>
#include <stdint.h>

// Problem constants: B=4, N=4096, C=512, H=8, M=64, HD=64
#define QSZe 8388608ull  // elements per Q/K/V tensor (B*H*N*HD)

typedef __attribute__((ext_vector_type(8))) short bf16x8;
typedef __attribute__((ext_vector_type(4))) float f32x4;
typedef const __attribute__((address_space(1))) unsigned int* gas1_t;
typedef __attribute__((address_space(3))) unsigned int* las3_t;

__device__ __forceinline__ float bf2f(unsigned short u) {
  return __uint_as_float(((unsigned int)u) << 16);
}
__device__ __forceinline__ unsigned short f2bf(float f) {
  unsigned int u = __float_as_uint(f);
  unsigned int r = (u + 0x7FFFu + ((u >> 16) & 1u)) >> 16;
  return (unsigned short)r;
}
__device__ __forceinline__ void gload_lds16(const void* g, void* l) {
  __builtin_amdgcn_global_load_lds((gas1_t)g, (las3_t)l, 16, 0, 0);
}

// ---------------------------------------------------------------------------
// detect dtype (flag=1 -> fp32 inputs) + convert proj_b to fp32. 1 block.
// ---------------------------------------------------------------------------
__global__ void detect_bias(const unsigned short* __restrict__ raw_x,
                            const void* __restrict__ raw_b,
                            float* __restrict__ cbf,
                            unsigned int* __restrict__ flag) {
  __shared__ unsigned int fl;
  int t = threadIdx.x;  // 256
  if (t < 64) {
    int big = 0;
    for (int i = t; i < 256; i += 64) {
      int e = (raw_x[i] >> 7) & 0xFF;
      if (e >= 0x8F) big = 1;  // |val| >= 2^16 -> fp32 bits
    }
    unsigned long long b = __ballot(big);
    if (t == 0) {
      fl = (b != 0ull) ? 1u : 0u;
      flag[0] = fl;
    }
  }
  __syncthreads();
  unsigned int f = fl;
  for (int i = t; i < 512; i += 256)
    cbf[i] = f ? ((const float*)raw_b)[i]
               : bf2f(((const unsigned short*)raw_b)[i]);
}

// ---------------------------------------------------------------------------
// Canonicalize x, qkv_w, proj_w to bf16 in ONE dispatch. Grid 4608 x 256.
// Region split at block granularity (no intra-block divergence).
// ---------------------------------------------------------------------------
__global__ __launch_bounds__(256) void conv_all(
    const void* __restrict__ rx, const void* __restrict__ rwq,
    const void* __restrict__ rwp, unsigned short* __restrict__ cx,
    unsigned short* __restrict__ cwq, unsigned short* __restrict__ cwp,
    const unsigned int* __restrict__ flag) {
  int gid = blockIdx.x * 256 + threadIdx.x;
  const void* src;
  unsigned short* dst;
  int i8;
  if (gid < 1048576) {
    src = rx; dst = cx; i8 = gid * 8;
  } else if (gid < 1146880) {
    src = rwq; dst = cwq; i8 = (gid - 1048576) * 8;
  } else {
    src = rwp; dst = cwp; i8 = (gid - 1146880) * 8;
  }
  if (flag[0]) {
    const float* f = (const float*)src;
    float4 a = *(const float4*)(f + i8);
    float4 b = *(const float4*)(f + i8 + 4);
    unsigned short o[8] = {f2bf(a.x), f2bf(a.y), f2bf(a.z), f2bf(a.w),
                           f2bf(b.x), f2bf(b.y), f2bf(b.z), f2bf(b.w)};
    *(uint4*)(dst + i8) = *(const uint4*)o;
  } else {
    *(uint4*)(dst + i8) = *(const uint4*)((const unsigned short*)src + i8);
  }
}

// ---------------------------------------------------------------------------
// bf16 MFMA 64x64x64 helper for ns_kernel (see r6 notes).
// ---------------------------------------------------------------------------
__device__ __forceinline__ void mmB(const unsigned short* A_R,
                                    const unsigned short* B_T,
                                    unsigned short* out_R,
                                    unsigned short* out_T, int wave, int lane,
                                    float s, float dg, float a7,
                                    const unsigned short* Aelt) {
  const int fr = lane & 15, fq = lane >> 4;
  bf16x8 af0 = *(const bf16x8*)&A_R[(wave * 16 + fr) * 64 + fq * 8];
  bf16x8 af1 = *(const bf16x8*)&A_R[(wave * 16 + fr) * 64 + 32 + fq * 8];
  f32x4 acc[4] = {};
#pragma unroll
  for (int j = 0; j < 4; j++) {
    bf16x8 b0 = *(const bf16x8*)&B_T[(j * 16 + fr) * 64 + fq * 8];
    bf16x8 b1 = *(const bf16x8*)&B_T[(j * 16 + fr) * 64 + 32 + fq * 8];
    acc[j] = __builtin_amdgcn_mfma_f32_16x16x32_bf16(af0, b0, acc[j], 0, 0, 0);
    acc[j] = __builtin_amdgcn_mfma_f32_16x16x32_bf16(af1, b1, acc[j], 0, 0, 0);
  }
  float ael[4][4];
  if (Aelt) {
#pragma unroll
    for (int j = 0; j < 4; j++)
#pragma unroll
      for (int r = 0; r < 4; r++)
        ael[j][r] = bf2f(Aelt[(wave * 16 + fq * 4 + r) * 64 + j * 16 + fr]);
  }
  __syncthreads();  // all reads complete before any write
#pragma unroll
  for (int j = 0; j < 4; j++) {
    int col = j * 16 + fr;
    unsigned short pack[4];
#pragma unroll
    for (int r = 0; r < 4; r++) {
      int row = wave * 16 + fq * 4 + r;
      float v = s * acc[j][r] + ((row == col) ? dg : 0.0f);
      if (Aelt) v += a7 * ael[j][r];
      unsigned short bv = f2bf(v);
      if (out_R) out_R[row * 64 + col] = bv;
      pack[r] = bv;
    }
    if (out_T)
      *(uint2*)&out_T[col * 64 + wave * 16 + fq * 4] = *(const uint2*)pack;
  }
}

// ---------------------------------------------------------------------------
// Kernel A (MFMA, C^T orientation): qkv = x @ qkv_w^T via D = W @ X^T.
// A = qkv_w rows (features), B = x rows (tokens); acc rows = features so each
// lane holds 4 consecutive d -> uint2 stores.  Each wave's 64 token-columns
// are exactly one landmark -> landmark mean pooling FUSED into the epilogue
// (unique writer per (bh,m,d), no atomics).  Grid (12, 128), 256 thr.
// ---------------------------------------------------------------------------
__global__ __launch_bounds__(256) void qkv_gemm_mfma(
    const unsigned short* __restrict__ w, const unsigned short* __restrict__ x,
    unsigned short* __restrict__ qkv, float* __restrict__ Ql,
    float* __restrict__ Kl, unsigned short* __restrict__ Qlb,
    unsigned short* __restrict__ Klb) {
  __shared__ __align__(16) unsigned short At[128 * 64];
  __shared__ __align__(16) unsigned short Bt[128 * 64];
  const int t = threadIdx.x;
  const int lane = t & 63, wave = t >> 6;
  const int wf = wave >> 1, wt = wave & 1;
  const int f0 = blockIdx.x * 128, n0g = blockIdx.y * 128;
  const int srow = lane >> 3, skc = (lane & 7) * 8;
  const int fr = lane & 15, fq = lane >> 4;
  f32x4 acc[4][4] = {};

  for (int k0 = 0; k0 < 512; k0 += 64) {
#pragma unroll
    for (int s = 0; s < 4; s++) {
      int inst = wave * 4 + s;
      int row = inst * 8 + srow;
      gload_lds16(w + (size_t)(f0 + row) * 512 + k0 + skc, &At[inst * 512]);
      gload_lds16(x + (size_t)(n0g + row) * 512 + k0 + skc, &Bt[inst * 512]);
    }
    __syncthreads();
#pragma unroll
    for (int kk = 0; kk < 64; kk += 32) {
      bf16x8 af[4], bxf[4];
#pragma unroll
      for (int i = 0; i < 4; i++)
        af[i] = *(const bf16x8*)&At[(wf * 64 + i * 16 + fr) * 64 + kk + fq * 8];
#pragma unroll
      for (int j = 0; j < 4; j++)
        bxf[j] =
            *(const bf16x8*)&Bt[(wt * 64 + j * 16 + fr) * 64 + kk + fq * 8];
#pragma unroll
      for (int i = 0; i < 4; i++)
#pragma unroll
        for (int j = 0; j < 4; j++)
          acc[i][j] = __builtin_amdgcn_mfma_f32_16x16x32_bf16(
              af[i], bxf[j], acc[i][j], 0, 0, 0);
    }
    __syncthreads();
  }
  // epilogue: wave-uniform (which, h); rows = features, cols = tokens
  const int fbase = f0 + wf * 64;
  const int which = fbase >> 9;
  const int h = (fbase >> 6) & 7;
  const float scale = (which < 2) ? 0.3535533905932738f : 1.0f;
  const int b_ = n0g >> 12;
  const int bh = b_ * 8 + h;
  const int m_loc = ((n0g + wt * 64) & 4095) >> 6;  // landmark (wave-uniform)
#pragma unroll
  for (int i = 0; i < 4; i++) {
    int d0 = i * 16 + fq * 4;
#pragma unroll
    for (int j = 0; j < 4; j++) {
      int nn = (n0g + wt * 64 + j * 16 + fr) & 4095;
      unsigned short pack[4];
#pragma unroll
      for (int r = 0; r < 4; r++) pack[r] = f2bf(acc[i][j][r] * scale);
      *(uint2*)&qkv[(size_t)which * QSZe + ((size_t)bh * 4096 + nn) * 64 +
                    d0] = *(const uint2*)pack;
    }
  }
  if (which < 2) {  // fused landmark pooling (mean over this wave's 64 tokens)
    const float ps = scale * (1.0f / 64.0f);
#pragma unroll
    for (int i = 0; i < 4; i++) {
      float sm[4];
#pragma unroll
      for (int r = 0; r < 4; r++)
        sm[r] = acc[i][0][r] + acc[i][1][r] + acc[i][2][r] + acc[i][3][r];
#pragma unroll
      for (int mask = 1; mask < 16; mask <<= 1)
#pragma unroll
        for (int r = 0; r < 4; r++) sm[r] += __shfl_xor(sm[r], mask, 64);
      if (fr == 0) {
        int d0 = i * 16 + fq * 4;
        float4 v4 = make_float4(sm[0] * ps, sm[1] * ps, sm[2] * ps, sm[3] * ps);
        unsigned short pk[4] = {f2bf(v4.x), f2bf(v4.y), f2bf(v4.z), f2bf(v4.w)};
        size_t off = (size_t)bh * 4096 + m_loc * 64 + d0;
        if (which == 0) {
          *(float4*)&Ql[off] = v4;
          *(uint2*)&Qlb[off] = *(const uint2*)pk;
        } else {
          *(float4*)&Kl[off] = v4;
          *(uint2*)&Klb[off] = *(const uint2*)pk;
        }
      }
    }
  }
}

// ---------------------------------------------------------------------------
// Kernel C: kernel_2 = softmax(Ql@Kl^T) per (b,h); global max colsum/rowsum
// via atomicMax (positive-float-as-uint).  Grid 32 x 256.
// ---------------------------------------------------------------------------
__global__ __launch_bounds__(256) void k2_kernel(
    const float* __restrict__ Ql, const float* __restrict__ Kl,
    float* __restrict__ k2, unsigned int* __restrict__ gstat) {
  __shared__ float KlT[64 * 64];  // [d][l]
  __shared__ float Ps[64][65];
  int t = threadIdx.x;
  int lane = t & 63, wv = t >> 6;
  int bh = blockIdx.x;
#pragma unroll
  for (int i = 0; i < 16; i++) {
    int idx = i * 256 + t;
    KlT[(idx & 63) * 64 + (idx >> 6)] = Kl[bh * 4096 + idx];
  }
  __syncthreads();
  for (int r = wv * 16; r < wv * 16 + 16; r++) {
    float qv = Ql[(bh * 64 + r) * 64 + lane];
    float acc = 0.f;
#pragma unroll
    for (int k = 0; k < 64; k++) acc += __shfl(qv, k, 64) * KlT[k * 64 + lane];
    float mx = acc;
#pragma unroll
    for (int o = 32; o > 0; o >>= 1) mx = fmaxf(mx, __shfl_xor(mx, o, 64));
    float e = __expf(acc - mx);
    float s = e;
#pragma unroll
    for (int o = 32; o > 0; o >>= 1) s += __shfl_xor(s, o, 64);
    float p = e / s;
    k2[(bh * 64 + r) * 64 + lane] = p;
    Ps[r][lane] = p;
  }
  __syncthreads();
  float val = 0.f;
  if (t < 64) {
    for (int r = 0; r < 64; r++) val += Ps[r][t];  // column sums
  } else if (t < 128) {
    int r = t - 64;
    for (int c = 0; c < 64; c++) val += Ps[r][c];  // row sums
  }
  float mv = val;
#pragma unroll
  for (int o = 32; o > 0; o >>= 1) mv = fmaxf(mv, __shfl_xor(mv, o, 64));
  if (t == 0) atomicMax(gstat + 0, __float_as_uint(mv));
  if (t == 64) atomicMax(gstat + 1, __float_as_uint(mv));
}

// ---------------------------------------------------------------------------
// Kernel E (MFMA): kernel_3 + P@V partials. Grid (8 slabs, 32 bh), 256 thr.
// ---------------------------------------------------------------------------
__global__ __launch_bounds__(256) void k3_mfma(
    const unsigned short* __restrict__ Qlb,
    const unsigned short* __restrict__ qkv, float* __restrict__ Wp,
    float* __restrict__ sp) {
  __shared__ __align__(16) unsigned short Et[64 * 136];  // E^T [m][n]
  __shared__ __align__(16) unsigned short Vt[64 * 136];  // V^T [d][n]
  __shared__ float scol_l[4][64];
  const int t = threadIdx.x;
  const int lane = t & 63, wave = t >> 6;
  const int fr = lane & 15, fq = lane >> 4;
  const int slab = blockIdx.x, bh = blockIdx.y;
  const int n_base = slab * 512;
  const unsigned short* Kb = qkv + QSZe + (size_t)bh * 262144;
  const unsigned short* Vb = qkv + 2 * QSZe + (size_t)bh * 262144;
  const unsigned short* Qlp = Qlb + bh * 4096;

  bf16x8 qb[2][4];
#pragma unroll
  for (int h = 0; h < 2; h++)
#pragma unroll
    for (int j = 0; j < 4; j++)
      qb[h][j] = *(const bf16x8*)(Qlp + (j * 16 + fr) * 64 + h * 32 + fq * 8);

  f32x4 accW[4] = {};
  float scol[4] = {0.f, 0.f, 0.f, 0.f};

  for (int sc = 0; sc < 4; sc++) {
    const int n0 = n_base + sc * 128;
    {
      int n = t & 127, dg = t >> 7;
#pragma unroll
      for (int i = 0; i < 4; i++) {
        int d0 = (dg + 2 * i) * 8;
        uint4 v = *(const uint4*)(Vb + (size_t)(n0 + n) * 64 + d0);
        const unsigned short* s = (const unsigned short*)&v;
#pragma unroll
        for (int u = 0; u < 8; u++) Vt[(d0 + u) * 136 + n] = s[u];
      }
    }
    f32x4 acc[2][4] = {};
#pragma unroll
    for (int i = 0; i < 2; i++) {
      const unsigned short* Kr =
          Kb + (size_t)(n0 + wave * 32 + i * 16 + fr) * 64;
      bf16x8 a0 = *(const bf16x8*)(Kr + fq * 8);
      bf16x8 a1 = *(const bf16x8*)(Kr + 32 + fq * 8);
#pragma unroll
      for (int j = 0; j < 4; j++) {
        acc[i][j] = __builtin_amdgcn_mfma_f32_16x16x32_bf16(a0, qb[0][j],
                                                            acc[i][j], 0, 0, 0);
        acc[i][j] = __builtin_amdgcn_mfma_f32_16x16x32_bf16(a1, qb[1][j],
                                                            acc[i][j], 0, 0, 0);
      }
    }
#pragma unroll
    for (int i = 0; i < 2; i++)
#pragma unroll
      for (int j = 0; j < 4; j++) {
        unsigned short pack[4];
        float s4 = 0.f;
#pragma unroll
        for (int r = 0; r < 4; r++) {
          float e = __expf(acc[i][j][r]);
          s4 += e;
          pack[r] = f2bf(e);
        }
        scol[j] += s4;
        *(uint2*)&Et[(j * 16 + fr) * 136 + wave * 32 + i * 16 + fq * 4] =
            *(const uint2*)pack;
      }
    __syncthreads();
#pragma unroll
    for (int kk = 0; kk < 128; kk += 32) {
      bf16x8 ap = *(const bf16x8*)&Et[(wave * 16 + fr) * 136 + kk + fq * 8];
#pragma unroll
      for (int j = 0; j < 4; j++) {
        bf16x8 bv = *(const bf16x8*)&Vt[(j * 16 + fr) * 136 + kk + fq * 8];
        accW[j] =
            __builtin_amdgcn_mfma_f32_16x16x32_bf16(ap, bv, accW[j], 0, 0, 0);
      }
    }
    __syncthreads();
  }
#pragma unroll
  for (int j = 0; j < 4; j++) {
    float s = scol[j];
    s += __shfl_xor(s, 16, 64);
    s += __shfl_xor(s, 32, 64);
    if (fq == 0) scol_l[wave][j * 16 + fr] = s;
  }
  __syncthreads();
  if (t < 64)
    sp[(bh * 8 + slab) * 64 + t] =
        scol_l[0][t] + scol_l[1][t] + scol_l[2][t] + scol_l[3][t];
  float* wpo = Wp + ((size_t)bh * 8 + slab) * 4096;
#pragma unroll
  for (int j = 0; j < 4; j++)
#pragma unroll
    for (int r = 0; r < 4; r++)
      wpo[(wave * 16 + fq * 4 + r) * 64 + j * 16 + fr] = accW[j][r];
}

// ---------------------------------------------------------------------------
// Kernel D (MFMA): Newton-Schulz (6 iters) + FUSED k3 reduction (W from
// Wp/sp) + Z^T -> Ztb[bh][d][m] bf16.  One block per (b,h).
// ---------------------------------------------------------------------------
__global__ __launch_bounds__(256) void ns_kernel(
    const float* __restrict__ k2g, const unsigned int* __restrict__ gstat,
    const float* __restrict__ Wp, const float* __restrict__ sp,
    unsigned short* __restrict__ Ztb) {
  __shared__ __align__(16) unsigned short L[8 * 4096];
  __shared__ float ssum[64];
  unsigned short* K2R = L;
  unsigned short* VR = L + 4096;
  unsigned short* VT = L + 2 * 4096;
  unsigned short* AR = L + 3 * 4096;
  unsigned short* AT = L + 4 * 4096;
  unsigned short* T2T = L + 5 * 4096;
  unsigned short* T3T = L + 6 * 4096;
  unsigned short* WT = L + 7 * 4096;
  const int t = threadIdx.x, bh = blockIdx.x;
  const int lane = t & 63, wave = t >> 6;
  const float scale =
      1.0f / (__uint_as_float(gstat[0]) * __uint_as_float(gstat[1]));
  const float* k2p = k2g + bh * 4096;
  if (t < 64) {
    float s = 0.f;
#pragma unroll
    for (int c = 0; c < 8; c++) s += sp[(bh * 8 + c) * 64 + t];
    ssum[t] = s;
  }
  __syncthreads();
#pragma unroll
  for (int i = 0; i < 16; i++) {
    int idx = i * 256 + t;
    int m = idx >> 6, d = idx & 63;
    float kv = k2p[idx];
    K2R[idx] = f2bf(kv);
    VT[idx] = f2bf(kv * scale);
    VR[idx] = f2bf(k2p[d * 64 + m] * scale);
    float wv = 0.f;
#pragma unroll
    for (int cc = 0; cc < 8; cc++)
      wv += Wp[((size_t)(bh * 8 + cc)) * 4096 + idx];
    WT[d * 64 + m] = f2bf(wv / ssum[m]);
  }
  __syncthreads();
  for (int it = 0; it < 6; it++) {
    mmB(K2R, VT, AR, AT, wave, lane, 1.0f, 0.0f, 0.0f, nullptr);
    __syncthreads();
    mmB(AR, AT, nullptr, T2T, wave, lane, 1.0f, 15.0f, -7.0f, AR);
    __syncthreads();
    mmB(AR, T2T, nullptr, T3T, wave, lane, -1.0f, 13.0f, 0.0f, nullptr);
    __syncthreads();
    mmB(VR, T3T, VR, VT, wave, lane, 0.25f, 0.0f, 0.0f, nullptr);
    __syncthreads();
  }
  {
    const int fr = lane & 15, fq = lane >> 4;
    bf16x8 af0 = *(const bf16x8*)&WT[(wave * 16 + fr) * 64 + fq * 8];
    bf16x8 af1 = *(const bf16x8*)&WT[(wave * 16 + fr) * 64 + 32 + fq * 8];
    f32x4 acc[4] = {};
#pragma unroll
    for (int j = 0; j < 4; j++) {
      bf16x8 b0 = *(const bf16x8*)&VR[(j * 16 + fr) * 64 + fq * 8];
      bf16x8 b1 = *(const bf16x8*)&VR[(j * 16 + fr) * 64 + 32 + fq * 8];
      acc[j] =
          __builtin_amdgcn_mfma_f32_16x16x32_bf16(af0, b0, acc[j], 0, 0, 0);
      acc[j] =
          __builtin_amdgcn_mfma_f32_16x16x32_bf16(af1, b1, acc[j], 0, 0, 0);
    }
#pragma unroll
    for (int j = 0; j < 4; j++) {
      int m = j * 16 + fr;
#pragma unroll
      for (int r = 0; r < 4; r++) {
        int d = wave * 16 + fq * 4 + r;
        Ztb[bh * 4096 + d * 64 + m] = f2bf(acc[j][r]);
      }
    }
  }
}

// ---------------------------------------------------------------------------
// Kernel G (MFMA): kernel_1 softmax fused with X = P @ Z. Grid (32, 32).
// ---------------------------------------------------------------------------
__global__ __launch_bounds__(256) void k1x_mfma(
    const unsigned short* __restrict__ qkv,
    const unsigned short* __restrict__ Klb,
    const unsigned short* __restrict__ Ztb, unsigned short* __restrict__ X) {
  __shared__ __align__(16) unsigned short Qt[128 * 64];  // 16 KB
  __shared__ __align__(16) unsigned short Ps[128 * 72];  // 18 KB
  const int t = threadIdx.x;
  const int lane = t & 63, wave = t >> 6;
  const int fr = lane & 15, fq = lane >> 4;
  const int bh = blockIdx.x;
  const int n0 = blockIdx.y * 128;
  const unsigned short* Qb = qkv + (size_t)bh * 262144 + (size_t)n0 * 64;
  const unsigned short* Klp = Klb + bh * 4096;
  const unsigned short* Ztp = Ztb + bh * 4096;

  {
    const int srow = lane >> 3, skc = (lane & 7) * 8;
#pragma unroll
    for (int s = 0; s < 4; s++) {
      int inst = wave * 4 + s;
      gload_lds16(Qb + (size_t)(inst * 8 + srow) * 64 + skc, &Qt[inst * 512]);
    }
  }
  __syncthreads();

  f32x4 acc[2][4] = {};
#pragma unroll
  for (int kk = 0; kk < 64; kk += 32) {
    bf16x8 af[2], bg[4];
#pragma unroll
    for (int i = 0; i < 2; i++)
      af[i] =
          *(const bf16x8*)&Qt[(wave * 32 + i * 16 + fr) * 64 + kk + fq * 8];
#pragma unroll
    for (int j = 0; j < 4; j++)
      bg[j] = *(const bf16x8*)(Klp + (j * 16 + fr) * 64 + kk + fq * 8);
#pragma unroll
    for (int i = 0; i < 2; i++)
#pragma unroll
      for (int j = 0; j < 4; j++)
        acc[i][j] = __builtin_amdgcn_mfma_f32_16x16x32_bf16(af[i], bg[j],
                                                            acc[i][j], 0, 0, 0);
  }

#pragma unroll
  for (int i = 0; i < 2; i++) {
    float sr[4] = {0.f, 0.f, 0.f, 0.f};
#pragma unroll
    for (int j = 0; j < 4; j++)
#pragma unroll
      for (int r = 0; r < 4; r++) {
        float e = __expf(acc[i][j][r]);
        acc[i][j][r] = e;
        sr[r] += e;
      }
#pragma unroll
    for (int mask = 1; mask < 16; mask <<= 1)
#pragma unroll
      for (int r = 0; r < 4; r++) sr[r] += __shfl_xor(sr[r], mask, 64);
    float is[4];
#pragma unroll
    for (int r = 0; r < 4; r++) is[r] = 1.0f / sr[r];
#pragma unroll
    for (int j = 0; j < 4; j++)
#pragma unroll
      for (int r = 0; r < 4; r++)
        Ps[(wave * 32 + i * 16 + fq * 4 + r) * 72 + j * 16 + fr] =
            f2bf(acc[i][j][r] * is[r]);
  }
  __syncthreads();

  f32x4 ax[2][4] = {};
#pragma unroll
  for (int kk = 0; kk < 64; kk += 32) {
    bf16x8 ap[2], bz[4];
#pragma unroll
    for (int i = 0; i < 2; i++)
      ap[i] =
          *(const bf16x8*)&Ps[(wave * 32 + i * 16 + fr) * 72 + kk + fq * 8];
#pragma unroll
    for (int j = 0; j < 4; j++)
      bz[j] = *(const bf16x8*)(Ztp + (j * 16 + fr) * 64 + kk + fq * 8);
#pragma unroll
    for (int i = 0; i < 2; i++)
#pragma unroll
      for (int j = 0; j < 4; j++)
        ax[i][j] = __builtin_amdgcn_mfma_f32_16x16x32_bf16(ap[i], bz[j],
                                                           ax[i][j], 0, 0, 0);
  }

  const int b_ = bh >> 3, h = bh & 7;
#pragma unroll
  for (int i = 0; i < 2; i++) {
#pragma unroll
    for (int j = 0; j < 4; j++) {
      int c = h * 64 + j * 16 + fr;
#pragma unroll
      for (int r = 0; r < 4; r++) {
        int n = n0 + wave * 32 + i * 16 + fq * 4 + r;
        X[((size_t)(b_ * 4096 + n)) * 512 + c] = f2bf(ax[i][j][r]);
      }
    }
  }
}

// ---------------------------------------------------------------------------
// Kernel H (MFMA): out = X @ proj_w^T + proj_b, fp32 OUT. Grid (4, 128).
// ---------------------------------------------------------------------------
__global__ __launch_bounds__(256) void proj_gemm_mfma(
    const unsigned short* __restrict__ X, const unsigned short* __restrict__ w,
    const float* __restrict__ bias, float* __restrict__ out) {
  __shared__ __align__(16) unsigned short At[128 * 64];
  __shared__ __align__(16) unsigned short Bt[128 * 64];
  const int t = threadIdx.x;
  const int lane = t & 63, wave = t >> 6;
  const int wr = wave >> 1, wc = wave & 1;
  const int i0 = blockIdx.y * 128, j0 = blockIdx.x * 128;
  const int srow = lane >> 3;
  const int skc = (lane & 7) * 8;
  const int fr = lane & 15, fq = lane >> 4;
  f32x4 acc[4][4] = {};

  for (int k0 = 0; k0 < 512; k0 += 64) {
#pragma unroll
    for (int s = 0; s < 4; s++) {
      int inst = wave * 4 + s;
      int row = inst * 8 + srow;
      gload_lds16(X + (size_t)(i0 + row) * 512 + k0 + skc, &At[inst * 512]);
      gload_lds16(w + (size_t)(j0 + row) * 512 + k0 + skc, &Bt[inst * 512]);
    }
    __syncthreads();
#pragma unroll
    for (int kk = 0; kk < 64; kk += 32) {
      bf16x8 af[4], bg[4];
#pragma unroll
      for (int i = 0; i < 4; i++)
        af[i] = *(const bf16x8*)&At[(wr * 64 + i * 16 + fr) * 64 + kk + fq * 8];
#pragma unroll
      for (int j = 0; j < 4; j++)
        bg[j] = *(const bf16x8*)&Bt[(wc * 64 + j * 16 + fr) * 64 + kk + fq * 8];
#pragma unroll
      for (int i = 0; i < 4; i++)
#pragma unroll
        for (int j = 0; j < 4; j++)
          acc[i][j] = __builtin_amdgcn_mfma_f32_16x16x32_bf16(
              af[i], bg[j], acc[i][j], 0, 0, 0);
    }
    __syncthreads();
  }
#pragma unroll
  for (int j = 0; j < 4; j++) {
    int col = j0 + wc * 64 + j * 16 + fr;  // 0..511
    float bia = bias[col];
#pragma unroll
    for (int i = 0; i < 4; i++) {
      int rbase = i0 + wr * 64 + i * 16 + fq * 4;
#pragma unroll
      for (int r = 0; r < 4; r++) {
        out[(size_t)(rbase + r) * 512 + col] = acc[i][j][r] + bia;
      }
    }
  }
}

// ---------------------------------------------------------------------------
extern "C" void kernel_launch(void* const* d_in, const int* in_sizes, int n_in,
                              void* d_out, int out_size, void* d_ws,
                              size_t ws_size, hipStream_t stream) {
  (void)in_sizes; (void)n_in; (void)out_size; (void)ws_size;

  char* w8 = (char*)d_ws;
  unsigned short* cx  = (unsigned short*)(w8 + 0);         // x canon bf16
  unsigned short* cwq = (unsigned short*)(w8 + 16777216);  // qkv_w canon
  unsigned short* cwp = (unsigned short*)(w8 + 18350080);  // proj_w canon
  float*          cbf = (float*)(w8 + 18874368);           // proj_b fp32
  unsigned short* qkv = (unsigned short*)(w8 + 18876416);  // Q,K,V bf16
  unsigned short* X   = (unsigned short*)(w8 + 69208064);  // attn out bf16
  float* Ql = (float*)(w8 + 85985280);
  float* Kl = (float*)(w8 + 86509568);
  float* k2 = (float*)(w8 + 87033856);
  unsigned short* Ztb = (unsigned short*)(w8 + 88082432);  // Z^T bf16 [bh][d][m]
  unsigned int* gstat = (unsigned int*)(w8 + 88606720);  // [cmax, rmax, flag]
  float* Wp = (float*)(w8 + 88608768);                   // 32*8*4096*4 B
  float* sp = (float*)(w8 + 92803072);                   // 32*8*64*4 B
  unsigned short* Klb = (unsigned short*)(w8 + 92868608); // Kl bf16
  unsigned short* Qlb = (unsigned short*)(w8 + 93130752); // Ql bf16

  hipMemsetAsync(gstat, 0, 16, stream);
  detect_bias<<<1, 256, 0, stream>>>((const unsigned short*)d_in[0], d_in[3],
                                     cbf, gstat + 2);
  conv_all<<<4608, 256, 0, stream>>>(d_in[0], d_in[1], d_in[2], cx, cwq, cwp,
                                     gstat + 2);
  qkv_gemm_mfma<<<dim3(12, 128), 256, 0, stream>>>(cwq, cx, qkv, Ql, Kl, Qlb,
                                                   Klb);
  k2_kernel<<<32, 256, 0, stream>>>(Ql, Kl, k2, gstat);
  k3_mfma<<<dim3(8, 32), 256, 0, stream>>>(Qlb, qkv, Wp, sp);
  ns_kernel<<<32, 256, 0, stream>>>(k2, gstat, Wp, sp, Ztb);
  k1x_mfma<<<dim3(32, 32), 256, 0, stream>>>(qkv, Klb, Ztb, X);
  proj_gemm_mfma<<<dim3(4, 128), 256, 0, stream>>>(X, cwp, cbf,
                                                   (float*)d_out);
}